// Round 1
// baseline (831.434 us; speedup 1.0000x reference)
//
#include <hip/hip_runtime.h>
#include <hip/hip_bf16.h>

typedef unsigned short u16;
typedef unsigned int u32;
typedef __attribute__((ext_vector_type(8))) short s8v;
typedef __attribute__((ext_vector_type(4))) float f4v;

#define HDIM 512
#define NNODE 16384
#define NB 15

__device__ __forceinline__ u16 f2bu(float x) {
  union { float f; u32 i; } v; v.f = x;
  u32 r = v.i + 0x7FFFu + ((v.i >> 16) & 1u);
  return (u16)(r >> 16);
}
__device__ __forceinline__ float bu2f(u16 u) {
  union { u32 i; float f; } v; v.i = ((u32)u) << 16;
  return v.f;
}

// ---------------- slice-convert f32 -> bf16 ----------------
__global__ void k_cvt(const float* __restrict__ src, u16* __restrict__ dst,
                      int R, int Csrc, int c0, int C) {
  int i = blockIdx.x * 256 + threadIdx.x;
  if (i >= R * C) return;
  int r = i / C, c = i - r * C;
  dst[i] = f2bu(src[(size_t)r * Csrc + c0 + c]);
}

// ---------------- gather: sum_h (f32+bf16), cur_o (bf16) ----------------
__global__ __launch_bounds__(256) void k_gather(
    const float* __restrict__ H_msg,
    const int* __restrict__ nei_idx, const int* __restrict__ nei_mask,
    const int* __restrict__ o_idx, const int* __restrict__ o_mask,
    float* __restrict__ sum_h_f, u16* __restrict__ sum_h_bf,
    u16* __restrict__ cur_o_bf) {
  int n = blockIdx.x;
  int t = threadIdx.x;
  __shared__ int sidx[NB], smsk[NB], soid[NB], somk[NB];
  if (t < NB) {
    sidx[t] = nei_idx[(size_t)n * NB + t];
    smsk[t] = nei_mask[(size_t)n * NB + t];
    soid[t] = o_idx[(size_t)n * NB + t];
    somk[t] = o_mask[(size_t)n * NB + t];
  }
  __syncthreads();
  float s0 = 0.f, s1 = 0.f, o0 = 0.f, o1 = 0.f;
  for (int k = 0; k < NB; k++) {
    if (smsk[k]) {
      const float* r = H_msg + (size_t)sidx[k] * HDIM;
      s0 += r[t]; s1 += r[t + 256];
    }
    if (somk[k]) {
      const float* r = H_msg + (size_t)soid[k] * HDIM;
      o0 += r[t]; o1 += r[t + 256];
    }
  }
  size_t base = (size_t)n * HDIM;
  sum_h_f[base + t] = s0;           sum_h_f[base + t + 256] = s1;
  sum_h_bf[base + t] = f2bu(s0);    sum_h_bf[base + t + 256] = f2bu(s1);
  cur_o_bf[base + t] = f2bu(o0);    cur_o_bf[base + t + 256] = f2bu(o1);
}

// ---------------- generic NT GEMM (A[M,K] bf16, B[Nout,K] bf16) + epilogues ----
// EP 0: outf[row*ldo+col] = acc + bias[col]
// EP 1: outf = sigmoid(acc + gadd[gidx[row]][col])                (z)
// EP 2: outh = bf16((1-z)*sum_h + z*tanh(acc + gadd[gidx[row]][col]))  (new_h)
// EP 3: outh = bf16(relu(acc + gadd[gidx[row]][col]))             (w_hid/stop_h/s_hid)
template<int EP>
__global__ __launch_bounds__(256) void k_gemm(
    const u16* __restrict__ A, const u16* __restrict__ B, int K,
    const float* __restrict__ gadd, const int* __restrict__ gidx,
    const float* __restrict__ bias, const float* __restrict__ zf,
    const float* __restrict__ shf, float* __restrict__ outf,
    u16* __restrict__ outh, int ldo) {
  __shared__ u16 As[128 * 32];
  __shared__ u16 Bs[128 * 32];
  const int tid = threadIdx.x, lane = tid & 63, w = tid >> 6;
  const int wm = (w >> 1) * 64, wn = (w & 1) * 64;
  const int m0 = blockIdx.x * 128, n0 = blockIdx.y * 128;
  f4v acc[4][4];
  f4v z4 = {0.f, 0.f, 0.f, 0.f};
#pragma unroll
  for (int a = 0; a < 4; a++)
#pragma unroll
    for (int b = 0; b < 4; b++) acc[a][b] = z4;

  for (int k0 = 0; k0 < K; k0 += 32) {
    __syncthreads();
#pragma unroll
    for (int i = 0; i < 2; i++) {
      int t = tid + i * 256;
      int r = t >> 2, s = t & 3;
      *reinterpret_cast<uint4*>(&As[r * 32 + s * 8]) =
          *reinterpret_cast<const uint4*>(&A[(size_t)(m0 + r) * K + k0 + s * 8]);
      *reinterpret_cast<uint4*>(&Bs[r * 32 + s * 8]) =
          *reinterpret_cast<const uint4*>(&B[(size_t)(n0 + r) * K + k0 + s * 8]);
    }
    __syncthreads();
    s8v af[4], bf[4];
#pragma unroll
    for (int i = 0; i < 4; i++) {
      af[i] = *reinterpret_cast<const s8v*>(
          &As[(wm + i * 16 + (lane & 15)) * 32 + (lane >> 4) * 8]);
      bf[i] = *reinterpret_cast<const s8v*>(
          &Bs[(wn + i * 16 + (lane & 15)) * 32 + (lane >> 4) * 8]);
    }
#pragma unroll
    for (int mi = 0; mi < 4; mi++)
#pragma unroll
      for (int ni = 0; ni < 4; ni++)
        acc[mi][ni] = __builtin_amdgcn_mfma_f32_16x16x32_bf16(
            af[mi], bf[ni], acc[mi][ni], 0, 0, 0);
  }
  // epilogue: D mapping col=lane&15, row=(lane>>4)*4+r  [guide §3, m89/m91]
#pragma unroll
  for (int mi = 0; mi < 4; mi++) {
#pragma unroll
    for (int ni = 0; ni < 4; ni++) {
#pragma unroll
      for (int r = 0; r < 4; r++) {
        int row = m0 + wm + mi * 16 + (lane >> 4) * 4 + r;
        int col = n0 + wn + ni * 16 + (lane & 15);
        float v = acc[mi][ni][r];
        if constexpr (EP == 0) {
          outf[(size_t)row * ldo + col] = v + (bias ? bias[col] : 0.f);
        } else if constexpr (EP == 1) {
          float pre = v + gadd[(size_t)gidx[row] * HDIM + col];
          outf[(size_t)row * ldo + col] = 1.f / (1.f + __expf(-pre));
        } else if constexpr (EP == 2) {
          float pre = tanhf(v + gadd[(size_t)gidx[row] * HDIM + col]);
          float z = zf[(size_t)row * HDIM + col];
          float sh = shf[(size_t)row * HDIM + col];
          outh[(size_t)row * ldo + col] = f2bu((1.f - z) * sh + z * pre);
        } else {  // EP == 3
          float pre = v + gadd[(size_t)gidx[row] * HDIM + col];
          outh[(size_t)row * ldo + col] = f2bu(pre > 0.f ? pre : 0.f);
        }
      }
    }
  }
}

// ---------------- fused r2 GEMM + sigmoid + weighted neighbor sum ----------
// block: 16 nodes x 256 cols; 8 waves; 15 slot accumulators live across K-loop.
__global__ __launch_bounds__(512) void k_r2sg(
    const float* __restrict__ H_msg, const int* __restrict__ nei_idx,
    const int* __restrict__ nei_mask, const int* __restrict__ x_ids,
    const u16* __restrict__ Ur_bf, const float* __restrict__ E_r,
    u16* __restrict__ sg_bf) {
  __shared__ u16 As[240 * 32];   // [slot*16+node][k] bf16
  __shared__ u16 Bs[256 * 32];   // [col][k] bf16 (Ur rows)
  __shared__ int s_idx[240];
  __shared__ float s_msk[240];
  __shared__ int s_xid[16];
  const int n0 = blockIdx.x * 16;
  const int c0 = blockIdx.y * 256;
  const int tid = threadIdx.x, lane = tid & 63, w = tid >> 6;
  if (tid < 240) {
    int slot = tid >> 4, node = tid & 15;
    s_idx[tid] = nei_idx[(size_t)(n0 + node) * NB + slot];
    s_msk[tid] = (float)nei_mask[(size_t)(n0 + node) * NB + slot];
  }
  if (tid < 16) s_xid[tid] = x_ids[n0 + tid];

  f4v acc[15][2];
  f4v z4 = {0.f, 0.f, 0.f, 0.f};
#pragma unroll
  for (int s = 0; s < 15; s++) { acc[s][0] = z4; acc[s][1] = z4; }

  for (int k0 = 0; k0 < HDIM; k0 += 32) {
    __syncthreads();
    // stage A: gather 240 rows x 32 f32 from H_msg, convert to bf16
#pragma unroll
    for (int i = 0; i < 4; i++) {
      int t = tid + i * 512;
      if (t < 1920) {
        int r = t >> 3, s = t & 7;
        float4 v = *reinterpret_cast<const float4*>(
            &H_msg[(size_t)s_idx[r] * HDIM + k0 + s * 4]);
        uint2 p;
        p.x = (u32)f2bu(v.x) | ((u32)f2bu(v.y) << 16);
        p.y = (u32)f2bu(v.z) | ((u32)f2bu(v.w) << 16);
        *reinterpret_cast<uint2*>(&As[r * 32 + s * 4]) = p;
      }
    }
    // stage B: Ur rows c0..c0+255, 32 k each
#pragma unroll
    for (int i = 0; i < 2; i++) {
      int t = tid + i * 512;
      int r = t >> 2, s = t & 3;
      *reinterpret_cast<uint4*>(&Bs[r * 32 + s * 8]) =
          *reinterpret_cast<const uint4*>(
              &Ur_bf[(size_t)(c0 + r) * HDIM + k0 + s * 8]);
    }
    __syncthreads();
    s8v b0 = *reinterpret_cast<const s8v*>(
        &Bs[(w * 32 + (lane & 15)) * 32 + (lane >> 4) * 8]);
    s8v b1 = *reinterpret_cast<const s8v*>(
        &Bs[(w * 32 + 16 + (lane & 15)) * 32 + (lane >> 4) * 8]);
#pragma unroll
    for (int s = 0; s < 15; s++) {
      s8v a = *reinterpret_cast<const s8v*>(
          &As[(s * 16 + (lane & 15)) * 32 + (lane >> 4) * 8]);
      acc[s][0] = __builtin_amdgcn_mfma_f32_16x16x32_bf16(a, b0, acc[s][0], 0, 0, 0);
      acc[s][1] = __builtin_amdgcn_mfma_f32_16x16x32_bf16(a, b1, acc[s][1], 0, 0, 0);
    }
  }
  // epilogue: r = sigmoid(r2 + r1_gather); sg += r * h_nei * mask
  const int colb = c0 + w * 32;
  float er[2][4], sg[2][4];
#pragma unroll
  for (int cf = 0; cf < 2; cf++)
#pragma unroll
    for (int r = 0; r < 4; r++) {
      int node = (lane >> 4) * 4 + r;
      int col = colb + cf * 16 + (lane & 15);
      er[cf][r] = E_r[(size_t)s_xid[node] * HDIM + col];
      sg[cf][r] = 0.f;
    }
#pragma unroll
  for (int s = 0; s < 15; s++) {
#pragma unroll
    for (int cf = 0; cf < 2; cf++)
#pragma unroll
      for (int r = 0; r < 4; r++) {
        int node = (lane >> 4) * 4 + r;
        int col = colb + cf * 16 + (lane & 15);
        float rv = acc[s][cf][r] + er[cf][r];
        rv = 1.f / (1.f + __expf(-rv));
        float h = H_msg[(size_t)s_idx[s * 16 + node] * HDIM + col] *
                  s_msk[s * 16 + node];
        sg[cf][r] += rv * h;
      }
  }
#pragma unroll
  for (int cf = 0; cf < 2; cf++)
#pragma unroll
    for (int r = 0; r < 4; r++) {
      int node = (lane >> 4) * 4 + r;
      int col = colb + cf * 16 + (lane & 15);
      sg_bf[(size_t)(n0 + node) * HDIM + col] = f2bu(sg[cf][r]);
    }
}

// ---------------- stop score: dot(s_hid, Uo_w) + Uo_b ----------------
__global__ __launch_bounds__(256) void k_stop(
    const u16* __restrict__ shid, const float* __restrict__ Uo_w,
    const float* __restrict__ Uo_b, float* __restrict__ out) {
  int n = blockIdx.x * 4 + (threadIdx.x >> 6);
  int lane = threadIdx.x & 63;
  float s = 0.f;
  for (int j = lane; j < HDIM; j += 64)
    s += bu2f(shid[(size_t)n * HDIM + j]) * Uo_w[j];
#pragma unroll
  for (int off = 32; off; off >>= 1) s += __shfl_xor(s, off, 64);
  if (lane == 0) out[(size_t)n * 1025 + 1024] = s + Uo_b[0];
}

// ---------------- host ----------------
extern "C" void kernel_launch(void* const* d_in, const int* in_sizes, int n_in,
                              void* d_out, int out_size, void* d_ws, size_t ws_size,
                              hipStream_t stream) {
  const int* x_ids = (const int*)d_in[0];
  const int* contexts = (const int*)d_in[1];
  const int* nei_idx = (const int*)d_in[2];
  const int* nei_mask = (const int*)d_in[3];
  const int* o_idx = (const int*)d_in[4];
  const int* o_mask = (const int*)d_in[5];
  const float* H_msg = (const float*)d_in[6];
  const float* xtree = (const float*)d_in[7];
  const float* emb = (const float*)d_in[8];
  const float* Wz_w = (const float*)d_in[9];  const float* Wz_b = (const float*)d_in[10];
  const float* Wr_w = (const float*)d_in[11]; const float* Wr_b = (const float*)d_in[12];
  const float* Ur_w = (const float*)d_in[13];
  const float* Wh_w = (const float*)d_in[14]; const float* Wh_b = (const float*)d_in[15];
  const float* W_w  = (const float*)d_in[16]; const float* W_b  = (const float*)d_in[17];
  const float* Wo_w = (const float*)d_in[18]; const float* Wo_b = (const float*)d_in[19];
  const float* Ui_w = (const float*)d_in[20]; const float* Ui_b = (const float*)d_in[21];
  const float* U_w  = (const float*)d_in[22]; const float* U_b  = (const float*)d_in[23];
  const float* Uo_w = (const float*)d_in[24]; const float* Uo_b = (const float*)d_in[25];
  float* out = (float*)d_out;

  char* base = (char*)d_ws;
  size_t ofs = 0;
  auto alloc = [&](size_t bytes) -> char* {
    char* p = base + ofs;
    ofs = (ofs + bytes + 255) & ~(size_t)255;
    return p;
  };
  const size_t W512 = 512 * 512 * 2;
  u16* wz_x = (u16*)alloc(W512);
  u16* wz_h = (u16*)alloc(W512);
  u16* wr   = (u16*)alloc(W512);
  u16* ur   = (u16*)alloc(W512);
  u16* wh_x = (u16*)alloc(W512);
  u16* wh_h = (u16*)alloc(W512);
  u16* w_n  = (u16*)alloc(W512);
  u16* w_c  = (u16*)alloc(512 * 128 * 2);
  u16* wo   = (u16*)alloc(1024 * 512 * 2);
  u16* ui_x = (u16*)alloc(W512);
  u16* ui_h = (u16*)alloc(W512);
  u16* u_n  = (u16*)alloc(W512);
  u16* u_c  = (u16*)alloc(512 * 128 * 2);
  u16* emb_bf = (u16*)alloc(1024 * 512 * 2);
  u16* xt_bf  = (u16*)alloc(256 * 128 * 2);
  float* E_z = (float*)alloc(1024 * 512 * 4);
  float* E_r = (float*)alloc(1024 * 512 * 4);
  float* E_h = (float*)alloc(1024 * 512 * 4);
  float* E_i = (float*)alloc(1024 * 512 * 4);
  float* Cw  = (float*)alloc(256 * 512 * 4);
  float* Cu  = (float*)alloc(256 * 512 * 4);
  float* sum_h_f  = (float*)alloc((size_t)NNODE * 512 * 4);
  float* z_f      = (float*)alloc((size_t)NNODE * 512 * 4);
  u16* sum_h_bf = (u16*)alloc((size_t)NNODE * 512 * 2);
  u16* cur_o_bf = (u16*)alloc((size_t)NNODE * 512 * 2);
  u16* sg_bf    = (u16*)alloc((size_t)NNODE * 512 * 2);
  u16* newh_bf  = (u16*)alloc((size_t)NNODE * 512 * 2);
  u16* whid_bf  = (u16*)alloc((size_t)NNODE * 512 * 2);
  u16* stoph_bf = (u16*)alloc((size_t)NNODE * 512 * 2);
  u16* shid_bf  = (u16*)alloc((size_t)NNODE * 512 * 2);

  auto cvt = [&](const float* src, u16* dst, int R, int Cs, int c0, int C) {
    int tot = R * C;
    k_cvt<<<dim3((tot + 255) / 256), dim3(256), 0, stream>>>(src, dst, R, Cs, c0, C);
  };
  cvt(Wz_w, wz_x, 512, 1024, 0, 512);
  cvt(Wz_w, wz_h, 512, 1024, 512, 512);
  cvt(Wr_w, wr, 512, 512, 0, 512);
  cvt(Ur_w, ur, 512, 512, 0, 512);
  cvt(Wh_w, wh_x, 512, 1024, 0, 512);
  cvt(Wh_w, wh_h, 512, 1024, 512, 512);
  cvt(W_w, w_n, 512, 640, 0, 512);
  cvt(W_w, w_c, 512, 640, 512, 128);
  cvt(Wo_w, wo, 1024, 512, 0, 512);
  cvt(Ui_w, ui_x, 512, 1024, 0, 512);
  cvt(Ui_w, ui_h, 512, 1024, 512, 512);
  cvt(U_w, u_n, 512, 640, 0, 512);
  cvt(U_w, u_c, 512, 640, 512, 128);
  cvt(emb, emb_bf, 1024, 512, 0, 512);
  cvt(xtree, xt_bf, 256, 128, 0, 128);

  auto gemm = [&](int ep, const u16* A, const u16* B, int M, int Nout, int K,
                  const float* gadd, const int* gidx, const float* bias,
                  const float* zf, const float* shf, float* outf, u16* outh,
                  int ldo) {
    dim3 g(M / 128, Nout / 128), b(256);
    switch (ep) {
      case 0: k_gemm<0><<<g, b, 0, stream>>>(A, B, K, gadd, gidx, bias, zf, shf, outf, outh, ldo); break;
      case 1: k_gemm<1><<<g, b, 0, stream>>>(A, B, K, gadd, gidx, bias, zf, shf, outf, outh, ldo); break;
      case 2: k_gemm<2><<<g, b, 0, stream>>>(A, B, K, gadd, gidx, bias, zf, shf, outf, outh, ldo); break;
      case 3: k_gemm<3><<<g, b, 0, stream>>>(A, B, K, gadd, gidx, bias, zf, shf, outf, outh, ldo); break;
    }
  };

  // precompute embedding/ctx projection tables
  gemm(0, emb_bf, wz_x, 1024, 512, 512, nullptr, nullptr, Wz_b, nullptr, nullptr, E_z, nullptr, 512);
  gemm(0, emb_bf, wr,   1024, 512, 512, nullptr, nullptr, Wr_b, nullptr, nullptr, E_r, nullptr, 512);
  gemm(0, emb_bf, wh_x, 1024, 512, 512, nullptr, nullptr, Wh_b, nullptr, nullptr, E_h, nullptr, 512);
  gemm(0, emb_bf, ui_x, 1024, 512, 512, nullptr, nullptr, Ui_b, nullptr, nullptr, E_i, nullptr, 512);
  gemm(0, xt_bf, w_c, 256, 512, 128, nullptr, nullptr, W_b, nullptr, nullptr, Cw, nullptr, 512);
  gemm(0, xt_bf, u_c, 256, 512, 128, nullptr, nullptr, U_b, nullptr, nullptr, Cu, nullptr, 512);

  // gathers
  k_gather<<<dim3(NNODE), dim3(256), 0, stream>>>(
      H_msg, nei_idx, nei_mask, o_idx, o_mask, sum_h_f, sum_h_bf, cur_o_bf);

  // z = sigmoid(sum_h @ Wz_h^T + E_z[x_ids])
  gemm(1, sum_h_bf, wz_h, NNODE, 512, 512, E_z, x_ids, nullptr, nullptr, nullptr, z_f, nullptr, 512);

  // fused r2 + sigmoid + weighted sum -> sum_gated (bf16)
  k_r2sg<<<dim3(NNODE / 16, 2), dim3(512), 0, stream>>>(
      H_msg, nei_idx, nei_mask, x_ids, ur, E_r, sg_bf);

  // new_h = (1-z)*sum_h + z*tanh(sg @ Wh_h^T + E_h[x_ids])
  gemm(2, sg_bf, wh_h, NNODE, 512, 512, E_h, x_ids, nullptr, z_f, sum_h_f, nullptr, newh_bf, 512);

  // w_hid = relu(new_h @ W_n^T + Cw[contexts])
  gemm(3, newh_bf, w_n, NNODE, 512, 512, Cw, contexts, nullptr, nullptr, nullptr, nullptr, whid_bf, 512);

  // word_scores = w_hid @ Wo^T + Wo_b -> out[:, 0:1024] (row stride 1025)
  gemm(0, whid_bf, wo, NNODE, 1024, 512, nullptr, nullptr, Wo_b, nullptr, nullptr, out, nullptr, 1025);

  // stop_h = relu(cur_o @ Ui_h^T + E_i[x_ids])
  gemm(3, cur_o_bf, ui_h, NNODE, 512, 512, E_i, x_ids, nullptr, nullptr, nullptr, nullptr, stoph_bf, 512);

  // s_hid = relu(stop_h @ U_n^T + Cu[contexts])
  gemm(3, stoph_bf, u_n, NNODE, 512, 512, Cu, contexts, nullptr, nullptr, nullptr, nullptr, shid_bf, 512);

  // stop score -> out[:, 1024]
  k_stop<<<dim3(NNODE / 4), dim3(256), 0, stream>>>(shid_bf, Uo_w, Uo_b, out);
}

// Round 2
// 701.899 us; speedup vs baseline: 1.1845x; 1.1845x over previous
//
#include <hip/hip_runtime.h>
#include <hip/hip_bf16.h>

typedef unsigned short u16;
typedef unsigned int u32;
typedef __attribute__((ext_vector_type(8))) short s8v;
typedef __attribute__((ext_vector_type(4))) float f4v;

#define HDIM 512
#define NNODE 16384
#define NB 15
#define SENT NNODE  // sentinel node id for pad rows

__device__ __forceinline__ u16 f2bu(float x) {
  union { float f; u32 i; } v; v.f = x;
  u32 r = v.i + 0x7FFFu + ((v.i >> 16) & 1u);
  return (u16)(r >> 16);
}
__device__ __forceinline__ float bu2f(u16 u) {
  union { u32 i; float f; } v; v.i = ((u32)u) << 16;
  return v.f;
}
// async global->LDS, 16B per lane; LDS dest must be linear per wave (it is).
__device__ __forceinline__ void gl16(const void* g, void* l) {
  __builtin_amdgcn_global_load_lds(
      (const __attribute__((address_space(1))) u32*)g,
      (__attribute__((address_space(3))) u32*)l, 16, 0, 0);
}

// ---------------- slice-convert f32 -> bf16 ----------------
__global__ void k_cvt(const float* __restrict__ src, u16* __restrict__ dst,
                      int R, int Csrc, int c0, int C) {
  int i = blockIdx.x * 256 + threadIdx.x;
  if (i >= R * C) return;
  int r = i / C, c = i - r * C;
  dst[i] = f2bu(src[(size_t)r * Csrc + c0 + c]);
}

// ---------------- H_msg f32 -> bf16 (8 elems/thread) ----------------
__global__ void k_cvtH(const float* __restrict__ src, u16* __restrict__ dst) {
  size_t i = ((size_t)blockIdx.x * 256 + threadIdx.x) * 8;
  float4 a = *reinterpret_cast<const float4*>(src + i);
  float4 b = *reinterpret_cast<const float4*>(src + i + 4);
  uint4 o;
  o.x = (u32)f2bu(a.x) | ((u32)f2bu(a.y) << 16);
  o.y = (u32)f2bu(a.z) | ((u32)f2bu(a.w) << 16);
  o.z = (u32)f2bu(b.x) | ((u32)f2bu(b.y) << 16);
  o.w = (u32)f2bu(b.z) | ((u32)f2bu(b.w) << 16);
  *reinterpret_cast<uint4*>(dst + i) = o;
}

// ---------------- compaction: count, scan, fill, pad ----------------
__global__ void k_cnt(const int* __restrict__ nm, int* __restrict__ cnt) {
  int n = blockIdx.x * 256 + threadIdx.x;
  if (n >= NNODE) return;
  int c = 0;
  for (int s = 0; s < NB; s++) c += nm[(size_t)n * NB + s];
  cnt[n] = c;
}

__global__ __launch_bounds__(1024) void k_scan(const int* __restrict__ cnt,
                                               int* __restrict__ base,
                                               int* __restrict__ mpad) {
  __shared__ int part[1024];
  int t = threadIdx.x;
  int local[16];
  int s = 0;
  for (int j = 0; j < 16; j++) { local[j] = s; s += cnt[t * 16 + j]; }
  part[t] = s;
  __syncthreads();
  for (int d = 1; d < 1024; d <<= 1) {
    int v = (t >= d) ? part[t - d] : 0;
    __syncthreads();
    part[t] += v;
    __syncthreads();
  }
  int off = part[t] - s;  // exclusive
  for (int j = 0; j < 16; j++) base[t * 16 + j] = off + local[j];
  if (t == 1023) {
    int tot = part[1023];
    mpad[0] = (tot + 127) & ~127;
    mpad[1] = tot;
  }
}

__global__ void k_fill(const int* __restrict__ ni, const int* __restrict__ nm,
                       const int* __restrict__ base, int* __restrict__ row_idx,
                       int* __restrict__ row_node) {
  int n = blockIdx.x * 256 + threadIdx.x;
  if (n >= NNODE) return;
  int b = base[n], j = 0;
  for (int s = 0; s < NB; s++) {
    if (nm[(size_t)n * NB + s]) {
      row_idx[b + j] = ni[(size_t)n * NB + s];
      row_node[b + j] = n;
      j++;
    }
  }
}

__global__ void k_padrows(const int* __restrict__ mpad, int* __restrict__ row_idx,
                          int* __restrict__ row_node) {
  int r = mpad[1] + threadIdx.x;
  if (r < mpad[0]) { row_idx[r] = 0; row_node[r] = SENT; }
}

// ---------------- gather (bf16 H): sum_h (f32+bf16), cur_o (bf16) ----------
__global__ __launch_bounds__(256) void k_gather(
    const u16* __restrict__ Hb,
    const int* __restrict__ nei_idx, const int* __restrict__ nei_mask,
    const int* __restrict__ o_idx, const int* __restrict__ o_mask,
    float* __restrict__ sum_h_f, u16* __restrict__ sum_h_bf,
    u16* __restrict__ cur_o_bf) {
  int n = blockIdx.x;
  int t = threadIdx.x;  // covers cols 2t, 2t+1
  __shared__ int si[NB], sm[NB], so[NB], sq[NB];
  if (t < NB) {
    si[t] = nei_idx[(size_t)n * NB + t];
    sm[t] = nei_mask[(size_t)n * NB + t];
    so[t] = o_idx[(size_t)n * NB + t];
    sq[t] = o_mask[(size_t)n * NB + t];
  }
  __syncthreads();
  float s0 = 0.f, s1 = 0.f, o0 = 0.f, o1 = 0.f;
  for (int k = 0; k < NB; k++) {
    if (sm[k]) {
      u32 v = *reinterpret_cast<const u32*>(Hb + (size_t)si[k] * HDIM + 2 * t);
      s0 += bu2f((u16)v); s1 += bu2f((u16)(v >> 16));
    }
    if (sq[k]) {
      u32 v = *reinterpret_cast<const u32*>(Hb + (size_t)so[k] * HDIM + 2 * t);
      o0 += bu2f((u16)v); o1 += bu2f((u16)(v >> 16));
    }
  }
  size_t b = (size_t)n * HDIM + 2 * t;
  *reinterpret_cast<float2*>(&sum_h_f[b]) = make_float2(s0, s1);
  *reinterpret_cast<u32*>(&sum_h_bf[b]) = (u32)f2bu(s0) | ((u32)f2bu(s1) << 16);
  *reinterpret_cast<u32*>(&cur_o_bf[b]) = (u32)f2bu(o0) | ((u32)f2bu(o1) << 16);
}

// ---------------- generic NT GEMM (A[M,K] bf16, B[Nout,K] bf16) + epilogues ----
// EP 0: outf = acc + bias[col]
// EP 1: outf = sigmoid(acc + gadd[gidx[row]][col])                (z)
// EP 2: outh = bf16((1-z)*sum_h + z*tanh(acc + gadd[gidx[row]][col]))  (new_h)
// EP 3: outh = bf16(relu(acc + gadd[gidx[row]][col]))             (w_hid/stop_h/s_hid)
template<int EP>
__global__ __launch_bounds__(256) void k_gemm(
    const u16* __restrict__ A, const u16* __restrict__ B, int K,
    const float* __restrict__ gadd, const int* __restrict__ gidx,
    const float* __restrict__ bias, const float* __restrict__ zf,
    const float* __restrict__ shf, float* __restrict__ outf,
    u16* __restrict__ outh, int ldo) {
  __shared__ u16 As[128 * 32];
  __shared__ u16 Bs[128 * 32];
  const int tid = threadIdx.x, lane = tid & 63, w = tid >> 6;
  const int wm = (w >> 1) * 64, wn = (w & 1) * 64;
  const int m0 = blockIdx.x * 128, n0 = blockIdx.y * 128;
  f4v acc[4][4];
  f4v z4 = {0.f, 0.f, 0.f, 0.f};
#pragma unroll
  for (int a = 0; a < 4; a++)
#pragma unroll
    for (int b = 0; b < 4; b++) acc[a][b] = z4;

  for (int k0 = 0; k0 < K; k0 += 32) {
    __syncthreads();
#pragma unroll
    for (int i = 0; i < 2; i++) {
      int t = tid + i * 256;
      gl16(&A[(size_t)(m0 + (t >> 2)) * K + k0 + (t & 3) * 8], &As[t * 8]);
    }
#pragma unroll
    for (int i = 0; i < 2; i++) {
      int t = tid + i * 256;
      gl16(&B[(size_t)(n0 + (t >> 2)) * K + k0 + (t & 3) * 8], &Bs[t * 8]);
    }
    __syncthreads();
    s8v af[4], bf[4];
#pragma unroll
    for (int i = 0; i < 4; i++) {
      af[i] = *reinterpret_cast<const s8v*>(
          &As[(wm + i * 16 + (lane & 15)) * 32 + (lane >> 4) * 8]);
      bf[i] = *reinterpret_cast<const s8v*>(
          &Bs[(wn + i * 16 + (lane & 15)) * 32 + (lane >> 4) * 8]);
    }
#pragma unroll
    for (int mi = 0; mi < 4; mi++)
#pragma unroll
      for (int ni = 0; ni < 4; ni++)
        acc[mi][ni] = __builtin_amdgcn_mfma_f32_16x16x32_bf16(
            af[mi], bf[ni], acc[mi][ni], 0, 0, 0);
  }
#pragma unroll
  for (int mi = 0; mi < 4; mi++) {
#pragma unroll
    for (int ni = 0; ni < 4; ni++) {
#pragma unroll
      for (int r = 0; r < 4; r++) {
        int row = m0 + wm + mi * 16 + (lane >> 4) * 4 + r;
        int col = n0 + wn + ni * 16 + (lane & 15);
        float v = acc[mi][ni][r];
        if constexpr (EP == 0) {
          outf[(size_t)row * ldo + col] = v + (bias ? bias[col] : 0.f);
        } else if constexpr (EP == 1) {
          float pre = v + gadd[(size_t)gidx[row] * HDIM + col];
          outf[(size_t)row * ldo + col] = 1.f / (1.f + __expf(-pre));
        } else if constexpr (EP == 2) {
          float pre = tanhf(v + gadd[(size_t)gidx[row] * HDIM + col]);
          float z = zf[(size_t)row * HDIM + col];
          float sh = shf[(size_t)row * HDIM + col];
          outh[(size_t)row * ldo + col] = f2bu((1.f - z) * sh + z * pre);
        } else {
          float pre = v + gadd[(size_t)gidx[row] * HDIM + col];
          outh[(size_t)row * ldo + col] = f2bu(pre > 0.f ? pre : 0.f);
        }
      }
    }
  }
}

// ---------------- compacted r2 GEMM + sigmoid + in-block segmented reduce ----
// rows = packed active (node,slot) pairs; 128 rows x 128 cols per block.
// 8 waves; wave w owns rows w*16..w*16+15, all 128 cols. acc[8] = 32 regs.
__global__ __launch_bounds__(512, 4) void k_r2c(
    const u16* __restrict__ Hb, const u16* __restrict__ Ur,
    const float* __restrict__ E_r, const int* __restrict__ x_ids,
    const int* __restrict__ row_idx, const int* __restrict__ row_node,
    const int* __restrict__ mpad, float* __restrict__ sg_f) {
  const int row0 = blockIdx.x * 128;
  if (row0 >= mpad[0]) return;
  const int c0 = blockIdx.y * 128;
  const int tid = threadIdx.x, lane = tid & 63, w = tid >> 6;
  __shared__ union {
    struct { u16 As[128 * 32]; u16 Bs[128 * 32]; } s;
    u16 rvh[128 * 136];
  } u;
  __shared__ int s_idx[128], s_node[128], s_xid[128];

  if (tid < 128) {
    int ri = row_idx[row0 + tid];
    int nd = row_node[row0 + tid];
    s_idx[tid] = ri;
    s_node[tid] = nd;
    s_xid[tid] = (nd < NNODE) ? x_ids[nd] : 0;
  }
  __syncthreads();

  const u16* ap = Hb + (size_t)s_idx[tid >> 2] * HDIM + (tid & 3) * 8;
  const u16* bp = Ur + (size_t)(c0 + (tid >> 2)) * HDIM + (tid & 3) * 8;
  u16* al = &u.s.As[tid * 8];
  u16* bl = &u.s.Bs[tid * 8];

  f4v acc[8];
  f4v z4 = {0.f, 0.f, 0.f, 0.f};
#pragma unroll
  for (int i = 0; i < 8; i++) acc[i] = z4;

  for (int k0 = 0; k0 < HDIM; k0 += 32) {
    __syncthreads();
    gl16(ap + k0, al);
    gl16(bp + k0, bl);
    __syncthreads();
    s8v af = *reinterpret_cast<const s8v*>(
        &u.s.As[((w << 4) + (lane & 15)) * 32 + (lane >> 4) * 8]);
#pragma unroll
    for (int cf = 0; cf < 8; cf++) {
      s8v bf = *reinterpret_cast<const s8v*>(
          &u.s.Bs[((cf << 4) + (lane & 15)) * 32 + (lane >> 4) * 8]);
      acc[cf] = __builtin_amdgcn_mfma_f32_16x16x32_bf16(af, bf, acc[cf], 0, 0, 0);
    }
  }
  __syncthreads();  // As/Bs dead; rvh takes over the union

  // epilogue: rv = sigmoid(r2 + r1[xid]); rvh = rv * h  -> LDS (C-layout)
  const int rb = (w << 4) + ((lane >> 4) << 2);
#pragma unroll
  for (int r = 0; r < 4; r++) {
    int lr = rb + r;
    const float* erow = E_r + (size_t)s_xid[lr] * HDIM + c0;
    const u16* hrow = Hb + (size_t)s_idx[lr] * HDIM + c0;
#pragma unroll
    for (int cf = 0; cf < 8; cf++) {
      int cl = (cf << 4) + (lane & 15);
      float pre = acc[cf][r] + erow[cl];
      float rv = 1.f / (1.f + __expf(-pre));
      u.rvh[lr * 136 + cl] = f2bu(rv * bu2f(hrow[cl]));
    }
  }
  __syncthreads();

  // segmented reduce over rows (globally node-contiguous).
  // first/last segments may straddle blocks -> atomicAdd (<=2 addends:
  // bitwise-deterministic); interior segments are exclusive -> plain store.
  if (tid < 128) {
    int c = c0 + tid;
    float a = 0.f;
    int cur = s_node[0];
    int segs = 0;
    for (int r = 0; r < 128; r++) {
      int nd = s_node[r];
      if (nd != cur) {
        float* p = &sg_f[(size_t)cur * HDIM + c];
        if (segs == 0) atomicAdd(p, a); else *p = a;
        cur = nd; a = 0.f; segs++;
      }
      a += bu2f(u.rvh[r * 136 + tid]);
    }
    atomicAdd(&sg_f[(size_t)cur * HDIM + c], a);
  }
}

// ---------------- stop score: dot(s_hid, Uo_w) + Uo_b ----------------
__global__ __launch_bounds__(256) void k_stop(
    const u16* __restrict__ shid, const float* __restrict__ Uo_w,
    const float* __restrict__ Uo_b, float* __restrict__ out) {
  int n = blockIdx.x * 4 + (threadIdx.x >> 6);
  int lane = threadIdx.x & 63;
  float s = 0.f;
  for (int j = lane; j < HDIM; j += 64)
    s += bu2f(shid[(size_t)n * HDIM + j]) * Uo_w[j];
#pragma unroll
  for (int off = 32; off; off >>= 1) s += __shfl_xor(s, off, 64);
  if (lane == 0) out[(size_t)n * 1025 + 1024] = s + Uo_b[0];
}

// ---------------- host ----------------
extern "C" void kernel_launch(void* const* d_in, const int* in_sizes, int n_in,
                              void* d_out, int out_size, void* d_ws, size_t ws_size,
                              hipStream_t stream) {
  const int* x_ids = (const int*)d_in[0];
  const int* contexts = (const int*)d_in[1];
  const int* nei_idx = (const int*)d_in[2];
  const int* nei_mask = (const int*)d_in[3];
  const int* o_idx = (const int*)d_in[4];
  const int* o_mask = (const int*)d_in[5];
  const float* H_msg = (const float*)d_in[6];
  const float* xtree = (const float*)d_in[7];
  const float* emb = (const float*)d_in[8];
  const float* Wz_w = (const float*)d_in[9];  const float* Wz_b = (const float*)d_in[10];
  const float* Wr_w = (const float*)d_in[11]; const float* Wr_b = (const float*)d_in[12];
  const float* Ur_w = (const float*)d_in[13];
  const float* Wh_w = (const float*)d_in[14]; const float* Wh_b = (const float*)d_in[15];
  const float* W_w  = (const float*)d_in[16]; const float* W_b  = (const float*)d_in[17];
  const float* Wo_w = (const float*)d_in[18]; const float* Wo_b = (const float*)d_in[19];
  const float* Ui_w = (const float*)d_in[20]; const float* Ui_b = (const float*)d_in[21];
  const float* U_w  = (const float*)d_in[22]; const float* U_b  = (const float*)d_in[23];
  const float* Uo_w = (const float*)d_in[24]; const float* Uo_b = (const float*)d_in[25];
  float* out = (float*)d_out;
  const int M = 65536;

  char* base = (char*)d_ws;
  size_t ofs = 0;
  auto alloc = [&](size_t bytes) -> char* {
    char* p = base + ofs;
    ofs = (ofs + bytes + 255) & ~(size_t)255;
    return p;
  };
  const size_t W512 = 512 * 512 * 2;
  u16* wz_x = (u16*)alloc(W512);
  u16* wz_h = (u16*)alloc(W512);
  u16* wr   = (u16*)alloc(W512);
  u16* ur   = (u16*)alloc(W512);
  u16* wh_x = (u16*)alloc(W512);
  u16* wh_h = (u16*)alloc(W512);
  u16* w_n  = (u16*)alloc(W512);
  u16* w_c  = (u16*)alloc(512 * 128 * 2);
  u16* wo   = (u16*)alloc(1024 * 512 * 2);
  u16* ui_x = (u16*)alloc(W512);
  u16* ui_h = (u16*)alloc(W512);
  u16* u_n  = (u16*)alloc(W512);
  u16* u_c  = (u16*)alloc(512 * 128 * 2);
  u16* emb_bf = (u16*)alloc(1024 * 512 * 2);
  u16* xt_bf  = (u16*)alloc(256 * 128 * 2);
  float* E_z = (float*)alloc(1024 * 512 * 4);
  float* E_r = (float*)alloc(1024 * 512 * 4);
  float* E_h = (float*)alloc(1024 * 512 * 4);
  float* E_i = (float*)alloc(1024 * 512 * 4);
  float* Cw  = (float*)alloc(256 * 512 * 4);
  float* Cu  = (float*)alloc(256 * 512 * 4);
  u16* H_bf = (u16*)alloc((size_t)M * HDIM * 2);
  float* sum_h_f = (float*)alloc((size_t)NNODE * HDIM * 4);
  float* z_f     = (float*)alloc((size_t)NNODE * HDIM * 4);
  float* sg_f    = (float*)alloc((size_t)(NNODE + 1) * HDIM * 4);
  u16* sum_h_bf = (u16*)alloc((size_t)NNODE * HDIM * 2);
  u16* cur_o_bf = (u16*)alloc((size_t)NNODE * HDIM * 2);
  u16* sg_bf    = (u16*)alloc((size_t)NNODE * HDIM * 2);
  u16* newh_bf  = (u16*)alloc((size_t)NNODE * HDIM * 2);
  u16* whid_bf  = (u16*)alloc((size_t)NNODE * HDIM * 2);
  u16* stoph_bf = (u16*)alloc((size_t)NNODE * HDIM * 2);
  u16* shid_bf  = (u16*)alloc((size_t)NNODE * HDIM * 2);
  int* cnt      = (int*)alloc(NNODE * 4);
  int* rbase    = (int*)alloc(NNODE * 4);
  int* row_idx  = (int*)alloc((size_t)NNODE * NB * 4);
  int* row_node = (int*)alloc((size_t)NNODE * NB * 4);
  int* mpad     = (int*)alloc(256);

  hipMemsetAsync(sg_f, 0, (size_t)(NNODE + 1) * HDIM * 4, stream);

  auto cvt = [&](const float* src, u16* dst, int R, int Cs, int c0, int C) {
    int tot = R * C;
    k_cvt<<<dim3((tot + 255) / 256), dim3(256), 0, stream>>>(src, dst, R, Cs, c0, C);
  };
  cvt(Wz_w, wz_x, 512, 1024, 0, 512);
  cvt(Wz_w, wz_h, 512, 1024, 512, 512);
  cvt(Wr_w, wr, 512, 512, 0, 512);
  cvt(Ur_w, ur, 512, 512, 0, 512);
  cvt(Wh_w, wh_x, 512, 1024, 0, 512);
  cvt(Wh_w, wh_h, 512, 1024, 512, 512);
  cvt(W_w, w_n, 512, 640, 0, 512);
  cvt(W_w, w_c, 512, 640, 512, 128);
  cvt(Wo_w, wo, 1024, 512, 0, 512);
  cvt(Ui_w, ui_x, 512, 1024, 0, 512);
  cvt(Ui_w, ui_h, 512, 1024, 512, 512);
  cvt(U_w, u_n, 512, 640, 0, 512);
  cvt(U_w, u_c, 512, 640, 512, 128);
  cvt(emb, emb_bf, 1024, 512, 0, 512);
  cvt(xtree, xt_bf, 256, 128, 0, 128);
  k_cvtH<<<dim3((int)((size_t)M * HDIM / 2048)), dim3(256), 0, stream>>>(H_msg, H_bf);

  auto gemm = [&](int ep, const u16* A, const u16* B, int Mr, int Nout, int K,
                  const float* gadd, const int* gidx, const float* bias,
                  const float* zf, const float* shf, float* outf, u16* outh,
                  int ldo) {
    dim3 g(Mr / 128, Nout / 128), b(256);
    switch (ep) {
      case 0: k_gemm<0><<<g, b, 0, stream>>>(A, B, K, gadd, gidx, bias, zf, shf, outf, outh, ldo); break;
      case 1: k_gemm<1><<<g, b, 0, stream>>>(A, B, K, gadd, gidx, bias, zf, shf, outf, outh, ldo); break;
      case 2: k_gemm<2><<<g, b, 0, stream>>>(A, B, K, gadd, gidx, bias, zf, shf, outf, outh, ldo); break;
      case 3: k_gemm<3><<<g, b, 0, stream>>>(A, B, K, gadd, gidx, bias, zf, shf, outf, outh, ldo); break;
    }
  };

  // embedding/ctx projection tables
  gemm(0, emb_bf, wz_x, 1024, 512, 512, nullptr, nullptr, Wz_b, nullptr, nullptr, E_z, nullptr, 512);
  gemm(0, emb_bf, wr,   1024, 512, 512, nullptr, nullptr, Wr_b, nullptr, nullptr, E_r, nullptr, 512);
  gemm(0, emb_bf, wh_x, 1024, 512, 512, nullptr, nullptr, Wh_b, nullptr, nullptr, E_h, nullptr, 512);
  gemm(0, emb_bf, ui_x, 1024, 512, 512, nullptr, nullptr, Ui_b, nullptr, nullptr, E_i, nullptr, 512);
  gemm(0, xt_bf, w_c, 256, 512, 128, nullptr, nullptr, W_b, nullptr, nullptr, Cw, nullptr, 512);
  gemm(0, xt_bf, u_c, 256, 512, 128, nullptr, nullptr, U_b, nullptr, nullptr, Cu, nullptr, 512);

  // compaction
  k_cnt<<<dim3(NNODE / 256), dim3(256), 0, stream>>>(nei_mask, cnt);
  k_scan<<<dim3(1), dim3(1024), 0, stream>>>(cnt, rbase, mpad);
  k_fill<<<dim3(NNODE / 256), dim3(256), 0, stream>>>(nei_idx, nei_mask, rbase, row_idx, row_node);
  k_padrows<<<dim3(1), dim3(128), 0, stream>>>(mpad, row_idx, row_node);

  // gathers (sum_h + cur_o)
  k_gather<<<dim3(NNODE), dim3(256), 0, stream>>>(
      H_bf, nei_idx, nei_mask, o_idx, o_mask, sum_h_f, sum_h_bf, cur_o_bf);

  // z = sigmoid(sum_h @ Wz_h^T + E_z[x_ids])
  gemm(1, sum_h_bf, wz_h, NNODE, 512, 512, E_z, x_ids, nullptr, nullptr, nullptr, z_f, nullptr, 512);

  // compacted r2 + sigmoid + weighted neighbor sum -> sg_f
  k_r2c<<<dim3(NNODE * NB / 128, 4), dim3(512), 0, stream>>>(
      H_bf, ur, E_r, x_ids, row_idx, row_node, mpad, sg_f);
  cvt(sg_f, sg_bf, NNODE, 512, 0, 512);

  // new_h = (1-z)*sum_h + z*tanh(sg @ Wh_h^T + E_h[x_ids])
  gemm(2, sg_bf, wh_h, NNODE, 512, 512, E_h, x_ids, nullptr, z_f, sum_h_f, nullptr, newh_bf, 512);

  // w_hid = relu(new_h @ W_n^T + Cw[contexts])
  gemm(3, newh_bf, w_n, NNODE, 512, 512, Cw, contexts, nullptr, nullptr, nullptr, nullptr, whid_bf, 512);

  // word_scores -> out[:, 0:1024] (row stride 1025)
  gemm(0, whid_bf, wo, NNODE, 1024, 512, nullptr, nullptr, Wo_b, nullptr, nullptr, out, nullptr, 1025);

  // stop_h = relu(cur_o @ Ui_h^T + E_i[x_ids])
  gemm(3, cur_o_bf, ui_h, NNODE, 512, 512, E_i, x_ids, nullptr, nullptr, nullptr, nullptr, stoph_bf, 512);

  // s_hid = relu(stop_h @ U_n^T + Cu[contexts])
  gemm(3, stoph_bf, u_n, NNODE, 512, 512, Cu, contexts, nullptr, nullptr, nullptr, nullptr, shid_bf, 512);

  // stop score -> out[:, 1024]
  k_stop<<<dim3(NNODE / 4), dim3(256), 0, stream>>>(shid_bf, Uo_w, Uo_b, out);
}

// Round 3
// 695.382 us; speedup vs baseline: 1.1957x; 1.0094x over previous
//
#include <hip/hip_runtime.h>
#include <hip/hip_bf16.h>

typedef unsigned short u16;
typedef unsigned int u32;
typedef __attribute__((ext_vector_type(8))) short s8v;
typedef __attribute__((ext_vector_type(4))) float f4v;

#define HDIM 512
#define NNODE 16384
#define NB 15
#define SENT NNODE

__device__ __forceinline__ u16 f2bu(float x) {
  union { float f; u32 i; } v; v.f = x;
  u32 r = v.i + 0x7FFFu + ((v.i >> 16) & 1u);
  return (u16)(r >> 16);
}
__device__ __forceinline__ float bu2f(u16 u) {
  union { u32 i; float f; } v; v.i = ((u32)u) << 16;
  return v.f;
}
__device__ __forceinline__ u32 pk(float a, float b) {
  return (u32)f2bu(a) | ((u32)f2bu(b) << 16);
}
__device__ __forceinline__ void gl16(const void* g, void* l) {
  __builtin_amdgcn_global_load_lds(
      (const __attribute__((address_space(1))) u32*)g,
      (__attribute__((address_space(3))) u32*)l, 16, 0, 0);
}

// ---------------- fused weight/bias conversion (21 segments) ----------------
__global__ __launch_bounds__(256) void k_cvt_all(
    const float* Wz_w, const float* Wr_w, const float* Wh_w, const float* Ui_w,
    const float* Ur_w, const float* W_w, const float* U_w, const float* Wo_w,
    const float* emb, const float* xtree,
    const float* Wz_b, const float* Wr_b, const float* Wh_b, const float* Ui_b,
    const float* W_b, const float* U_b,
    u16* wcat, u16* wz_h, u16* wh_h, u16* ui_h, u16* ur, u16* w_n, u16* u_n,
    u16* ccat, u16* wo, u16* emb_bf, u16* xt_bf, float* ebias, float* cbias) {
  int seg = blockIdx.y;
  const float* src = nullptr; u16* dst = nullptr;
  const float* fsrc = nullptr; float* fdst = nullptr;
  int R = 0, Cs = 0, c0 = 0, C = 0, fn = 0;
  switch (seg) {
    case 0:  src = Wz_w; dst = wcat;              R = 512;  Cs = 1024; c0 = 0;   C = 512; break;
    case 1:  src = Wr_w; dst = wcat + 512 * 512;  R = 512;  Cs = 512;  c0 = 0;   C = 512; break;
    case 2:  src = Wh_w; dst = wcat + 1024 * 512; R = 512;  Cs = 1024; c0 = 0;   C = 512; break;
    case 3:  src = Ui_w; dst = wcat + 1536 * 512; R = 512;  Cs = 1024; c0 = 0;   C = 512; break;
    case 4:  src = Wz_w; dst = wz_h;              R = 512;  Cs = 1024; c0 = 512; C = 512; break;
    case 5:  src = Wh_w; dst = wh_h;              R = 512;  Cs = 1024; c0 = 512; C = 512; break;
    case 6:  src = Ui_w; dst = ui_h;              R = 512;  Cs = 1024; c0 = 512; C = 512; break;
    case 7:  src = Ur_w; dst = ur;                R = 512;  Cs = 512;  c0 = 0;   C = 512; break;
    case 8:  src = W_w;  dst = w_n;               R = 512;  Cs = 640;  c0 = 0;   C = 512; break;
    case 9:  src = U_w;  dst = u_n;               R = 512;  Cs = 640;  c0 = 0;   C = 512; break;
    case 10: src = W_w;  dst = ccat;              R = 512;  Cs = 640;  c0 = 512; C = 128; break;
    case 11: src = U_w;  dst = ccat + 512 * 128;  R = 512;  Cs = 640;  c0 = 512; C = 128; break;
    case 12: src = Wo_w; dst = wo;                R = 1024; Cs = 512;  c0 = 0;   C = 512; break;
    case 13: src = emb;  dst = emb_bf;            R = 1024; Cs = 512;  c0 = 0;   C = 512; break;
    case 14: src = xtree; dst = xt_bf;            R = 256;  Cs = 128;  c0 = 0;   C = 128; break;
    case 15: fsrc = Wz_b; fdst = ebias;        fn = 512; break;
    case 16: fsrc = Wr_b; fdst = ebias + 512;  fn = 512; break;
    case 17: fsrc = Wh_b; fdst = ebias + 1024; fn = 512; break;
    case 18: fsrc = Ui_b; fdst = ebias + 1536; fn = 512; break;
    case 19: fsrc = W_b;  fdst = cbias;        fn = 512; break;
    case 20: fsrc = U_b;  fdst = cbias + 512;  fn = 512; break;
  }
  int i = blockIdx.x * 256 + threadIdx.x;
  if (fdst) { if (i < fn) fdst[i] = fsrc[i]; return; }
  int e0 = i * 8;
  if (e0 >= R * C) return;
  int r = e0 / C, c = e0 - r * C;
  const float* s = src + (size_t)r * Cs + c0 + c;
  float4 a = *reinterpret_cast<const float4*>(s);
  float4 b = *reinterpret_cast<const float4*>(s + 4);
  uint4 o = {pk(a.x, a.y), pk(a.z, a.w), pk(b.x, b.y), pk(b.z, b.w)};
  *reinterpret_cast<uint4*>(&dst[e0]) = o;
}

// ---------------- flat f32 -> bf16, 8 elems/thread ----------------
__global__ void k_cvt8(const float* __restrict__ src, u16* __restrict__ dst) {
  size_t i = ((size_t)blockIdx.x * 256 + threadIdx.x) * 8;
  float4 a = *reinterpret_cast<const float4*>(src + i);
  float4 b = *reinterpret_cast<const float4*>(src + i + 4);
  uint4 o = {pk(a.x, a.y), pk(a.z, a.w), pk(b.x, b.y), pk(b.z, b.w)};
  *reinterpret_cast<uint4*>(dst + i) = o;
}

// ---------------- compaction ----------------
__global__ void k_cnt(const int* __restrict__ nm, int* __restrict__ cnt) {
  int n = blockIdx.x * 256 + threadIdx.x;
  int c = 0;
  for (int s = 0; s < NB; s++) c += nm[(size_t)n * NB + s];
  cnt[n] = c;
}

__global__ __launch_bounds__(1024) void k_scan(const int* __restrict__ cnt,
                                               int* __restrict__ base,
                                               int* __restrict__ mpad) {
  __shared__ int part[1024];
  int t = threadIdx.x;
  int local[16];
  int s = 0;
  for (int j = 0; j < 16; j++) { local[j] = s; s += cnt[t * 16 + j]; }
  part[t] = s;
  __syncthreads();
  for (int d = 1; d < 1024; d <<= 1) {
    int v = (t >= d) ? part[t - d] : 0;
    __syncthreads();
    part[t] += v;
    __syncthreads();
  }
  int off = part[t] - s;
  for (int j = 0; j < 16; j++) base[t * 16 + j] = off + local[j];
  if (t == 1023) {
    mpad[0] = (part[1023] + 127) & ~127;
    mpad[1] = part[1023];
  }
}

__global__ void k_fill(const int* __restrict__ ni, const int* __restrict__ nm,
                       const int* __restrict__ base, int* __restrict__ row_idx,
                       int* __restrict__ row_node, const int* __restrict__ mpad) {
  int n = blockIdx.x * 256 + threadIdx.x;
  int b = base[n], j = 0;
  for (int s = 0; s < NB; s++) {
    if (nm[(size_t)n * NB + s]) {
      row_idx[b + j] = ni[(size_t)n * NB + s];
      row_node[b + j] = n;
      j++;
    }
  }
  if (blockIdx.x == 0 && threadIdx.x < 128) {
    int r = mpad[1] + threadIdx.x;
    if (r < mpad[0]) { row_idx[r] = 0; row_node[r] = SENT; }
  }
}

// ---------------- gather: half-block nei -> sum_h, half-block o -> cur_o ----
__global__ __launch_bounds__(256) void k_gather(
    const u16* __restrict__ Hb,
    const int* __restrict__ nei_idx, const int* __restrict__ nei_mask,
    const int* __restrict__ o_idx, const int* __restrict__ o_mask,
    float* __restrict__ sum_h_f, u16* __restrict__ sum_h_bf,
    u16* __restrict__ cur_o_bf) {
  int n = blockIdx.x;
  int t = threadIdx.x;
  int half = t >> 7, q = t & 127;  // q covers cols 4q..4q+3
  __shared__ int sidx[2][NB];
  __shared__ float smsk[2][NB];
  if (t < NB) {
    sidx[0][t] = nei_idx[(size_t)n * NB + t];
    smsk[0][t] = (float)nei_mask[(size_t)n * NB + t];
  } else if (t >= 128 && t < 128 + NB) {
    int k = t - 128;
    sidx[1][k] = o_idx[(size_t)n * NB + k];
    smsk[1][k] = (float)o_mask[(size_t)n * NB + k];
  }
  __syncthreads();
  float a0 = 0.f, a1 = 0.f, a2 = 0.f, a3 = 0.f;
#pragma unroll
  for (int k = 0; k < NB; k++) {
    if (smsk[half][k] != 0.f) {
      uint2 v = *reinterpret_cast<const uint2*>(Hb + (size_t)sidx[half][k] * HDIM + q * 4);
      a0 += bu2f((u16)v.x); a1 += bu2f((u16)(v.x >> 16));
      a2 += bu2f((u16)v.y); a3 += bu2f((u16)(v.y >> 16));
    }
  }
  size_t b = (size_t)n * HDIM + q * 4;
  if (half == 0) {
    *reinterpret_cast<float4*>(&sum_h_f[b]) = make_float4(a0, a1, a2, a3);
    uint2 p = {pk(a0, a1), pk(a2, a3)};
    *reinterpret_cast<uint2*>(&sum_h_bf[b]) = p;
  } else {
    uint2 p = {pk(a0, a1), pk(a2, a3)};
    *reinterpret_cast<uint2*>(&cur_o_bf[b]) = p;
  }
}

// ---------------- GEMM core: 128x128 tile, BK=64, XOR-swizzled LDS ----------
struct GP {
  const u16* A; const u16* B; int K;
  const float* gadd; int ldg; const int* gidx;
  const float* bias; const float* zf; const float* shf;
  float* outf; u16* outh; int ldo;
};

template<int EP>
__device__ __forceinline__ void epi(int row, int col, float v, const GP& g) {
  if constexpr (EP == 0) {
    g.outf[(size_t)row * g.ldo + col] = v + (g.bias ? g.bias[col] : 0.f);
  } else if constexpr (EP == 1) {
    float pre = v + g.gadd[(size_t)g.gidx[row] * g.ldg + col];
    g.outf[(size_t)row * g.ldo + col] = 1.f / (1.f + __expf(-pre));
  } else if constexpr (EP == 2) {
    float pre = tanhf(v + g.gadd[(size_t)g.gidx[row] * g.ldg + col]);
    float z = g.zf[(size_t)row * HDIM + col];
    float sh = g.shf[(size_t)row * HDIM + col];
    g.outh[(size_t)row * g.ldo + col] = f2bu((1.f - z) * sh + z * pre);
  } else {
    float pre = v + g.gadd[(size_t)g.gidx[row] * g.ldg + col];
    g.outh[(size_t)row * g.ldo + col] = f2bu(pre > 0.f ? pre : 0.f);
  }
}

template<int EP>
__device__ void gemm_core(const GP& g, u16* As, u16* Bs) {
  const int tid = threadIdx.x, lane = tid & 63, w = tid >> 6;
  const int wm = (w >> 1) * 64, wn = (w & 1) * 64;
  const int m0 = blockIdx.x * 128, n0 = blockIdx.y * 128;
  const int K = g.K;
  f4v acc[4][4];
  f4v z4 = {0.f, 0.f, 0.f, 0.f};
#pragma unroll
  for (int a = 0; a < 4; a++)
#pragma unroll
    for (int b = 0; b < 4; b++) acc[a][b] = z4;

  for (int k0 = 0; k0 < K; k0 += 64) {
    __syncthreads();
#pragma unroll
    for (int i = 0; i < 4; i++) {
      int slot = tid + i * 256;
      int r = slot >> 3, c = (slot & 7) ^ (r & 7);
      gl16(&g.A[(size_t)(m0 + r) * K + k0 + c * 8], &As[slot * 8]);
    }
#pragma unroll
    for (int i = 0; i < 4; i++) {
      int slot = tid + i * 256;
      int r = slot >> 3, c = (slot & 7) ^ (r & 7);
      gl16(&g.B[(size_t)(n0 + r) * K + k0 + c * 8], &Bs[slot * 8]);
    }
    __syncthreads();
#pragma unroll
    for (int ks = 0; ks < 2; ks++) {
      s8v af[4], bf[4];
      int cc = ks * 4 + (lane >> 4);
#pragma unroll
      for (int i = 0; i < 4; i++) {
        int R = wm + i * 16 + (lane & 15);
        af[i] = *reinterpret_cast<const s8v*>(&As[R * 64 + (cc ^ (R & 7)) * 8]);
        int C = wn + i * 16 + (lane & 15);
        bf[i] = *reinterpret_cast<const s8v*>(&Bs[C * 64 + (cc ^ (C & 7)) * 8]);
      }
#pragma unroll
      for (int mi = 0; mi < 4; mi++)
#pragma unroll
        for (int ni = 0; ni < 4; ni++)
          acc[mi][ni] = __builtin_amdgcn_mfma_f32_16x16x32_bf16(
              af[mi], bf[ni], acc[mi][ni], 0, 0, 0);
    }
  }
#pragma unroll
  for (int mi = 0; mi < 4; mi++)
#pragma unroll
    for (int ni = 0; ni < 4; ni++)
#pragma unroll
      for (int r = 0; r < 4; r++) {
        int row = m0 + wm + mi * 16 + (lane >> 4) * 4 + r;
        int col = n0 + wn + ni * 16 + (lane & 15);
        epi<EP>(row, col, acc[mi][ni][r], g);
      }
}

template<int EP>
__global__ __launch_bounds__(256) void k_gemm(GP g) {
  __shared__ u16 As[128 * 64], Bs[128 * 64];
  gemm_core<EP>(g, As, Bs);
}

template<int EPa, int EPb>
__global__ __launch_bounds__(256) void k_pair(GP a, GP b) {
  __shared__ u16 As[128 * 64], Bs[128 * 64];
  if (blockIdx.z == 0) gemm_core<EPa>(a, As, Bs);
  else gemm_core<EPb>(b, As, Bs);
}

// ---------------- compacted r2: 128 rows x 256 cols, BK=64, swizzled -------
__global__ __launch_bounds__(512, 2) void k_r2c(
    const u16* __restrict__ Hb, const u16* __restrict__ Ur,
    const float* __restrict__ E_r, int ldg, const int* __restrict__ x_ids,
    const int* __restrict__ row_idx, const int* __restrict__ row_node,
    const int* __restrict__ mpad, float* __restrict__ sg_f) {
  const int row0 = blockIdx.x * 128;
  if (row0 >= mpad[0]) return;
  const int c0 = blockIdx.y * 256;
  const int tid = threadIdx.x, lane = tid & 63, w = tid >> 6;
  const int wrow = (w >> 2) * 64, wcol = (w & 3) * 64;
  __shared__ union SU {
    struct { u16 As[128 * 64]; u16 Bs[256 * 64]; } s;  // 16KB + 32KB
    u16 rvh[128 * 136];                                 // 34.8KB per half
  } u;
  __shared__ int s_idx[128], s_node[128], s_xid[128];
  if (tid < 128) {
    int nd = row_node[row0 + tid];
    s_idx[tid] = row_idx[row0 + tid];
    s_node[tid] = nd;
    s_xid[tid] = (nd < NNODE) ? x_ids[nd] : 0;
  }
  __syncthreads();

  f4v acc[4][4];
  f4v z4 = {0.f, 0.f, 0.f, 0.f};
#pragma unroll
  for (int a = 0; a < 4; a++)
#pragma unroll
    for (int b = 0; b < 4; b++) acc[a][b] = z4;

  for (int k0 = 0; k0 < HDIM; k0 += 64) {
    __syncthreads();
#pragma unroll
    for (int i = 0; i < 2; i++) {
      int slot = tid + i * 512;
      int r = slot >> 3, c = (slot & 7) ^ (r & 7);
      gl16(&Hb[(size_t)s_idx[r] * HDIM + k0 + c * 8], &u.s.As[slot * 8]);
    }
#pragma unroll
    for (int i = 0; i < 4; i++) {
      int slot = tid + i * 512;
      int r = slot >> 3, c = (slot & 7) ^ (r & 7);
      gl16(&Ur[(size_t)(c0 + r) * HDIM + k0 + c * 8], &u.s.Bs[slot * 8]);
    }
    __syncthreads();
#pragma unroll
    for (int ks = 0; ks < 2; ks++) {
      s8v af[4], bf[4];
      int cc = ks * 4 + (lane >> 4);
#pragma unroll
      for (int i = 0; i < 4; i++) {
        int R = wrow + i * 16 + (lane & 15);
        af[i] = *reinterpret_cast<const s8v*>(&u.s.As[R * 64 + (cc ^ (R & 7)) * 8]);
        int C = wcol + i * 16 + (lane & 15);
        bf[i] = *reinterpret_cast<const s8v*>(&u.s.Bs[C * 64 + (cc ^ (C & 7)) * 8]);
      }
#pragma unroll
      for (int mi = 0; mi < 4; mi++)
#pragma unroll
        for (int ni = 0; ni < 4; ni++)
          acc[mi][ni] = __builtin_amdgcn_mfma_f32_16x16x32_bf16(
              af[mi], bf[ni], acc[mi][ni], 0, 0, 0);
    }
  }

  // two 128-col halves: rv = sigmoid(r2 + E_r), rvh = rv*h -> LDS -> seg-reduce
#pragma unroll
  for (int half = 0; half < 2; half++) {
    __syncthreads();
    if ((wcol >> 7) == half) {
      int lc0 = wcol & 127;
#pragma unroll
      for (int mi = 0; mi < 4; mi++) {
#pragma unroll
        for (int r = 0; r < 4; r++) {
          int R = wrow + mi * 16 + (lane >> 4) * 4 + r;
          const float* erow = E_r + (size_t)s_xid[R] * ldg;
          const u16* hrow = Hb + (size_t)s_idx[R] * HDIM;
#pragma unroll
          for (int ni = 0; ni < 4; ni++) {
            int cl = ni * 16 + (lane & 15);
            int gcol = c0 + wcol + cl;
            float pre = acc[mi][ni][r] + erow[gcol];
            float rv = 1.f / (1.f + __expf(-pre));
            u.rvh[R * 136 + lc0 + cl] = f2bu(rv * bu2f(hrow[gcol]));
          }
        }
      }
    }
    __syncthreads();
    if (tid < 128) {
      int cglob = c0 + half * 128 + tid;
      float a = 0.f;
      int cur = s_node[0], segs = 0;
      for (int r = 0; r < 128; r++) {
        int nd = s_node[r];
        if (nd != cur) {
          float* p = &sg_f[(size_t)cur * HDIM + cglob];
          if (segs == 0) atomicAdd(p, a); else *p = a;
          cur = nd; a = 0.f; segs++;
        }
        a += bu2f(u.rvh[r * 136 + tid]);
      }
      atomicAdd(&sg_f[(size_t)cur * HDIM + cglob], a);
    }
  }
}

// ---------------- stop score ----------------
__global__ __launch_bounds__(256) void k_stop(
    const u16* __restrict__ shid, const float* __restrict__ Uo_w,
    const float* __restrict__ Uo_b, float* __restrict__ out) {
  int n = blockIdx.x * 4 + (threadIdx.x >> 6);
  int lane = threadIdx.x & 63;
  float s = 0.f;
  for (int j = lane; j < HDIM; j += 64)
    s += bu2f(shid[(size_t)n * HDIM + j]) * Uo_w[j];
#pragma unroll
  for (int off = 32; off; off >>= 1) s += __shfl_xor(s, off, 64);
  if (lane == 0) out[(size_t)n * 1025 + 1024] = s + Uo_b[0];
}

// ---------------- host ----------------
extern "C" void kernel_launch(void* const* d_in, const int* in_sizes, int n_in,
                              void* d_out, int out_size, void* d_ws, size_t ws_size,
                              hipStream_t stream) {
  const int* x_ids = (const int*)d_in[0];
  const int* contexts = (const int*)d_in[1];
  const int* nei_idx = (const int*)d_in[2];
  const int* nei_mask = (const int*)d_in[3];
  const int* o_idx = (const int*)d_in[4];
  const int* o_mask = (const int*)d_in[5];
  const float* H_msg = (const float*)d_in[6];
  const float* xtree = (const float*)d_in[7];
  const float* emb = (const float*)d_in[8];
  const float* Wz_w = (const float*)d_in[9];  const float* Wz_b = (const float*)d_in[10];
  const float* Wr_w = (const float*)d_in[11];
  const float* Ur_w = (const float*)d_in[13];
  const float* Wh_w = (const float*)d_in[14]; const float* Wh_b = (const float*)d_in[15];
  const float* W_w  = (const float*)d_in[16]; const float* W_b  = (const float*)d_in[17];
  const float* Wo_w = (const float*)d_in[18]; const float* Wo_b = (const float*)d_in[19];
  const float* Ui_w = (const float*)d_in[20]; const float* Ui_b = (const float*)d_in[21];
  const float* U_w  = (const float*)d_in[22]; const float* U_b  = (const float*)d_in[23];
  const float* Uo_w = (const float*)d_in[24]; const float* Uo_b = (const float*)d_in[25];
  const float* Wr_b = (const float*)d_in[12];
  float* out = (float*)d_out;
  const int M = 65536;

  char* base = (char*)d_ws;
  size_t ofs = 0;
  auto alloc = [&](size_t bytes) -> char* {
    char* p = base + ofs;
    ofs = (ofs + bytes + 255) & ~(size_t)255;
    return p;
  };
  u16* wcat  = (u16*)alloc((size_t)2048 * 512 * 2);
  u16* wz_h  = (u16*)alloc(512 * 512 * 2);
  u16* wh_h  = (u16*)alloc(512 * 512 * 2);
  u16* ui_h  = (u16*)alloc(512 * 512 * 2);
  u16* ur    = (u16*)alloc(512 * 512 * 2);
  u16* w_n   = (u16*)alloc(512 * 512 * 2);
  u16* u_n   = (u16*)alloc(512 * 512 * 2);
  u16* ccat  = (u16*)alloc(1024 * 128 * 2);
  u16* wo    = (u16*)alloc(1024 * 512 * 2);
  u16* emb_bf = (u16*)alloc(1024 * 512 * 2);
  u16* xt_bf  = (u16*)alloc(256 * 128 * 2);
  float* ebias = (float*)alloc(2048 * 4);
  float* cbias = (float*)alloc(1024 * 4);
  float* E_cat = (float*)alloc((size_t)1024 * 2048 * 4);
  float* C_cat = (float*)alloc((size_t)256 * 1024 * 4);
  u16* H_bf = (u16*)alloc((size_t)M * HDIM * 2);
  float* sum_h_f = (float*)alloc((size_t)NNODE * HDIM * 4);
  float* z_f     = (float*)alloc((size_t)NNODE * HDIM * 4);
  float* sg_f    = (float*)alloc((size_t)(NNODE + 1) * HDIM * 4);
  u16* sum_h_bf = (u16*)alloc((size_t)NNODE * HDIM * 2);
  u16* cur_o_bf = (u16*)alloc((size_t)NNODE * HDIM * 2);
  u16* sg_bf    = (u16*)alloc((size_t)NNODE * HDIM * 2);
  u16* newh_bf  = (u16*)alloc((size_t)NNODE * HDIM * 2);
  u16* whid_bf  = (u16*)alloc((size_t)NNODE * HDIM * 2);
  u16* stoph_bf = (u16*)alloc((size_t)NNODE * HDIM * 2);
  u16* shid_bf  = (u16*)alloc((size_t)NNODE * HDIM * 2);
  int* cnt      = (int*)alloc(NNODE * 4);
  int* rbase    = (int*)alloc(NNODE * 4);
  int* row_idx  = (int*)alloc((size_t)NNODE * NB * 4);
  int* row_node = (int*)alloc((size_t)NNODE * NB * 4);
  int* mpad     = (int*)alloc(256);

  hipMemsetAsync(sg_f, 0, (size_t)(NNODE + 1) * HDIM * 4, stream);

  k_cvt_all<<<dim3(256, 21), dim3(256), 0, stream>>>(
      Wz_w, Wr_w, Wh_w, Ui_w, Ur_w, W_w, U_w, Wo_w, emb, xtree,
      Wz_b, Wr_b, Wh_b, Ui_b, W_b, U_b,
      wcat, wz_h, wh_h, ui_h, ur, w_n, u_n, ccat, wo, emb_bf, xt_bf,
      ebias, cbias);
  k_cvt8<<<dim3(16384), dim3(256), 0, stream>>>(H_msg, H_bf);

  // E tables: [1024 x 2048] = emb @ [Wz_x|Wr|Wh_x|Ui_x]^T + [biases]
  GP ge{emb_bf, wcat, 512, nullptr, 0, nullptr, ebias, nullptr, nullptr,
        E_cat, nullptr, 2048};
  k_gemm<0><<<dim3(8, 16), dim3(256), 0, stream>>>(ge);
  // ctx tables: [256 x 1024] = xt @ [W_c|U_c]^T + [biases]
  GP gc{xt_bf, ccat, 128, nullptr, 0, nullptr, cbias, nullptr, nullptr,
        C_cat, nullptr, 1024};
  k_gemm<0><<<dim3(2, 8), dim3(256), 0, stream>>>(gc);

  k_cnt<<<dim3(NNODE / 256), dim3(256), 0, stream>>>(nei_mask, cnt);
  k_scan<<<dim3(1), dim3(1024), 0, stream>>>(cnt, rbase, mpad);
  k_fill<<<dim3(NNODE / 256), dim3(256), 0, stream>>>(
      nei_idx, nei_mask, rbase, row_idx, row_node, mpad);

  k_gather<<<dim3(NNODE), dim3(256), 0, stream>>>(
      H_bf, nei_idx, nei_mask, o_idx, o_mask, sum_h_f, sum_h_bf, cur_o_bf);

  // z (EP1) + stop_h (EP3) paired
  GP gz{sum_h_bf, wz_h, 512, E_cat, 2048, x_ids, nullptr, nullptr, nullptr,
        z_f, nullptr, 512};
  GP gs{cur_o_bf, ui_h, 512, E_cat + 1536, 2048, x_ids, nullptr, nullptr, nullptr,
        nullptr, stoph_bf, 512};
  k_pair<1, 3><<<dim3(128, 4, 2), dim3(256), 0, stream>>>(gz, gs);

  // compacted r2 + sigmoid + weighted neighbor sum
  k_r2c<<<dim3(NNODE * NB / 128, 2), dim3(512), 0, stream>>>(
      H_bf, ur, E_cat + 512, 2048, x_ids, row_idx, row_node, mpad, sg_f);
  k_cvt8<<<dim3(4096), dim3(256), 0, stream>>>(sg_f, sg_bf);

  // new_h (EP2)
  GP gn{sg_bf, wh_h, 512, E_cat + 1024, 2048, x_ids, nullptr, z_f, sum_h_f,
        nullptr, newh_bf, 512};
  k_gemm<2><<<dim3(128, 4), dim3(256), 0, stream>>>(gn);

  // w_hid + s_hid paired (both EP3)
  GP gw{newh_bf, w_n, 512, C_cat, 1024, contexts, nullptr, nullptr, nullptr,
        nullptr, whid_bf, 512};
  GP gu{stoph_bf, u_n, 512, C_cat + 512, 1024, contexts, nullptr, nullptr, nullptr,
        nullptr, shid_bf, 512};
  k_pair<3, 3><<<dim3(128, 4, 2), dim3(256), 0, stream>>>(gw, gu);

  // word scores -> out[:, 0:1024] (row stride 1025)
  GP gword{whid_bf, wo, 512, nullptr, 0, nullptr, Wo_b, nullptr, nullptr,
           out, nullptr, 1025};
  k_gemm<0><<<dim3(128, 8), dim3(256), 0, stream>>>(gword);

  k_stop<<<dim3(NNODE / 4), dim3(256), 0, stream>>>(shid_bf, Uo_w, Uo_b, out);
}

// Round 4
// 603.415 us; speedup vs baseline: 1.3779x; 1.1524x over previous
//
#include <hip/hip_runtime.h>
#include <hip/hip_bf16.h>

typedef unsigned short u16;
typedef unsigned int u32;
typedef __attribute__((ext_vector_type(8))) short s8v;
typedef __attribute__((ext_vector_type(4))) float f4v;

#define HDIM 512
#define NNODE 16384
#define NB 15
#define SENT NNODE

__device__ __forceinline__ u16 f2bu(float x) {
  union { float f; u32 i; } v; v.f = x;
  u32 r = v.i + 0x7FFFu + ((v.i >> 16) & 1u);
  return (u16)(r >> 16);
}
__device__ __forceinline__ float bu2f(u16 u) {
  union { u32 i; float f; } v; v.i = ((u32)u) << 16;
  return v.f;
}
__device__ __forceinline__ u32 pk(float a, float b) {
  return (u32)f2bu(a) | ((u32)f2bu(b) << 16);
}
__device__ __forceinline__ void gl16(const void* g, void* l) {
  __builtin_amdgcn_global_load_lds(
      (const __attribute__((address_space(1))) u32*)g,
      (__attribute__((address_space(3))) u32*)l, 16, 0, 0);
}

// ---------------- fused weight/bias conversion (21 segments) ----------------
__global__ __launch_bounds__(256) void k_cvt_all(
    const float* Wz_w, const float* Wr_w, const float* Wh_w, const float* Ui_w,
    const float* Ur_w, const float* W_w, const float* U_w, const float* Wo_w,
    const float* emb, const float* xtree,
    const float* Wz_b, const float* Wr_b, const float* Wh_b, const float* Ui_b,
    const float* W_b, const float* U_b,
    u16* wcat, u16* wz_h, u16* wh_h, u16* ui_h, u16* ur, u16* w_n, u16* u_n,
    u16* ccat, u16* wo, u16* emb_bf, u16* xt_bf, float* ebias, float* cbias) {
  int seg = blockIdx.y;
  const float* src = nullptr; u16* dst = nullptr;
  const float* fsrc = nullptr; float* fdst = nullptr;
  int R = 0, Cs = 0, c0 = 0, C = 0, fn = 0;
  switch (seg) {
    case 0:  src = Wz_w; dst = wcat;              R = 512;  Cs = 1024; c0 = 0;   C = 512; break;
    case 1:  src = Wr_w; dst = wcat + 512 * 512;  R = 512;  Cs = 512;  c0 = 0;   C = 512; break;
    case 2:  src = Wh_w; dst = wcat + 1024 * 512; R = 512;  Cs = 1024; c0 = 0;   C = 512; break;
    case 3:  src = Ui_w; dst = wcat + 1536 * 512; R = 512;  Cs = 1024; c0 = 0;   C = 512; break;
    case 4:  src = Wz_w; dst = wz_h;              R = 512;  Cs = 1024; c0 = 512; C = 512; break;
    case 5:  src = Wh_w; dst = wh_h;              R = 512;  Cs = 1024; c0 = 512; C = 512; break;
    case 6:  src = Ui_w; dst = ui_h;              R = 512;  Cs = 1024; c0 = 512; C = 512; break;
    case 7:  src = Ur_w; dst = ur;                R = 512;  Cs = 512;  c0 = 0;   C = 512; break;
    case 8:  src = W_w;  dst = w_n;               R = 512;  Cs = 640;  c0 = 0;   C = 512; break;
    case 9:  src = U_w;  dst = u_n;               R = 512;  Cs = 640;  c0 = 0;   C = 512; break;
    case 10: src = W_w;  dst = ccat;              R = 512;  Cs = 640;  c0 = 512; C = 128; break;
    case 11: src = U_w;  dst = ccat + 512 * 128;  R = 512;  Cs = 640;  c0 = 512; C = 128; break;
    case 12: src = Wo_w; dst = wo;                R = 1024; Cs = 512;  c0 = 0;   C = 512; break;
    case 13: src = emb;  dst = emb_bf;            R = 1024; Cs = 512;  c0 = 0;   C = 512; break;
    case 14: src = xtree; dst = xt_bf;            R = 256;  Cs = 128;  c0 = 0;   C = 128; break;
    case 15: fsrc = Wz_b; fdst = ebias;        fn = 512; break;
    case 16: fsrc = Wr_b; fdst = ebias + 512;  fn = 512; break;
    case 17: fsrc = Wh_b; fdst = ebias + 1024; fn = 512; break;
    case 18: fsrc = Ui_b; fdst = ebias + 1536; fn = 512; break;
    case 19: fsrc = W_b;  fdst = cbias;        fn = 512; break;
    case 20: fsrc = U_b;  fdst = cbias + 512;  fn = 512; break;
  }
  int i = blockIdx.x * 256 + threadIdx.x;
  if (fdst) { if (i < fn) fdst[i] = fsrc[i]; return; }
  int e0 = i * 8;
  if (e0 >= R * C) return;
  int r = e0 / C, c = e0 - r * C;
  const float* s = src + (size_t)r * Cs + c0 + c;
  float4 a = *reinterpret_cast<const float4*>(s);
  float4 b = *reinterpret_cast<const float4*>(s + 4);
  uint4 o = {pk(a.x, a.y), pk(a.z, a.w), pk(b.x, b.y), pk(b.z, b.w)};
  *reinterpret_cast<uint4*>(&dst[e0]) = o;
}

// ---------------- flat f32 -> bf16, 8 elems/thread ----------------
__global__ void k_cvt8(const float* __restrict__ src, u16* __restrict__ dst) {
  size_t i = ((size_t)blockIdx.x * 256 + threadIdx.x) * 8;
  float4 a = *reinterpret_cast<const float4*>(src + i);
  float4 b = *reinterpret_cast<const float4*>(src + i + 4);
  uint4 o = {pk(a.x, a.y), pk(a.z, a.w), pk(b.x, b.y), pk(b.z, b.w)};
  *reinterpret_cast<uint4*>(dst + i) = o;
}

// ---------------- compaction ----------------
__global__ void k_cnt(const int* __restrict__ nm, int* __restrict__ cnt) {
  int n = blockIdx.x * 256 + threadIdx.x;
  int c = 0;
  for (int s = 0; s < NB; s++) c += nm[(size_t)n * NB + s];
  cnt[n] = c;
}

__global__ __launch_bounds__(1024) void k_scan(const int* __restrict__ cnt,
                                               int* __restrict__ base,
                                               int* __restrict__ mpad) {
  __shared__ int part[1024];
  int t = threadIdx.x;
  int local[16];
  int s = 0;
  for (int j = 0; j < 16; j++) { local[j] = s; s += cnt[t * 16 + j]; }
  part[t] = s;
  __syncthreads();
  for (int d = 1; d < 1024; d <<= 1) {
    int v = (t >= d) ? part[t - d] : 0;
    __syncthreads();
    part[t] += v;
    __syncthreads();
  }
  int off = part[t] - s;
  for (int j = 0; j < 16; j++) base[t * 16 + j] = off + local[j];
  if (t == 1023) {
    mpad[0] = (part[1023] + 127) & ~127;
    mpad[1] = part[1023];
  }
}

__global__ void k_fill(const int* __restrict__ ni, const int* __restrict__ nm,
                       const int* __restrict__ base, int* __restrict__ row_idx,
                       int* __restrict__ row_node, const int* __restrict__ mpad) {
  int n = blockIdx.x * 256 + threadIdx.x;
  int b = base[n], j = 0;
  for (int s = 0; s < NB; s++) {
    if (nm[(size_t)n * NB + s]) {
      row_idx[b + j] = ni[(size_t)n * NB + s];
      row_node[b + j] = n;
      j++;
    }
  }
  if (blockIdx.x == 0 && threadIdx.x < 128) {
    int r = mpad[1] + threadIdx.x;
    if (r < mpad[0]) { row_idx[r] = 0; row_node[r] = SENT; }
  }
}

// ---------------- gather: half-block nei -> sum_h, half-block o -> cur_o ----
__global__ __launch_bounds__(256) void k_gather(
    const u16* __restrict__ Hb,
    const int* __restrict__ nei_idx, const int* __restrict__ nei_mask,
    const int* __restrict__ o_idx, const int* __restrict__ o_mask,
    float* __restrict__ sum_h_f, u16* __restrict__ sum_h_bf,
    u16* __restrict__ cur_o_bf) {
  int n = blockIdx.x;
  int t = threadIdx.x;
  int half = t >> 7, q = t & 127;  // q covers cols 4q..4q+3
  __shared__ int sidx[2][NB];
  __shared__ float smsk[2][NB];
  if (t < NB) {
    sidx[0][t] = nei_idx[(size_t)n * NB + t];
    smsk[0][t] = (float)nei_mask[(size_t)n * NB + t];
  } else if (t >= 128 && t < 128 + NB) {
    int k = t - 128;
    sidx[1][k] = o_idx[(size_t)n * NB + k];
    smsk[1][k] = (float)o_mask[(size_t)n * NB + k];
  }
  __syncthreads();
  float a0 = 0.f, a1 = 0.f, a2 = 0.f, a3 = 0.f;
#pragma unroll
  for (int k = 0; k < NB; k++) {
    if (smsk[half][k] != 0.f) {
      uint2 v = *reinterpret_cast<const uint2*>(Hb + (size_t)sidx[half][k] * HDIM + q * 4);
      a0 += bu2f((u16)v.x); a1 += bu2f((u16)(v.x >> 16));
      a2 += bu2f((u16)v.y); a3 += bu2f((u16)(v.y >> 16));
    }
  }
  size_t b = (size_t)n * HDIM + q * 4;
  if (half == 0) {
    *reinterpret_cast<float4*>(&sum_h_f[b]) = make_float4(a0, a1, a2, a3);
    uint2 p = {pk(a0, a1), pk(a2, a3)};
    *reinterpret_cast<uint2*>(&sum_h_bf[b]) = p;
  } else {
    uint2 p = {pk(a0, a1), pk(a2, a3)};
    *reinterpret_cast<uint2*>(&cur_o_bf[b]) = p;
  }
}

// ---------------- GEMM core: 128x128 tile, BK=64, XOR-swizzled LDS ----------
struct GP {
  const u16* A; const u16* B; int K;
  const float* gadd; int ldg; const int* gidx;
  const float* bias; const float* zf; const float* shf;
  float* outf; u16* outh; int ldo;
};

template<int EP>
__device__ __forceinline__ void epi(int row, int col, float v, const GP& g) {
  if constexpr (EP == 0) {
    g.outf[(size_t)row * g.ldo + col] = v + (g.bias ? g.bias[col] : 0.f);
  } else if constexpr (EP == 1) {
    float pre = v + g.gadd[(size_t)g.gidx[row] * g.ldg + col];
    g.outf[(size_t)row * g.ldo + col] = 1.f / (1.f + __expf(-pre));
  } else if constexpr (EP == 2) {
    float pre = tanhf(v + g.gadd[(size_t)g.gidx[row] * g.ldg + col]);
    float z = g.zf[(size_t)row * HDIM + col];
    float sh = g.shf[(size_t)row * HDIM + col];
    g.outh[(size_t)row * g.ldo + col] = f2bu((1.f - z) * sh + z * pre);
  } else {
    float pre = v + g.gadd[(size_t)g.gidx[row] * g.ldg + col];
    g.outh[(size_t)row * g.ldo + col] = f2bu(pre > 0.f ? pre : 0.f);
  }
}

template<int EP>
__device__ void gemm_core(const GP& g, u16* As, u16* Bs) {
  const int tid = threadIdx.x, lane = tid & 63, w = tid >> 6;
  const int wm = (w >> 1) * 64, wn = (w & 1) * 64;
  const int m0 = blockIdx.x * 128, n0 = blockIdx.y * 128;
  const int K = g.K;
  f4v acc[4][4];
  f4v z4 = {0.f, 0.f, 0.f, 0.f};
#pragma unroll
  for (int a = 0; a < 4; a++)
#pragma unroll
    for (int b = 0; b < 4; b++) acc[a][b] = z4;

  for (int k0 = 0; k0 < K; k0 += 64) {
    __syncthreads();
#pragma unroll
    for (int i = 0; i < 4; i++) {
      int slot = tid + i * 256;
      int r = slot >> 3, c = (slot & 7) ^ (r & 7);
      gl16(&g.A[(size_t)(m0 + r) * K + k0 + c * 8], &As[slot * 8]);
    }
#pragma unroll
    for (int i = 0; i < 4; i++) {
      int slot = tid + i * 256;
      int r = slot >> 3, c = (slot & 7) ^ (r & 7);
      gl16(&g.B[(size_t)(n0 + r) * K + k0 + c * 8], &Bs[slot * 8]);
    }
    __syncthreads();
#pragma unroll
    for (int ks = 0; ks < 2; ks++) {
      s8v af[4], bf[4];
      int cc = ks * 4 + (lane >> 4);
#pragma unroll
      for (int i = 0; i < 4; i++) {
        int R = wm + i * 16 + (lane & 15);
        af[i] = *reinterpret_cast<const s8v*>(&As[R * 64 + (cc ^ (R & 7)) * 8]);
        int C = wn + i * 16 + (lane & 15);
        bf[i] = *reinterpret_cast<const s8v*>(&Bs[C * 64 + (cc ^ (C & 7)) * 8]);
      }
#pragma unroll
      for (int mi = 0; mi < 4; mi++)
#pragma unroll
        for (int ni = 0; ni < 4; ni++)
          acc[mi][ni] = __builtin_amdgcn_mfma_f32_16x16x32_bf16(
              af[mi], bf[ni], acc[mi][ni], 0, 0, 0);
    }
  }
#pragma unroll
  for (int mi = 0; mi < 4; mi++)
#pragma unroll
    for (int ni = 0; ni < 4; ni++)
#pragma unroll
      for (int r = 0; r < 4; r++) {
        int row = m0 + wm + mi * 16 + (lane >> 4) * 4 + r;
        int col = n0 + wn + ni * 16 + (lane & 15);
        epi<EP>(row, col, acc[mi][ni][r], g);
      }
}

template<int EP>
__global__ __launch_bounds__(256) void k_gemm(GP g) {
  __shared__ u16 As[128 * 64], Bs[128 * 64];
  gemm_core<EP>(g, As, Bs);
}

template<int EPa, int EPb>
__global__ __launch_bounds__(256) void k_pair(GP a, GP b) {
  __shared__ u16 As[128 * 64], Bs[128 * 64];
  if (blockIdx.z == 0) gemm_core<EPa>(a, As, Bs);
  else gemm_core<EPb>(b, As, Bs);
}

// ---------------- compacted r2: 128 rows x 128 cols, BK=64, swizzled -------
// 8 waves; wave w owns rows w*16..w*16+15 x all 128 cols (acc[8] = 32 VGPR).
// LDS union ~36.4KB -> 4 blocks/CU.
__global__ __launch_bounds__(512, 2) void k_r2c(
    const u16* __restrict__ Hb, const u16* __restrict__ Ur,
    const float* __restrict__ E_r, int ldg, const int* __restrict__ x_ids,
    const int* __restrict__ row_idx, const int* __restrict__ row_node,
    const int* __restrict__ mpad, float* __restrict__ sg_f) {
  const int row0 = blockIdx.x * 128;
  if (row0 >= mpad[0]) return;
  const int c0 = blockIdx.y * 128;
  const int tid = threadIdx.x, lane = tid & 63, w = tid >> 6;
  __shared__ union SU {
    struct { u16 As[128 * 64]; u16 Bs[128 * 64]; } s;  // 16KB + 16KB
    u16 rvh[128 * 136];                                 // 34.8KB
  } u;
  __shared__ int s_idx[128], s_node[128], s_xid[128];
  if (tid < 128) {
    int nd = row_node[row0 + tid];
    s_idx[tid] = row_idx[row0 + tid];
    s_node[tid] = nd;
    s_xid[tid] = (nd < NNODE) ? x_ids[nd] : 0;
  }
  __syncthreads();

  // hoisted staging pointers (each thread stages 2 A-slots + 2 B-slots / iter)
  const int ra = tid >> 3, ca = (tid & 7) ^ (ra & 7);
  const int rb = (tid + 512) >> 3, cb = ((tid + 512) & 7) ^ (rb & 7);
  const u16* gA0 = Hb + (size_t)s_idx[ra] * HDIM + ca * 8;
  const u16* gA1 = Hb + (size_t)s_idx[rb] * HDIM + cb * 8;
  const u16* gB0 = Ur + (size_t)(c0 + ra) * HDIM + ca * 8;
  const u16* gB1 = Ur + (size_t)(c0 + rb) * HDIM + cb * 8;
  u16* lA0 = &u.s.As[tid * 8];
  u16* lA1 = &u.s.As[(tid + 512) * 8];
  u16* lB0 = &u.s.Bs[tid * 8];
  u16* lB1 = &u.s.Bs[(tid + 512) * 8];

  f4v acc[8];
  f4v z4 = {0.f, 0.f, 0.f, 0.f};
#pragma unroll
  for (int i = 0; i < 8; i++) acc[i] = z4;

  for (int k0 = 0; k0 < HDIM; k0 += 64) {
    __syncthreads();
    gl16(gA0 + k0, lA0);
    gl16(gA1 + k0, lA1);
    gl16(gB0 + k0, lB0);
    gl16(gB1 + k0, lB1);
    __syncthreads();
#pragma unroll
    for (int ks = 0; ks < 2; ks++) {
      int cc = ks * 4 + (lane >> 4);
      int R = (w << 4) + (lane & 15);
      s8v af = *reinterpret_cast<const s8v*>(
          &u.s.As[R * 64 + (cc ^ (R & 7)) * 8]);
#pragma unroll
      for (int cf = 0; cf < 8; cf++) {
        int C = (cf << 4) + (lane & 15);
        s8v bf = *reinterpret_cast<const s8v*>(
            &u.s.Bs[C * 64 + (cc ^ (C & 7)) * 8]);
        acc[cf] = __builtin_amdgcn_mfma_f32_16x16x32_bf16(af, bf, acc[cf], 0, 0, 0);
      }
    }
  }
  __syncthreads();  // As/Bs dead; rvh takes over the union

  // epilogue: rv = sigmoid(r2 + E_r[xid]); rvh = bf16(rv * h) -> LDS
  const int rbase2 = (w << 4) + ((lane >> 4) << 2);
#pragma unroll
  for (int r = 0; r < 4; r++) {
    int lr = rbase2 + r;
    const float* erow = E_r + (size_t)s_xid[lr] * ldg + c0;
    const u16* hrow = Hb + (size_t)s_idx[lr] * HDIM + c0;
#pragma unroll
    for (int cf = 0; cf < 8; cf++) {
      int cl = (cf << 4) + (lane & 15);
      float pre = acc[cf][r] + erow[cl];
      float rv = 1.f / (1.f + __expf(-pre));
      u.rvh[lr * 136 + cl] = f2bu(rv * bu2f(hrow[cl]));
    }
  }
  __syncthreads();

  // ownership-based segmented reduce: 4 chunks x 128 cols = 512 threads.
  // Each segment (node-contiguous rows, <=15 long) is summed entirely by the
  // thread whose 32-row chunk contains its start row -> single writer.
  // Only block-edge segments (s==0 or r==128) use atomicAdd; <=2 contributors
  // per (node,col) -> a+b commutative -> bitwise-deterministic.
  {
    int k = tid >> 7, c = tid & 127;
    int r = k * 32, rend = r + 32;
    if (r > 0) {
      int pn = s_node[r - 1];
      while (r < rend && s_node[r] == pn) r++;  // skip rows owned by prev chunk
    }
    while (r < rend) {
      int nd = s_node[r];
      int s = r;
      float a = 0.f;
      while (r < 128 && s_node[r] == nd) { a += bu2f(u.rvh[r * 136 + c]); r++; }
      float* p = &sg_f[(size_t)nd * HDIM + c0 + c];
      if (s == 0 || r == 128) atomicAdd(p, a);
      else *p = a;
    }
  }
}

// ---------------- stop score ----------------
__global__ __launch_bounds__(256) void k_stop(
    const u16* __restrict__ shid, const float* __restrict__ Uo_w,
    const float* __restrict__ Uo_b, float* __restrict__ out) {
  int n = blockIdx.x * 4 + (threadIdx.x >> 6);
  int lane = threadIdx.x & 63;
  float s = 0.f;
  for (int j = lane; j < HDIM; j += 64)
    s += bu2f(shid[(size_t)n * HDIM + j]) * Uo_w[j];
#pragma unroll
  for (int off = 32; off; off >>= 1) s += __shfl_xor(s, off, 64);
  if (lane == 0) out[(size_t)n * 1025 + 1024] = s + Uo_b[0];
}

// ---------------- host ----------------
extern "C" void kernel_launch(void* const* d_in, const int* in_sizes, int n_in,
                              void* d_out, int out_size, void* d_ws, size_t ws_size,
                              hipStream_t stream) {
  const int* x_ids = (const int*)d_in[0];
  const int* contexts = (const int*)d_in[1];
  const int* nei_idx = (const int*)d_in[2];
  const int* nei_mask = (const int*)d_in[3];
  const int* o_idx = (const int*)d_in[4];
  const int* o_mask = (const int*)d_in[5];
  const float* H_msg = (const float*)d_in[6];
  const float* xtree = (const float*)d_in[7];
  const float* emb = (const float*)d_in[8];
  const float* Wz_w = (const float*)d_in[9];  const float* Wz_b = (const float*)d_in[10];
  const float* Wr_w = (const float*)d_in[11];
  const float* Ur_w = (const float*)d_in[13];
  const float* Wh_w = (const float*)d_in[14]; const float* Wh_b = (const float*)d_in[15];
  const float* W_w  = (const float*)d_in[16]; const float* W_b  = (const float*)d_in[17];
  const float* Wo_w = (const float*)d_in[18]; const float* Wo_b = (const float*)d_in[19];
  const float* Ui_w = (const float*)d_in[20]; const float* Ui_b = (const float*)d_in[21];
  const float* U_w  = (const float*)d_in[22]; const float* U_b  = (const float*)d_in[23];
  const float* Uo_w = (const float*)d_in[24]; const float* Uo_b = (const float*)d_in[25];
  const float* Wr_b = (const float*)d_in[12];
  float* out = (float*)d_out;
  const int M = 65536;

  char* base = (char*)d_ws;
  size_t ofs = 0;
  auto alloc = [&](size_t bytes) -> char* {
    char* p = base + ofs;
    ofs = (ofs + bytes + 255) & ~(size_t)255;
    return p;
  };
  u16* wcat  = (u16*)alloc((size_t)2048 * 512 * 2);
  u16* wz_h  = (u16*)alloc(512 * 512 * 2);
  u16* wh_h  = (u16*)alloc(512 * 512 * 2);
  u16* ui_h  = (u16*)alloc(512 * 512 * 2);
  u16* ur    = (u16*)alloc(512 * 512 * 2);
  u16* w_n   = (u16*)alloc(512 * 512 * 2);
  u16* u_n   = (u16*)alloc(512 * 512 * 2);
  u16* ccat  = (u16*)alloc(1024 * 128 * 2);
  u16* wo    = (u16*)alloc(1024 * 512 * 2);
  u16* emb_bf = (u16*)alloc(1024 * 512 * 2);
  u16* xt_bf  = (u16*)alloc(256 * 128 * 2);
  float* ebias = (float*)alloc(2048 * 4);
  float* cbias = (float*)alloc(1024 * 4);
  float* E_cat = (float*)alloc((size_t)1024 * 2048 * 4);
  float* C_cat = (float*)alloc((size_t)256 * 1024 * 4);
  u16* H_bf = (u16*)alloc((size_t)M * HDIM * 2);
  float* sum_h_f = (float*)alloc((size_t)NNODE * HDIM * 4);
  float* z_f     = (float*)alloc((size_t)NNODE * HDIM * 4);
  float* sg_f    = (float*)alloc((size_t)(NNODE + 1) * HDIM * 4);
  u16* sum_h_bf = (u16*)alloc((size_t)NNODE * HDIM * 2);
  u16* cur_o_bf = (u16*)alloc((size_t)NNODE * HDIM * 2);
  u16* sg_bf    = (u16*)alloc((size_t)NNODE * HDIM * 2);
  u16* newh_bf  = (u16*)alloc((size_t)NNODE * HDIM * 2);
  u16* whid_bf  = (u16*)alloc((size_t)NNODE * HDIM * 2);
  u16* stoph_bf = (u16*)alloc((size_t)NNODE * HDIM * 2);
  u16* shid_bf  = (u16*)alloc((size_t)NNODE * HDIM * 2);
  int* cnt      = (int*)alloc(NNODE * 4);
  int* rbase    = (int*)alloc(NNODE * 4);
  int* row_idx  = (int*)alloc((size_t)NNODE * NB * 4);
  int* row_node = (int*)alloc((size_t)NNODE * NB * 4);
  int* mpad     = (int*)alloc(256);

  hipMemsetAsync(sg_f, 0, (size_t)(NNODE + 1) * HDIM * 4, stream);

  k_cvt_all<<<dim3(256, 21), dim3(256), 0, stream>>>(
      Wz_w, Wr_w, Wh_w, Ui_w, Ur_w, W_w, U_w, Wo_w, emb, xtree,
      Wz_b, Wr_b, Wh_b, Ui_b, W_b, U_b,
      wcat, wz_h, wh_h, ui_h, ur, w_n, u_n, ccat, wo, emb_bf, xt_bf,
      ebias, cbias);
  k_cvt8<<<dim3(16384), dim3(256), 0, stream>>>(H_msg, H_bf);

  // E tables: [1024 x 2048] = emb @ [Wz_x|Wr|Wh_x|Ui_x]^T + [biases]
  GP ge{emb_bf, wcat, 512, nullptr, 0, nullptr, ebias, nullptr, nullptr,
        E_cat, nullptr, 2048};
  k_gemm<0><<<dim3(8, 16), dim3(256), 0, stream>>>(ge);
  // ctx tables: [256 x 1024] = xt @ [W_c|U_c]^T + [biases]
  GP gc{xt_bf, ccat, 128, nullptr, 0, nullptr, cbias, nullptr, nullptr,
        C_cat, nullptr, 1024};
  k_gemm<0><<<dim3(2, 8), dim3(256), 0, stream>>>(gc);

  k_cnt<<<dim3(NNODE / 256), dim3(256), 0, stream>>>(nei_mask, cnt);
  k_scan<<<dim3(1), dim3(1024), 0, stream>>>(cnt, rbase, mpad);
  k_fill<<<dim3(NNODE / 256), dim3(256), 0, stream>>>(
      nei_idx, nei_mask, rbase, row_idx, row_node, mpad);

  k_gather<<<dim3(NNODE), dim3(256), 0, stream>>>(
      H_bf, nei_idx, nei_mask, o_idx, o_mask, sum_h_f, sum_h_bf, cur_o_bf);

  // z (EP1) + stop_h (EP3) paired
  GP gz{sum_h_bf, wz_h, 512, E_cat, 2048, x_ids, nullptr, nullptr, nullptr,
        z_f, nullptr, 512};
  GP gs{cur_o_bf, ui_h, 512, E_cat + 1536, 2048, x_ids, nullptr, nullptr, nullptr,
        nullptr, stoph_bf, 512};
  k_pair<1, 3><<<dim3(128, 4, 2), dim3(256), 0, stream>>>(gz, gs);

  // compacted r2 + sigmoid + weighted neighbor sum
  k_r2c<<<dim3(NNODE * NB / 128, 4), dim3(512), 0, stream>>>(
      H_bf, ur, E_cat + 512, 2048, x_ids, row_idx, row_node, mpad, sg_f);
  k_cvt8<<<dim3(4096), dim3(256), 0, stream>>>(sg_f, sg_bf);

  // new_h (EP2)
  GP gn{sg_bf, wh_h, 512, E_cat + 1024, 2048, x_ids, nullptr, z_f, sum_h_f,
        nullptr, newh_bf, 512};
  k_gemm<2><<<dim3(128, 4), dim3(256), 0, stream>>>(gn);

  // w_hid + s_hid paired (both EP3)
  GP gw{newh_bf, w_n, 512, C_cat, 1024, contexts, nullptr, nullptr, nullptr,
        nullptr, whid_bf, 512};
  GP gu{stoph_bf, u_n, 512, C_cat + 512, 1024, contexts, nullptr, nullptr, nullptr,
        nullptr, shid_bf, 512};
  k_pair<3, 3><<<dim3(128, 4, 2), dim3(256), 0, stream>>>(gw, gu);

  // word scores -> out[:, 0:1024] (row stride 1025)
  GP gword{whid_bf, wo, 512, nullptr, 0, nullptr, Wo_b, nullptr, nullptr,
           out, nullptr, 1025};
  k_gemm<0><<<dim3(128, 8), dim3(256), 0, stream>>>(gword);

  k_stop<<<dim3(NNODE / 4), dim3(256), 0, stream>>>(shid_bf, Uo_w, Uo_b, out);
}

// Round 5
// 597.327 us; speedup vs baseline: 1.3919x; 1.0102x over previous
//
#include <hip/hip_runtime.h>
#include <hip/hip_bf16.h>

typedef unsigned short u16;
typedef unsigned int u32;
typedef __attribute__((ext_vector_type(8))) short s8v;
typedef __attribute__((ext_vector_type(4))) float f4v;

#define HDIM 512
#define NNODE 16384
#define NB 15
#define SENT NNODE

__device__ __forceinline__ u16 f2bu(float x) {
  union { float f; u32 i; } v; v.f = x;
  u32 r = v.i + 0x7FFFu + ((v.i >> 16) & 1u);
  return (u16)(r >> 16);
}
__device__ __forceinline__ float bu2f(u16 u) {
  union { u32 i; float f; } v; v.i = ((u32)u) << 16;
  return v.f;
}
__device__ __forceinline__ u32 pk(float a, float b) {
  return (u32)f2bu(a) | ((u32)f2bu(b) << 16);
}
__device__ __forceinline__ void gl16(const void* g, void* l) {
  __builtin_amdgcn_global_load_lds(
      (const __attribute__((address_space(1))) u32*)g,
      (__attribute__((address_space(3))) u32*)l, 16, 0, 0);
}

// ---------------- fused weight/bias conversion (21 segments) ----------------
__global__ __launch_bounds__(256) void k_cvt_all(
    const float* Wz_w, const float* Wr_w, const float* Wh_w, const float* Ui_w,
    const float* Ur_w, const float* W_w, const float* U_w, const float* Wo_w,
    const float* emb, const float* xtree,
    const float* Wz_b, const float* Wr_b, const float* Wh_b, const float* Ui_b,
    const float* W_b, const float* U_b,
    u16* wcat, u16* wz_h, u16* wh_h, u16* ui_h, u16* ur, u16* w_n, u16* u_n,
    u16* ccat, u16* wo, u16* emb_bf, u16* xt_bf, float* ebias, float* cbias) {
  int seg = blockIdx.y;
  const float* src = nullptr; u16* dst = nullptr;
  const float* fsrc = nullptr; float* fdst = nullptr;
  int R = 0, Cs = 0, c0 = 0, C = 0, fn = 0;
  switch (seg) {
    case 0:  src = Wz_w; dst = wcat;              R = 512;  Cs = 1024; c0 = 0;   C = 512; break;
    case 1:  src = Wr_w; dst = wcat + 512 * 512;  R = 512;  Cs = 512;  c0 = 0;   C = 512; break;
    case 2:  src = Wh_w; dst = wcat + 1024 * 512; R = 512;  Cs = 1024; c0 = 0;   C = 512; break;
    case 3:  src = Ui_w; dst = wcat + 1536 * 512; R = 512;  Cs = 1024; c0 = 0;   C = 512; break;
    case 4:  src = Wz_w; dst = wz_h;              R = 512;  Cs = 1024; c0 = 512; C = 512; break;
    case 5:  src = Wh_w; dst = wh_h;              R = 512;  Cs = 1024; c0 = 512; C = 512; break;
    case 6:  src = Ui_w; dst = ui_h;              R = 512;  Cs = 1024; c0 = 512; C = 512; break;
    case 7:  src = Ur_w; dst = ur;                R = 512;  Cs = 512;  c0 = 0;   C = 512; break;
    case 8:  src = W_w;  dst = w_n;               R = 512;  Cs = 640;  c0 = 0;   C = 512; break;
    case 9:  src = U_w;  dst = u_n;               R = 512;  Cs = 640;  c0 = 0;   C = 512; break;
    case 10: src = W_w;  dst = ccat;              R = 512;  Cs = 640;  c0 = 512; C = 128; break;
    case 11: src = U_w;  dst = ccat + 512 * 128;  R = 512;  Cs = 640;  c0 = 512; C = 128; break;
    case 12: src = Wo_w; dst = wo;                R = 1024; Cs = 512;  c0 = 0;   C = 512; break;
    case 13: src = emb;  dst = emb_bf;            R = 1024; Cs = 512;  c0 = 0;   C = 512; break;
    case 14: src = xtree; dst = xt_bf;            R = 256;  Cs = 128;  c0 = 0;   C = 128; break;
    case 15: fsrc = Wz_b; fdst = ebias;        fn = 512; break;
    case 16: fsrc = Wr_b; fdst = ebias + 512;  fn = 512; break;
    case 17: fsrc = Wh_b; fdst = ebias + 1024; fn = 512; break;
    case 18: fsrc = Ui_b; fdst = ebias + 1536; fn = 512; break;
    case 19: fsrc = W_b;  fdst = cbias;        fn = 512; break;
    case 20: fsrc = U_b;  fdst = cbias + 512;  fn = 512; break;
  }
  int i = blockIdx.x * 256 + threadIdx.x;
  if (fdst) { if (i < fn) fdst[i] = fsrc[i]; return; }
  int e0 = i * 8;
  if (e0 >= R * C) return;
  int r = e0 / C, c = e0 - r * C;
  const float* s = src + (size_t)r * Cs + c0 + c;
  float4 a = *reinterpret_cast<const float4*>(s);
  float4 b = *reinterpret_cast<const float4*>(s + 4);
  uint4 o = {pk(a.x, a.y), pk(a.z, a.w), pk(b.x, b.y), pk(b.z, b.w)};
  *reinterpret_cast<uint4*>(&dst[e0]) = o;
}

// ---------------- flat f32 -> bf16, 8 elems/thread ----------------
__global__ void k_cvt8(const float* __restrict__ src, u16* __restrict__ dst) {
  size_t i = ((size_t)blockIdx.x * 256 + threadIdx.x) * 8;
  float4 a = *reinterpret_cast<const float4*>(src + i);
  float4 b = *reinterpret_cast<const float4*>(src + i + 4);
  uint4 o = {pk(a.x, a.y), pk(a.z, a.w), pk(b.x, b.y), pk(b.z, b.w)};
  *reinterpret_cast<uint4*>(dst + i) = o;
}

// ---------------- compaction ----------------
__global__ void k_cnt(const int* __restrict__ nm, int* __restrict__ cnt) {
  int n = blockIdx.x * 256 + threadIdx.x;
  int c = 0;
  for (int s = 0; s < NB; s++) c += nm[(size_t)n * NB + s];
  cnt[n] = c;
}

__global__ __launch_bounds__(1024) void k_scan(const int* __restrict__ cnt,
                                               int* __restrict__ base,
                                               int* __restrict__ mpad) {
  __shared__ int part[1024];
  int t = threadIdx.x;
  int local[16];
  int s = 0;
  for (int j = 0; j < 16; j++) { local[j] = s; s += cnt[t * 16 + j]; }
  part[t] = s;
  __syncthreads();
  for (int d = 1; d < 1024; d <<= 1) {
    int v = (t >= d) ? part[t - d] : 0;
    __syncthreads();
    part[t] += v;
    __syncthreads();
  }
  int off = part[t] - s;
  for (int j = 0; j < 16; j++) base[t * 16 + j] = off + local[j];
  if (t == 1023) {
    mpad[0] = (part[1023] + 127) & ~127;
    mpad[1] = part[1023];
  }
}

__global__ void k_fill(const int* __restrict__ ni, const int* __restrict__ nm,
                       const int* __restrict__ base, int* __restrict__ row_idx,
                       int* __restrict__ row_node, const int* __restrict__ mpad) {
  int n = blockIdx.x * 256 + threadIdx.x;
  int b = base[n], j = 0;
  for (int s = 0; s < NB; s++) {
    if (nm[(size_t)n * NB + s]) {
      row_idx[b + j] = ni[(size_t)n * NB + s];
      row_node[b + j] = n;
      j++;
    }
  }
  if (blockIdx.x == 0 && threadIdx.x < 128) {
    int r = mpad[1] + threadIdx.x;
    if (r < mpad[0]) { row_idx[r] = 0; row_node[r] = SENT; }
  }
}

// ---------------- gather: half-block nei -> sum_h, half-block o -> cur_o ----
__global__ __launch_bounds__(256) void k_gather(
    const u16* __restrict__ Hb,
    const int* __restrict__ nei_idx, const int* __restrict__ nei_mask,
    const int* __restrict__ o_idx, const int* __restrict__ o_mask,
    u16* __restrict__ sum_h_bf, u16* __restrict__ cur_o_bf) {
  int n = blockIdx.x;
  int t = threadIdx.x;
  int half = t >> 7, q = t & 127;  // q covers cols 4q..4q+3
  __shared__ int sidx[2][NB];
  __shared__ float smsk[2][NB];
  if (t < NB) {
    sidx[0][t] = nei_idx[(size_t)n * NB + t];
    smsk[0][t] = (float)nei_mask[(size_t)n * NB + t];
  } else if (t >= 128 && t < 128 + NB) {
    int k = t - 128;
    sidx[1][k] = o_idx[(size_t)n * NB + k];
    smsk[1][k] = (float)o_mask[(size_t)n * NB + k];
  }
  __syncthreads();
  float a0 = 0.f, a1 = 0.f, a2 = 0.f, a3 = 0.f;
#pragma unroll
  for (int k = 0; k < NB; k++) {
    if (smsk[half][k] != 0.f) {
      uint2 v = *reinterpret_cast<const uint2*>(Hb + (size_t)sidx[half][k] * HDIM + q * 4);
      a0 += bu2f((u16)v.x); a1 += bu2f((u16)(v.x >> 16));
      a2 += bu2f((u16)v.y); a3 += bu2f((u16)(v.y >> 16));
    }
  }
  size_t b = (size_t)n * HDIM + q * 4;
  uint2 p = {pk(a0, a1), pk(a2, a3)};
  if (half == 0) *reinterpret_cast<uint2*>(&sum_h_bf[b]) = p;
  else           *reinterpret_cast<uint2*>(&cur_o_bf[b]) = p;
}

// ---------------- GEMM core: 128x128 tile, BK=64, XOR-swizzled LDS ----------
struct GP {
  const u16* A; const u16* B; int K;
  const float* gadd; int ldg; const int* gidx;
  const float* bias; const float* zf; const u16* shb;
  float* outf; u16* outh; int ldo;
};

template<int EP>
__device__ __forceinline__ void epi(int row, int col, float v, const GP& g) {
  if constexpr (EP == 0) {
    g.outf[(size_t)row * g.ldo + col] = v + (g.bias ? g.bias[col] : 0.f);
  } else if constexpr (EP == 1) {
    float pre = v + g.gadd[(size_t)g.gidx[row] * g.ldg + col];
    g.outf[(size_t)row * g.ldo + col] = 1.f / (1.f + __expf(-pre));
  } else if constexpr (EP == 2) {
    float pre = tanhf(v + g.gadd[(size_t)g.gidx[row] * g.ldg + col]);
    float z = g.zf[(size_t)row * HDIM + col];
    float sh = bu2f(g.shb[(size_t)row * HDIM + col]);
    g.outh[(size_t)row * g.ldo + col] = f2bu((1.f - z) * sh + z * pre);
  } else {
    float pre = v + g.gadd[(size_t)g.gidx[row] * g.ldg + col];
    g.outh[(size_t)row * g.ldo + col] = f2bu(pre > 0.f ? pre : 0.f);
  }
}

template<int EP>
__device__ void gemm_core(const GP& g, u16* As, u16* Bs) {
  const int tid = threadIdx.x, lane = tid & 63, w = tid >> 6;
  const int wm = (w >> 1) * 64, wn = (w & 1) * 64;
  const int m0 = blockIdx.x * 128, n0 = blockIdx.y * 128;
  const int K = g.K;
  f4v acc[4][4];
  f4v z4 = {0.f, 0.f, 0.f, 0.f};
#pragma unroll
  for (int a = 0; a < 4; a++)
#pragma unroll
    for (int b = 0; b < 4; b++) acc[a][b] = z4;

  for (int k0 = 0; k0 < K; k0 += 64) {
    __syncthreads();
#pragma unroll
    for (int i = 0; i < 4; i++) {
      int slot = tid + i * 256;
      int r = slot >> 3, c = (slot & 7) ^ (r & 7);
      gl16(&g.A[(size_t)(m0 + r) * K + k0 + c * 8], &As[slot * 8]);
    }
#pragma unroll
    for (int i = 0; i < 4; i++) {
      int slot = tid + i * 256;
      int r = slot >> 3, c = (slot & 7) ^ (r & 7);
      gl16(&g.B[(size_t)(n0 + r) * K + k0 + c * 8], &Bs[slot * 8]);
    }
    __syncthreads();
#pragma unroll
    for (int ks = 0; ks < 2; ks++) {
      s8v af[4], bf[4];
      int cc = ks * 4 + (lane >> 4);
#pragma unroll
      for (int i = 0; i < 4; i++) {
        int R = wm + i * 16 + (lane & 15);
        af[i] = *reinterpret_cast<const s8v*>(&As[R * 64 + (cc ^ (R & 7)) * 8]);
        int C = wn + i * 16 + (lane & 15);
        bf[i] = *reinterpret_cast<const s8v*>(&Bs[C * 64 + (cc ^ (C & 7)) * 8]);
      }
#pragma unroll
      for (int mi = 0; mi < 4; mi++)
#pragma unroll
        for (int ni = 0; ni < 4; ni++)
          acc[mi][ni] = __builtin_amdgcn_mfma_f32_16x16x32_bf16(
              af[mi], bf[ni], acc[mi][ni], 0, 0, 0);
    }
  }
#pragma unroll
  for (int mi = 0; mi < 4; mi++)
#pragma unroll
    for (int ni = 0; ni < 4; ni++)
#pragma unroll
      for (int r = 0; r < 4; r++) {
        int row = m0 + wm + mi * 16 + (lane >> 4) * 4 + r;
        int col = n0 + wn + ni * 16 + (lane & 15);
        epi<EP>(row, col, acc[mi][ni][r], g);
      }
}

template<int EP>
__global__ __launch_bounds__(256) void k_gemm(GP g) {
  __shared__ u16 As[128 * 64], Bs[128 * 64];
  gemm_core<EP>(g, As, Bs);
}

template<int EPa, int EPb>
__global__ __launch_bounds__(256) void k_pair(GP a, GP b) {
  __shared__ u16 As[128 * 64], Bs[128 * 64];
  if (blockIdx.z == 0) gemm_core<EPa>(a, As, Bs);
  else gemm_core<EPb>(b, As, Bs);
}

// ---------------- compacted r2: 128x128 tile, 4 waves of 64x64 --------------
// 0.5 ds_read per MFMA (vs 1.125 in the 16x128-wave layout) — LDS-port bound
// model: 64 reads/K-step/block. acc = 64 VGPR; LDS union 34.8KB -> 4 blk/CU.
__global__ __launch_bounds__(256, 4) void k_r2c(
    const u16* __restrict__ Hb, const u16* __restrict__ Ur,
    const float* __restrict__ E_r, int ldg, const int* __restrict__ x_ids,
    const int* __restrict__ row_idx, const int* __restrict__ row_node,
    const int* __restrict__ mpad, float* __restrict__ sg_f) {
  const int row0 = blockIdx.x * 128;
  if (row0 >= mpad[0]) return;
  const int c0 = blockIdx.y * 128;
  const int tid = threadIdx.x, lane = tid & 63, w = tid >> 6;
  const int wr = (w >> 1) * 64, wc = (w & 1) * 64;
  __shared__ union SU {
    struct { u16 As[128 * 64]; u16 Bs[128 * 64]; } s;  // 16KB + 16KB
    u16 rvh[128 * 136];                                 // 34.8KB
  } u;
  __shared__ int s_idx[128], s_node[128], s_xid[128];
  if (tid < 128) {
    int nd = row_node[row0 + tid];
    s_idx[tid] = row_idx[row0 + tid];
    s_node[tid] = nd;
    s_xid[tid] = (nd < NNODE) ? x_ids[nd] : 0;
  }
  __syncthreads();

  // hoisted staging pointers: 4 A-slots + 4 B-slots per thread per K-step
  const u16* gA[4]; const u16* gB[4];
  u16 *lA[4], *lB[4];
#pragma unroll
  for (int i = 0; i < 4; i++) {
    int slot = tid + i * 256;
    int r = slot >> 3, c = (slot & 7) ^ (r & 7);
    gA[i] = Hb + (size_t)s_idx[r] * HDIM + c * 8;
    gB[i] = Ur + (size_t)(c0 + r) * HDIM + c * 8;
    lA[i] = &u.s.As[slot * 8];
    lB[i] = &u.s.Bs[slot * 8];
  }

  f4v acc[4][4];
  f4v z4 = {0.f, 0.f, 0.f, 0.f};
#pragma unroll
  for (int a = 0; a < 4; a++)
#pragma unroll
    for (int b = 0; b < 4; b++) acc[a][b] = z4;

  for (int k0 = 0; k0 < HDIM; k0 += 64) {
    __syncthreads();
#pragma unroll
    for (int i = 0; i < 4; i++) gl16(gA[i] + k0, lA[i]);
#pragma unroll
    for (int i = 0; i < 4; i++) gl16(gB[i] + k0, lB[i]);
    __syncthreads();
#pragma unroll
    for (int ks = 0; ks < 2; ks++) {
      s8v af[4], bf[4];
      int cc = ks * 4 + (lane >> 4);
#pragma unroll
      for (int i = 0; i < 4; i++) {
        int R = wr + i * 16 + (lane & 15);
        af[i] = *reinterpret_cast<const s8v*>(&u.s.As[R * 64 + (cc ^ (R & 7)) * 8]);
        int C = wc + i * 16 + (lane & 15);
        bf[i] = *reinterpret_cast<const s8v*>(&u.s.Bs[C * 64 + (cc ^ (C & 7)) * 8]);
      }
#pragma unroll
      for (int mi = 0; mi < 4; mi++)
#pragma unroll
        for (int ni = 0; ni < 4; ni++)
          acc[mi][ni] = __builtin_amdgcn_mfma_f32_16x16x32_bf16(
              af[mi], bf[ni], acc[mi][ni], 0, 0, 0);
    }
  }
  __syncthreads();  // As/Bs dead; rvh takes over the union

  // epilogue: rv = sigmoid(r2 + E_r[xid]); rvh = bf16(rv * h) -> LDS
#pragma unroll
  for (int mi = 0; mi < 4; mi++) {
#pragma unroll
    for (int r = 0; r < 4; r++) {
      int lr = wr + mi * 16 + (lane >> 4) * 4 + r;
      const float* erow = E_r + (size_t)s_xid[lr] * ldg + c0;
      const u16* hrow = Hb + (size_t)s_idx[lr] * HDIM + c0;
#pragma unroll
      for (int ni = 0; ni < 4; ni++) {
        int cl = wc + ni * 16 + (lane & 15);
        float pre = acc[mi][ni][r] + erow[cl];
        float rv = 1.f / (1.f + __expf(-pre));
        u.rvh[lr * 136 + cl] = f2bu(rv * bu2f(hrow[cl]));
      }
    }
  }
  __syncthreads();

  // ownership-based segmented reduce: 2 chunks x 128 cols = 256 threads.
  // Segment (node-contiguous rows, <=15 long) summed by the thread whose
  // 64-row chunk contains its start -> single writer, plain store; block-edge
  // segments use atomicAdd (<=2 contributors -> bitwise-deterministic).
  {
    int k = tid >> 7, c = tid & 127;
    int r = k * 64, rend = r + 64;
    if (r > 0) {
      int pn = s_node[r - 1];
      while (r < rend && s_node[r] == pn) r++;  // rows owned by prev chunk
    }
    while (r < rend) {
      int nd = s_node[r];
      int s = r;
      float a = 0.f;
      while (r < 128 && s_node[r] == nd) { a += bu2f(u.rvh[r * 136 + c]); r++; }
      float* p = &sg_f[(size_t)nd * HDIM + c0 + c];
      if (s == 0 || r == 128) atomicAdd(p, a);
      else *p = a;
    }
  }
}

// ---------------- stop score ----------------
__global__ __launch_bounds__(256) void k_stop(
    const u16* __restrict__ shid, const float* __restrict__ Uo_w,
    const float* __restrict__ Uo_b, float* __restrict__ out) {
  int n = blockIdx.x * 4 + (threadIdx.x >> 6);
  int lane = threadIdx.x & 63;
  float s = 0.f;
  for (int j = lane; j < HDIM; j += 64)
    s += bu2f(shid[(size_t)n * HDIM + j]) * Uo_w[j];
#pragma unroll
  for (int off = 32; off; off >>= 1) s += __shfl_xor(s, off, 64);
  if (lane == 0) out[(size_t)n * 1025 + 1024] = s + Uo_b[0];
}

// ---------------- host ----------------
extern "C" void kernel_launch(void* const* d_in, const int* in_sizes, int n_in,
                              void* d_out, int out_size, void* d_ws, size_t ws_size,
                              hipStream_t stream) {
  const int* x_ids = (const int*)d_in[0];
  const int* contexts = (const int*)d_in[1];
  const int* nei_idx = (const int*)d_in[2];
  const int* nei_mask = (const int*)d_in[3];
  const int* o_idx = (const int*)d_in[4];
  const int* o_mask = (const int*)d_in[5];
  const float* H_msg = (const float*)d_in[6];
  const float* xtree = (const float*)d_in[7];
  const float* emb = (const float*)d_in[8];
  const float* Wz_w = (const float*)d_in[9];  const float* Wz_b = (const float*)d_in[10];
  const float* Wr_w = (const float*)d_in[11]; const float* Wr_b = (const float*)d_in[12];
  const float* Ur_w = (const float*)d_in[13];
  const float* Wh_w = (const float*)d_in[14]; const float* Wh_b = (const float*)d_in[15];
  const float* W_w  = (const float*)d_in[16]; const float* W_b  = (const float*)d_in[17];
  const float* Wo_w = (const float*)d_in[18]; const float* Wo_b = (const float*)d_in[19];
  const float* Ui_w = (const float*)d_in[20]; const float* Ui_b = (const float*)d_in[21];
  const float* U_w  = (const float*)d_in[22]; const float* U_b  = (const float*)d_in[23];
  const float* Uo_w = (const float*)d_in[24]; const float* Uo_b = (const float*)d_in[25];
  float* out = (float*)d_out;
  const int M = 65536;

  char* base = (char*)d_ws;
  size_t ofs = 0;
  auto alloc = [&](size_t bytes) -> char* {
    char* p = base + ofs;
    ofs = (ofs + bytes + 255) & ~(size_t)255;
    return p;
  };
  u16* wcat  = (u16*)alloc((size_t)2048 * 512 * 2);
  u16* wz_h  = (u16*)alloc(512 * 512 * 2);
  u16* wh_h  = (u16*)alloc(512 * 512 * 2);
  u16* ui_h  = (u16*)alloc(512 * 512 * 2);
  u16* ur    = (u16*)alloc(512 * 512 * 2);
  u16* w_n   = (u16*)alloc(512 * 512 * 2);
  u16* u_n   = (u16*)alloc(512 * 512 * 2);
  u16* ccat  = (u16*)alloc(1024 * 128 * 2);
  u16* wo    = (u16*)alloc(1024 * 512 * 2);
  u16* emb_bf = (u16*)alloc(1024 * 512 * 2);
  u16* xt_bf  = (u16*)alloc(256 * 128 * 2);
  float* ebias = (float*)alloc(2048 * 4);
  float* cbias = (float*)alloc(1024 * 4);
  float* E_cat = (float*)alloc((size_t)1024 * 2048 * 4);
  float* C_cat = (float*)alloc((size_t)256 * 1024 * 4);
  u16* H_bf = (u16*)alloc((size_t)M * HDIM * 2);
  float* z_f     = (float*)alloc((size_t)NNODE * HDIM * 4);
  float* sg_f    = (float*)alloc((size_t)(NNODE + 1) * HDIM * 4);
  u16* sum_h_bf = (u16*)alloc((size_t)NNODE * HDIM * 2);
  u16* cur_o_bf = (u16*)alloc((size_t)NNODE * HDIM * 2);
  u16* sg_bf    = (u16*)alloc((size_t)NNODE * HDIM * 2);
  u16* newh_bf  = (u16*)alloc((size_t)NNODE * HDIM * 2);
  u16* whid_bf  = (u16*)alloc((size_t)NNODE * HDIM * 2);
  u16* stoph_bf = (u16*)alloc((size_t)NNODE * HDIM * 2);
  u16* shid_bf  = (u16*)alloc((size_t)NNODE * HDIM * 2);
  int* cnt      = (int*)alloc(NNODE * 4);
  int* rbase    = (int*)alloc(NNODE * 4);
  int* row_idx  = (int*)alloc((size_t)NNODE * NB * 4);
  int* row_node = (int*)alloc((size_t)NNODE * NB * 4);
  int* mpad     = (int*)alloc(256);

  hipMemsetAsync(sg_f, 0, (size_t)(NNODE + 1) * HDIM * 4, stream);

  k_cvt_all<<<dim3(256, 21), dim3(256), 0, stream>>>(
      Wz_w, Wr_w, Wh_w, Ui_w, Ur_w, W_w, U_w, Wo_w, emb, xtree,
      Wz_b, Wr_b, Wh_b, Ui_b, W_b, U_b,
      wcat, wz_h, wh_h, ui_h, ur, w_n, u_n, ccat, wo, emb_bf, xt_bf,
      ebias, cbias);
  k_cvt8<<<dim3(16384), dim3(256), 0, stream>>>(H_msg, H_bf);

  // E tables: [1024 x 2048] = emb @ [Wz_x|Wr|Wh_x|Ui_x]^T + [biases]
  GP ge{emb_bf, wcat, 512, nullptr, 0, nullptr, ebias, nullptr, nullptr,
        E_cat, nullptr, 2048};
  k_gemm<0><<<dim3(8, 16), dim3(256), 0, stream>>>(ge);
  // ctx tables: [256 x 1024] = xt @ [W_c|U_c]^T + [biases]
  GP gc{xt_bf, ccat, 128, nullptr, 0, nullptr, cbias, nullptr, nullptr,
        C_cat, nullptr, 1024};
  k_gemm<0><<<dim3(2, 8), dim3(256), 0, stream>>>(gc);

  k_cnt<<<dim3(NNODE / 256), dim3(256), 0, stream>>>(nei_mask, cnt);
  k_scan<<<dim3(1), dim3(1024), 0, stream>>>(cnt, rbase, mpad);
  k_fill<<<dim3(NNODE / 256), dim3(256), 0, stream>>>(
      nei_idx, nei_mask, rbase, row_idx, row_node, mpad);

  k_gather<<<dim3(NNODE), dim3(256), 0, stream>>>(
      H_bf, nei_idx, nei_mask, o_idx, o_mask, sum_h_bf, cur_o_bf);

  // z (EP1) + stop_h (EP3) paired
  GP gz{sum_h_bf, wz_h, 512, E_cat, 2048, x_ids, nullptr, nullptr, nullptr,
        z_f, nullptr, 512};
  GP gs{cur_o_bf, ui_h, 512, E_cat + 1536, 2048, x_ids, nullptr, nullptr, nullptr,
        nullptr, stoph_bf, 512};
  k_pair<1, 3><<<dim3(128, 4, 2), dim3(256), 0, stream>>>(gz, gs);

  // compacted r2 + sigmoid + weighted neighbor sum
  k_r2c<<<dim3(NNODE * NB / 128, 4), dim3(256), 0, stream>>>(
      H_bf, ur, E_cat + 512, 2048, x_ids, row_idx, row_node, mpad, sg_f);
  k_cvt8<<<dim3(4096), dim3(256), 0, stream>>>(sg_f, sg_bf);

  // new_h (EP2): (1-z)*sum_h + z*tanh(sg @ Wh_h^T + E_h[x_ids])
  GP gn{sg_bf, wh_h, 512, E_cat + 1024, 2048, x_ids, nullptr, z_f, sum_h_bf,
        nullptr, newh_bf, 512};
  k_gemm<2><<<dim3(128, 4), dim3(256), 0, stream>>>(gn);

  // w_hid + s_hid paired (both EP3)
  GP gw{newh_bf, w_n, 512, C_cat, 1024, contexts, nullptr, nullptr, nullptr,
        nullptr, whid_bf, 512};
  GP gu{stoph_bf, u_n, 512, C_cat + 512, 1024, contexts, nullptr, nullptr, nullptr,
        nullptr, shid_bf, 512};
  k_pair<3, 3><<<dim3(128, 4, 2), dim3(256), 0, stream>>>(gw, gu);

  // word scores -> out[:, 0:1024] (row stride 1025)
  GP gword{whid_bf, wo, 512, nullptr, 0, nullptr, Wo_b, nullptr, nullptr,
           out, nullptr, 1025};
  k_gemm<0><<<dim3(128, 8), dim3(256), 0, stream>>>(gword);

  k_stop<<<dim3(NNODE / 4), dim3(256), 0, stream>>>(shid_bf, Uo_w, Uo_b, out);
}

// Round 6
// 481.545 us; speedup vs baseline: 1.7266x; 1.2404x over previous
//
#include <hip/hip_runtime.h>
#include <hip/hip_bf16.h>

typedef unsigned short u16;
typedef unsigned int u32;
typedef __attribute__((ext_vector_type(8))) short s8v;
typedef __attribute__((ext_vector_type(4))) float f4v;

#define HDIM 512
#define NNODE 16384
#define NB 15

__device__ __forceinline__ u16 f2bu(float x) {
  union { float f; u32 i; } v; v.f = x;
  u32 r = v.i + 0x7FFFu + ((v.i >> 16) & 1u);
  return (u16)(r >> 16);
}
__device__ __forceinline__ float bu2f(u16 u) {
  union { u32 i; float f; } v; v.i = ((u32)u) << 16;
  return v.f;
}
__device__ __forceinline__ u32 pk(float a, float b) {
  return (u32)f2bu(a) | ((u32)f2bu(b) << 16);
}
__device__ __forceinline__ void gl16(const void* g, void* l) {
  __builtin_amdgcn_global_load_lds(
      (const __attribute__((address_space(1))) u32*)g,
      (__attribute__((address_space(3))) u32*)l, 16, 0, 0);
}

// ---------------- fused weight/bias conversion (21 segments) ----------------
__global__ __launch_bounds__(256) void k_cvt_all(
    const float* Wz_w, const float* Wr_w, const float* Wh_w, const float* Ui_w,
    const float* Ur_w, const float* W_w, const float* U_w, const float* Wo_w,
    const float* emb, const float* xtree,
    const float* Wz_b, const float* Wr_b, const float* Wh_b, const float* Ui_b,
    const float* W_b, const float* U_b,
    u16* wcat, u16* wz_h, u16* wh_h, u16* ui_h, u16* ur, u16* w_n, u16* u_n,
    u16* ccat, u16* wo, u16* emb_bf, u16* xt_bf, float* ebias, float* cbias) {
  int seg = blockIdx.y;
  const float* src = nullptr; u16* dst = nullptr;
  const float* fsrc = nullptr; float* fdst = nullptr;
  int R = 0, Cs = 0, c0 = 0, C = 0, fn = 0;
  switch (seg) {
    case 0:  src = Wz_w; dst = wcat;              R = 512;  Cs = 1024; c0 = 0;   C = 512; break;
    case 1:  src = Wr_w; dst = wcat + 512 * 512;  R = 512;  Cs = 512;  c0 = 0;   C = 512; break;
    case 2:  src = Wh_w; dst = wcat + 1024 * 512; R = 512;  Cs = 1024; c0 = 0;   C = 512; break;
    case 3:  src = Ui_w; dst = wcat + 1536 * 512; R = 512;  Cs = 1024; c0 = 0;   C = 512; break;
    case 4:  src = Wz_w; dst = wz_h;              R = 512;  Cs = 1024; c0 = 512; C = 512; break;
    case 5:  src = Wh_w; dst = wh_h;              R = 512;  Cs = 1024; c0 = 512; C = 512; break;
    case 6:  src = Ui_w; dst = ui_h;              R = 512;  Cs = 1024; c0 = 512; C = 512; break;
    case 7:  src = Ur_w; dst = ur;                R = 512;  Cs = 512;  c0 = 0;   C = 512; break;
    case 8:  src = W_w;  dst = w_n;               R = 512;  Cs = 640;  c0 = 0;   C = 512; break;
    case 9:  src = U_w;  dst = u_n;               R = 512;  Cs = 640;  c0 = 0;   C = 512; break;
    case 10: src = W_w;  dst = ccat;              R = 512;  Cs = 640;  c0 = 512; C = 128; break;
    case 11: src = U_w;  dst = ccat + 512 * 128;  R = 512;  Cs = 640;  c0 = 512; C = 128; break;
    case 12: src = Wo_w; dst = wo;                R = 1024; Cs = 512;  c0 = 0;   C = 512; break;
    case 13: src = emb;  dst = emb_bf;            R = 1024; Cs = 512;  c0 = 0;   C = 512; break;
    case 14: src = xtree; dst = xt_bf;            R = 256;  Cs = 128;  c0 = 0;   C = 128; break;
    case 15: fsrc = Wz_b; fdst = ebias;        fn = 512; break;
    case 16: fsrc = Wr_b; fdst = ebias + 512;  fn = 512; break;
    case 17: fsrc = Wh_b; fdst = ebias + 1024; fn = 512; break;
    case 18: fsrc = Ui_b; fdst = ebias + 1536; fn = 512; break;
    case 19: fsrc = W_b;  fdst = cbias;        fn = 512; break;
    case 20: fsrc = U_b;  fdst = cbias + 512;  fn = 512; break;
  }
  int i = blockIdx.x * 256 + threadIdx.x;
  if (fdst) { if (i < fn) fdst[i] = fsrc[i]; return; }
  int e0 = i * 8;
  if (e0 >= R * C) return;
  int r = e0 / C, c = e0 - r * C;
  const float* s = src + (size_t)r * Cs + c0 + c;
  float4 a = *reinterpret_cast<const float4*>(s);
  float4 b = *reinterpret_cast<const float4*>(s + 4);
  uint4 o = {pk(a.x, a.y), pk(a.z, a.w), pk(b.x, b.y), pk(b.z, b.w)};
  *reinterpret_cast<uint4*>(&dst[e0]) = o;
}

// ---------------- flat f32 -> bf16, 8 elems/thread ----------------
__global__ void k_cvt8(const float* __restrict__ src, u16* __restrict__ dst) {
  size_t i = ((size_t)blockIdx.x * 256 + threadIdx.x) * 8;
  float4 a = *reinterpret_cast<const float4*>(src + i);
  float4 b = *reinterpret_cast<const float4*>(src + i + 4);
  uint4 o = {pk(a.x, a.y), pk(a.z, a.w), pk(b.x, b.y), pk(b.z, b.w)};
  *reinterpret_cast<uint4*>(dst + i) = o;
}

// ---------------- GEMM core: 128x128 tile, BK=64, XOR-swizzled LDS ----------
struct GP {
  const u16* A; const u16* B; int K;
  const float* gadd; int ldg; const int* gidx;
  const float* bias; const float* zf; const u16* shb;
  float* outf; u16* outh; int ldo;
};

template<int EP>
__device__ __forceinline__ void epi(int row, int col, float v, const GP& g) {
  if constexpr (EP == 0) {
    g.outf[(size_t)row * g.ldo + col] = v + (g.bias ? g.bias[col] : 0.f);
  } else if constexpr (EP == 1) {
    float pre = v + g.gadd[(size_t)g.gidx[row] * g.ldg + col];
    g.outf[(size_t)row * g.ldo + col] = 1.f / (1.f + __expf(-pre));
  } else if constexpr (EP == 2) {
    float pre = tanhf(v + g.gadd[(size_t)g.gidx[row] * g.ldg + col]);
    float z = g.zf[(size_t)row * HDIM + col];
    float sh = bu2f(g.shb[(size_t)row * HDIM + col]);
    g.outh[(size_t)row * g.ldo + col] = f2bu((1.f - z) * sh + z * pre);
  } else if constexpr (EP == 3) {
    float pre = v + g.gadd[(size_t)g.gidx[row] * g.ldg + col];
    g.outh[(size_t)row * g.ldo + col] = f2bu(pre > 0.f ? pre : 0.f);
  } else {  // EP == 4: plain bf16 store
    g.outh[(size_t)row * g.ldo + col] = f2bu(v);
  }
}

template<int EP>
__device__ void gemm_core(const GP& g, u16* As, u16* Bs) {
  const int tid = threadIdx.x, lane = tid & 63, w = tid >> 6;
  const int wm = (w >> 1) * 64, wn = (w & 1) * 64;
  const int m0 = blockIdx.x * 128, n0 = blockIdx.y * 128;
  const int K = g.K;
  f4v acc[4][4];
  f4v z4 = {0.f, 0.f, 0.f, 0.f};
#pragma unroll
  for (int a = 0; a < 4; a++)
#pragma unroll
    for (int b = 0; b < 4; b++) acc[a][b] = z4;

  for (int k0 = 0; k0 < K; k0 += 64) {
    __syncthreads();
#pragma unroll
    for (int i = 0; i < 4; i++) {
      int slot = tid + i * 256;
      int r = slot >> 3, c = (slot & 7) ^ (r & 7);
      gl16(&g.A[(size_t)(m0 + r) * K + k0 + c * 8], &As[slot * 8]);
    }
#pragma unroll
    for (int i = 0; i < 4; i++) {
      int slot = tid + i * 256;
      int r = slot >> 3, c = (slot & 7) ^ (r & 7);
      gl16(&g.B[(size_t)(n0 + r) * K + k0 + c * 8], &Bs[slot * 8]);
    }
    __syncthreads();
#pragma unroll
    for (int ks = 0; ks < 2; ks++) {
      s8v af[4], bf[4];
      int cc = ks * 4 + (lane >> 4);
#pragma unroll
      for (int i = 0; i < 4; i++) {
        int R = wm + i * 16 + (lane & 15);
        af[i] = *reinterpret_cast<const s8v*>(&As[R * 64 + (cc ^ (R & 7)) * 8]);
        int C = wn + i * 16 + (lane & 15);
        bf[i] = *reinterpret_cast<const s8v*>(&Bs[C * 64 + (cc ^ (C & 7)) * 8]);
      }
#pragma unroll
      for (int mi = 0; mi < 4; mi++)
#pragma unroll
        for (int ni = 0; ni < 4; ni++)
          acc[mi][ni] = __builtin_amdgcn_mfma_f32_16x16x32_bf16(
              af[mi], bf[ni], acc[mi][ni], 0, 0, 0);
    }
  }
#pragma unroll
  for (int mi = 0; mi < 4; mi++)
#pragma unroll
    for (int ni = 0; ni < 4; ni++)
#pragma unroll
      for (int r = 0; r < 4; r++) {
        int row = m0 + wm + mi * 16 + (lane >> 4) * 4 + r;
        int col = n0 + wn + ni * 16 + (lane & 15);
        epi<EP>(row, col, acc[mi][ni][r], g);
      }
}

template<int EP>
__global__ __launch_bounds__(256) void k_gemm(GP g) {
  __shared__ u16 As[128 * 64], Bs[128 * 64];
  gemm_core<EP>(g, As, Bs);
}

template<int EPa, int EPb>
__global__ __launch_bounds__(256) void k_pair(GP a, GP b) {
  __shared__ u16 As[128 * 64], Bs[128 * 64];
  if (blockIdx.z == 0) gemm_core<EPa>(a, As, Bs);
  else gemm_core<EPb>(b, As, Bs);
}

// ---------------- fused gather: sum_h, sg (=Σ sigmoid(r2+E_r)·h), cur_o ----
// One node per block, 512 threads: t<256 -> nei side (2 cols/thread, h+r2
// reads), t>=256 -> o side (2 cols/thread). All register accumulation;
// no atomics, no LDS staging. H_bf/R2 are L3-resident (67 MB each).
__global__ __launch_bounds__(512) void k_gsr(
    const u16* __restrict__ Hb, const u16* __restrict__ R2,
    const float* __restrict__ E_r, int ldg, const int* __restrict__ x_ids,
    const int* __restrict__ nei_idx, const int* __restrict__ nei_mask,
    const int* __restrict__ o_idx, const int* __restrict__ o_mask,
    u16* __restrict__ sum_h_bf, u16* __restrict__ sg_bf,
    u16* __restrict__ cur_o_bf) {
  int n = blockIdx.x;
  int t = threadIdx.x;
  __shared__ int sidx[NB], soid[NB];
  __shared__ int smsk[NB], somk[NB];
  __shared__ int sx;
  if (t < NB) {
    sidx[t] = nei_idx[(size_t)n * NB + t];
    smsk[t] = nei_mask[(size_t)n * NB + t];
  } else if (t >= 256 && t < 256 + NB) {
    int k = t - 256;
    soid[k] = o_idx[(size_t)n * NB + k];
    somk[k] = o_mask[(size_t)n * NB + k];
  } else if (t == 511) {
    sx = x_ids[n];
  }
  __syncthreads();
  if (t < 256) {
    int c = t * 2;
    const float* er = E_r + (size_t)sx * ldg + c;
    float e0 = er[0], e1 = er[1];
    float s0 = 0.f, s1 = 0.f, g0 = 0.f, g1 = 0.f;
#pragma unroll
    for (int k = 0; k < NB; k++) {
      if (smsk[k]) {
        u32 hv = *reinterpret_cast<const u32*>(Hb + (size_t)sidx[k] * HDIM + c);
        u32 rv = *reinterpret_cast<const u32*>(R2 + (size_t)sidx[k] * HDIM + c);
        float h0 = bu2f((u16)hv), h1 = bu2f((u16)(hv >> 16));
        float r0 = 1.f / (1.f + __expf(-(bu2f((u16)rv) + e0)));
        float r1 = 1.f / (1.f + __expf(-(bu2f((u16)(rv >> 16)) + e1)));
        s0 += h0; s1 += h1;
        g0 += r0 * h0; g1 += r1 * h1;
      }
    }
    size_t b = (size_t)n * HDIM + c;
    *reinterpret_cast<u32*>(&sum_h_bf[b]) = pk(s0, s1);
    *reinterpret_cast<u32*>(&sg_bf[b]) = pk(g0, g1);
  } else {
    int c = (t - 256) * 2;
    float o0 = 0.f, o1 = 0.f;
#pragma unroll
    for (int k = 0; k < NB; k++) {
      if (somk[k]) {
        u32 v = *reinterpret_cast<const u32*>(Hb + (size_t)soid[k] * HDIM + c);
        o0 += bu2f((u16)v); o1 += bu2f((u16)(v >> 16));
      }
    }
    *reinterpret_cast<u32*>(&cur_o_bf[(size_t)n * HDIM + c]) = pk(o0, o1);
  }
}

// ---------------- stop score ----------------
__global__ __launch_bounds__(256) void k_stop(
    const u16* __restrict__ shid, const float* __restrict__ Uo_w,
    const float* __restrict__ Uo_b, float* __restrict__ out) {
  int n = blockIdx.x * 4 + (threadIdx.x >> 6);
  int lane = threadIdx.x & 63;
  float s = 0.f;
  for (int j = lane; j < HDIM; j += 64)
    s += bu2f(shid[(size_t)n * HDIM + j]) * Uo_w[j];
#pragma unroll
  for (int off = 32; off; off >>= 1) s += __shfl_xor(s, off, 64);
  if (lane == 0) out[(size_t)n * 1025 + 1024] = s + Uo_b[0];
}

// ---------------- host ----------------
extern "C" void kernel_launch(void* const* d_in, const int* in_sizes, int n_in,
                              void* d_out, int out_size, void* d_ws, size_t ws_size,
                              hipStream_t stream) {
  const int* x_ids = (const int*)d_in[0];
  const int* contexts = (const int*)d_in[1];
  const int* nei_idx = (const int*)d_in[2];
  const int* nei_mask = (const int*)d_in[3];
  const int* o_idx = (const int*)d_in[4];
  const int* o_mask = (const int*)d_in[5];
  const float* H_msg = (const float*)d_in[6];
  const float* xtree = (const float*)d_in[7];
  const float* emb = (const float*)d_in[8];
  const float* Wz_w = (const float*)d_in[9];  const float* Wz_b = (const float*)d_in[10];
  const float* Wr_w = (const float*)d_in[11]; const float* Wr_b = (const float*)d_in[12];
  const float* Ur_w = (const float*)d_in[13];
  const float* Wh_w = (const float*)d_in[14]; const float* Wh_b = (const float*)d_in[15];
  const float* W_w  = (const float*)d_in[16]; const float* W_b  = (const float*)d_in[17];
  const float* Wo_w = (const float*)d_in[18]; const float* Wo_b = (const float*)d_in[19];
  const float* Ui_w = (const float*)d_in[20]; const float* Ui_b = (const float*)d_in[21];
  const float* U_w  = (const float*)d_in[22]; const float* U_b  = (const float*)d_in[23];
  const float* Uo_w = (const float*)d_in[24]; const float* Uo_b = (const float*)d_in[25];
  float* out = (float*)d_out;
  const int M = 65536;

  char* base = (char*)d_ws;
  size_t ofs = 0;
  auto alloc = [&](size_t bytes) -> char* {
    char* p = base + ofs;
    ofs = (ofs + bytes + 255) & ~(size_t)255;
    return p;
  };
  u16* wcat  = (u16*)alloc((size_t)2048 * 512 * 2);
  u16* wz_h  = (u16*)alloc(512 * 512 * 2);
  u16* wh_h  = (u16*)alloc(512 * 512 * 2);
  u16* ui_h  = (u16*)alloc(512 * 512 * 2);
  u16* ur    = (u16*)alloc(512 * 512 * 2);
  u16* w_n   = (u16*)alloc(512 * 512 * 2);
  u16* u_n   = (u16*)alloc(512 * 512 * 2);
  u16* ccat  = (u16*)alloc(1024 * 128 * 2);
  u16* wo    = (u16*)alloc(1024 * 512 * 2);
  u16* emb_bf = (u16*)alloc(1024 * 512 * 2);
  u16* xt_bf  = (u16*)alloc(256 * 128 * 2);
  float* ebias = (float*)alloc(2048 * 4);
  float* cbias = (float*)alloc(1024 * 4);
  float* E_cat = (float*)alloc((size_t)1024 * 2048 * 4);
  float* C_cat = (float*)alloc((size_t)256 * 1024 * 4);
  u16* H_bf = (u16*)alloc((size_t)M * HDIM * 2);
  u16* R2   = (u16*)alloc((size_t)M * HDIM * 2);
  float* z_f = (float*)alloc((size_t)NNODE * HDIM * 4);
  u16* sum_h_bf = (u16*)alloc((size_t)NNODE * HDIM * 2);
  u16* cur_o_bf = (u16*)alloc((size_t)NNODE * HDIM * 2);
  u16* sg_bf    = (u16*)alloc((size_t)NNODE * HDIM * 2);
  u16* newh_bf  = (u16*)alloc((size_t)NNODE * HDIM * 2);
  u16* whid_bf  = (u16*)alloc((size_t)NNODE * HDIM * 2);
  u16* stoph_bf = (u16*)alloc((size_t)NNODE * HDIM * 2);
  u16* shid_bf  = (u16*)alloc((size_t)NNODE * HDIM * 2);

  k_cvt_all<<<dim3(256, 21), dim3(256), 0, stream>>>(
      Wz_w, Wr_w, Wh_w, Ui_w, Ur_w, W_w, U_w, Wo_w, emb, xtree,
      Wz_b, Wr_b, Wh_b, Ui_b, W_b, U_b,
      wcat, wz_h, wh_h, ui_h, ur, w_n, u_n, ccat, wo, emb_bf, xt_bf,
      ebias, cbias);
  k_cvt8<<<dim3(16384), dim3(256), 0, stream>>>(H_msg, H_bf);

  // E tables: [1024 x 2048] = emb @ [Wz_x|Wr|Wh_x|Ui_x]^T + [biases]
  GP ge{emb_bf, wcat, 512, nullptr, 0, nullptr, ebias, nullptr, nullptr,
        E_cat, nullptr, 2048};
  k_gemm<0><<<dim3(8, 16), dim3(256), 0, stream>>>(ge);
  // ctx tables: [256 x 1024] = xt @ [W_c|U_c]^T + [biases]
  GP gc{xt_bf, ccat, 128, nullptr, 0, nullptr, cbias, nullptr, nullptr,
        C_cat, nullptr, 1024};
  k_gemm<0><<<dim3(2, 8), dim3(256), 0, stream>>>(gc);

  // R2_all = H_msg @ Ur^T for ALL messages (dense, 34.4 GF) -> bf16
  GP gr{H_bf, ur, 512, nullptr, 0, nullptr, nullptr, nullptr, nullptr,
        nullptr, R2, 512};
  k_gemm<4><<<dim3(512, 4), dim3(256), 0, stream>>>(gr);

  // fused gather: sum_h, sg = sum sigmoid(R2+E_r)*h, cur_o
  k_gsr<<<dim3(NNODE), dim3(512), 0, stream>>>(
      H_bf, R2, E_cat + 512, 2048, x_ids, nei_idx, nei_mask, o_idx, o_mask,
      sum_h_bf, sg_bf, cur_o_bf);

  // z (EP1) + stop_h (EP3) paired
  GP gz{sum_h_bf, wz_h, 512, E_cat, 2048, x_ids, nullptr, nullptr, nullptr,
        z_f, nullptr, 512};
  GP gs{cur_o_bf, ui_h, 512, E_cat + 1536, 2048, x_ids, nullptr, nullptr, nullptr,
        nullptr, stoph_bf, 512};
  k_pair<1, 3><<<dim3(128, 4, 2), dim3(256), 0, stream>>>(gz, gs);

  // new_h (EP2): (1-z)*sum_h + z*tanh(sg @ Wh_h^T + E_h[x_ids])
  GP gn{sg_bf, wh_h, 512, E_cat + 1024, 2048, x_ids, nullptr, z_f, sum_h_bf,
        nullptr, newh_bf, 512};
  k_gemm<2><<<dim3(128, 4), dim3(256), 0, stream>>>(gn);

  // w_hid + s_hid paired (both EP3)
  GP gw{newh_bf, w_n, 512, C_cat, 1024, contexts, nullptr, nullptr, nullptr,
        nullptr, whid_bf, 512};
  GP gu{stoph_bf, u_n, 512, C_cat + 512, 1024, contexts, nullptr, nullptr, nullptr,
        nullptr, shid_bf, 512};
  k_pair<3, 3><<<dim3(128, 4, 2), dim3(256), 0, stream>>>(gw, gu);

  // word scores -> out[:, 0:1024] (row stride 1025)
  GP gword{whid_bf, wo, 512, nullptr, 0, nullptr, Wo_b, nullptr, nullptr,
           out, nullptr, 1025};
  k_gemm<0><<<dim3(128, 8), dim3(256), 0, stream>>>(gword);

  k_stop<<<dim3(NNODE / 4), dim3(256), 0, stream>>>(shid_bf, Uo_w, Uo_b, out);
}

// Round 7
// 431.868 us; speedup vs baseline: 1.9252x; 1.1150x over previous
//
#include <hip/hip_runtime.h>
#include <hip/hip_bf16.h>

typedef unsigned short u16;
typedef unsigned int u32;
typedef __attribute__((ext_vector_type(8))) short s8v;
typedef __attribute__((ext_vector_type(4))) float f4v;

#define HDIM 512
#define NNODE 16384
#define NB 15

__device__ __forceinline__ u16 f2bu(float x) {
  union { float f; u32 i; } v; v.f = x;
  u32 r = v.i + 0x7FFFu + ((v.i >> 16) & 1u);
  return (u16)(r >> 16);
}
__device__ __forceinline__ float bu2f(u16 u) {
  union { u32 i; float f; } v; v.i = ((u32)u) << 16;
  return v.f;
}
__device__ __forceinline__ u32 pk(float a, float b) {
  return (u32)f2bu(a) | ((u32)f2bu(b) << 16);
}
__device__ __forceinline__ float sigm(float x) {
  return __builtin_amdgcn_rcpf(1.f + __expf(-x));
}
__device__ __forceinline__ void gl16(const void* g, void* l) {
  __builtin_amdgcn_global_load_lds(
      (const __attribute__((address_space(1))) u32*)g,
      (__attribute__((address_space(3))) u32*)l, 16, 0, 0);
}

// ---------------- fused weight/bias conversion (21 segments) ----------------
__global__ __launch_bounds__(256) void k_cvt_all(
    const float* Wz_w, const float* Wr_w, const float* Wh_w, const float* Ui_w,
    const float* Ur_w, const float* W_w, const float* U_w, const float* Wo_w,
    const float* emb, const float* xtree,
    const float* Wz_b, const float* Wr_b, const float* Wh_b, const float* Ui_b,
    const float* W_b, const float* U_b,
    u16* wcat, u16* wz_h, u16* wh_h, u16* ui_h, u16* ur, u16* w_n, u16* u_n,
    u16* ccat, u16* wo, u16* emb_bf, u16* xt_bf, float* ebias, float* cbias) {
  int seg = blockIdx.y;
  const float* src = nullptr; u16* dst = nullptr;
  const float* fsrc = nullptr; float* fdst = nullptr;
  int R = 0, Cs = 0, c0 = 0, C = 0, fn = 0;
  switch (seg) {
    case 0:  src = Wz_w; dst = wcat;              R = 512;  Cs = 1024; c0 = 0;   C = 512; break;
    case 1:  src = Wr_w; dst = wcat + 512 * 512;  R = 512;  Cs = 512;  c0 = 0;   C = 512; break;
    case 2:  src = Wh_w; dst = wcat + 1024 * 512; R = 512;  Cs = 1024; c0 = 0;   C = 512; break;
    case 3:  src = Ui_w; dst = wcat + 1536 * 512; R = 512;  Cs = 1024; c0 = 0;   C = 512; break;
    case 4:  src = Wz_w; dst = wz_h;              R = 512;  Cs = 1024; c0 = 512; C = 512; break;
    case 5:  src = Wh_w; dst = wh_h;              R = 512;  Cs = 1024; c0 = 512; C = 512; break;
    case 6:  src = Ui_w; dst = ui_h;              R = 512;  Cs = 1024; c0 = 512; C = 512; break;
    case 7:  src = Ur_w; dst = ur;                R = 512;  Cs = 512;  c0 = 0;   C = 512; break;
    case 8:  src = W_w;  dst = w_n;               R = 512;  Cs = 640;  c0 = 0;   C = 512; break;
    case 9:  src = U_w;  dst = u_n;               R = 512;  Cs = 640;  c0 = 0;   C = 512; break;
    case 10: src = W_w;  dst = ccat;              R = 512;  Cs = 640;  c0 = 512; C = 128; break;
    case 11: src = U_w;  dst = ccat + 512 * 128;  R = 512;  Cs = 640;  c0 = 512; C = 128; break;
    case 12: src = Wo_w; dst = wo;                R = 1024; Cs = 512;  c0 = 0;   C = 512; break;
    case 13: src = emb;  dst = emb_bf;            R = 1024; Cs = 512;  c0 = 0;   C = 512; break;
    case 14: src = xtree; dst = xt_bf;            R = 256;  Cs = 128;  c0 = 0;   C = 128; break;
    case 15: fsrc = Wz_b; fdst = ebias;        fn = 512; break;
    case 16: fsrc = Wr_b; fdst = ebias + 512;  fn = 512; break;
    case 17: fsrc = Wh_b; fdst = ebias + 1024; fn = 512; break;
    case 18: fsrc = Ui_b; fdst = ebias + 1536; fn = 512; break;
    case 19: fsrc = W_b;  fdst = cbias;        fn = 512; break;
    case 20: fsrc = U_b;  fdst = cbias + 512;  fn = 512; break;
  }
  int i = blockIdx.x * 256 + threadIdx.x;
  if (fdst) { if (i < fn) fdst[i] = fsrc[i]; return; }
  int e0 = i * 8;
  if (e0 >= R * C) return;
  int r = e0 / C, c = e0 - r * C;
  const float* s = src + (size_t)r * Cs + c0 + c;
  float4 a = *reinterpret_cast<const float4*>(s);
  float4 b = *reinterpret_cast<const float4*>(s + 4);
  uint4 o = {pk(a.x, a.y), pk(a.z, a.w), pk(b.x, b.y), pk(b.z, b.w)};
  *reinterpret_cast<uint4*>(&dst[e0]) = o;
}

// ---------------- flat f32 -> bf16, 8 elems/thread ----------------
__global__ void k_cvt8(const float* __restrict__ src, u16* __restrict__ dst) {
  size_t i = ((size_t)blockIdx.x * 256 + threadIdx.x) * 8;
  float4 a = *reinterpret_cast<const float4*>(src + i);
  float4 b = *reinterpret_cast<const float4*>(src + i + 4);
  uint4 o = {pk(a.x, a.y), pk(a.z, a.w), pk(b.x, b.y), pk(b.z, b.w)};
  *reinterpret_cast<uint4*>(dst + i) = o;
}

// ---------------- GEMM core: 128x128 tile, BK=64, XOR-swizzle, 2-phase dbuf --
// One barrier per K-step; STAGE(next) issued right after the barrier so the
// global_load_lds latency overlaps the MFMA phase of the current buffer.
struct GP {
  const u16* A; const u16* B; int K;
  const float* gadd; int ldg; const int* gidx;
  const float* bias; const float* zf; const u16* shb;
  float* outf; u16* outh; int ldo;
};

template<int EP>
__device__ __forceinline__ void epi(int row, int col, float v, const GP& g) {
  if constexpr (EP == 0) {
    g.outf[(size_t)row * g.ldo + col] = v + (g.bias ? g.bias[col] : 0.f);
  } else if constexpr (EP == 1) {
    float pre = v + g.gadd[(size_t)g.gidx[row] * g.ldg + col];
    g.outf[(size_t)row * g.ldo + col] = sigm(pre);
  } else if constexpr (EP == 2) {
    float pre = tanhf(v + g.gadd[(size_t)g.gidx[row] * g.ldg + col]);
    float z = g.zf[(size_t)row * HDIM + col];
    float sh = bu2f(g.shb[(size_t)row * HDIM + col]);
    g.outh[(size_t)row * g.ldo + col] = f2bu((1.f - z) * sh + z * pre);
  } else if constexpr (EP == 3) {
    float pre = v + g.gadd[(size_t)g.gidx[row] * g.ldg + col];
    g.outh[(size_t)row * g.ldo + col] = f2bu(pre > 0.f ? pre : 0.f);
  } else {  // EP == 4: plain bf16 store
    g.outh[(size_t)row * g.ldo + col] = f2bu(v);
  }
}

template<int EP>
__device__ void gemm_core(const GP& g, u16* AsB, u16* BsB) {
  const int tid = threadIdx.x, lane = tid & 63, w = tid >> 6;
  const int wm = (w >> 1) * 64, wn = (w & 1) * 64;
  const int m0 = blockIdx.x * 128, n0 = blockIdx.y * 128;
  const int K = g.K;

  const u16* gA[4]; const u16* gB[4]; int ls[4];
#pragma unroll
  for (int i = 0; i < 4; i++) {
    int slot = tid + i * 256;
    int r = slot >> 3, c = (slot & 7) ^ (r & 7);
    gA[i] = g.A + (size_t)(m0 + r) * K + c * 8;
    gB[i] = g.B + (size_t)(n0 + r) * K + c * 8;
    ls[i] = slot * 8;
  }

  f4v acc[4][4];
  f4v z4 = {0.f, 0.f, 0.f, 0.f};
#pragma unroll
  for (int a = 0; a < 4; a++)
#pragma unroll
    for (int b = 0; b < 4; b++) acc[a][b] = z4;

  const int T = K >> 6;
  // prologue: stage K-step 0 into buffer 0
#pragma unroll
  for (int i = 0; i < 4; i++) gl16(gA[i], AsB + ls[i]);
#pragma unroll
  for (int i = 0; i < 4; i++) gl16(gB[i], BsB + ls[i]);

  int cur = 0;
  for (int t = 0; t < T; t++) {
    __syncthreads();  // drains vmcnt: buf[cur] ready, buf[cur^1] free
    if (t + 1 < T) {
      int k0 = (t + 1) * 64;
      u16* as = AsB + (cur ^ 1) * 8192;
      u16* bs = BsB + (cur ^ 1) * 8192;
#pragma unroll
      for (int i = 0; i < 4; i++) gl16(gA[i] + k0, as + ls[i]);
#pragma unroll
      for (int i = 0; i < 4; i++) gl16(gB[i] + k0, bs + ls[i]);
    }
    const u16* as = AsB + cur * 8192;
    const u16* bs = BsB + cur * 8192;
#pragma unroll
    for (int ks = 0; ks < 2; ks++) {
      s8v af[4], bf[4];
      int cc = ks * 4 + (lane >> 4);
#pragma unroll
      for (int i = 0; i < 4; i++) {
        int R = wm + i * 16 + (lane & 15);
        af[i] = *reinterpret_cast<const s8v*>(&as[R * 64 + (cc ^ (R & 7)) * 8]);
        int C = wn + i * 16 + (lane & 15);
        bf[i] = *reinterpret_cast<const s8v*>(&bs[C * 64 + (cc ^ (C & 7)) * 8]);
      }
#pragma unroll
      for (int mi = 0; mi < 4; mi++)
#pragma unroll
        for (int ni = 0; ni < 4; ni++)
          acc[mi][ni] = __builtin_amdgcn_mfma_f32_16x16x32_bf16(
              af[mi], bf[ni], acc[mi][ni], 0, 0, 0);
    }
    cur ^= 1;
  }
#pragma unroll
  for (int mi = 0; mi < 4; mi++)
#pragma unroll
    for (int ni = 0; ni < 4; ni++)
#pragma unroll
      for (int r = 0; r < 4; r++) {
        int row = m0 + wm + mi * 16 + (lane >> 4) * 4 + r;
        int col = n0 + wn + ni * 16 + (lane & 15);
        epi<EP>(row, col, acc[mi][ni][r], g);
      }
}

template<int EP>
__global__ __launch_bounds__(256) void k_gemm(GP g) {
  __shared__ u16 As[2 * 128 * 64], Bs[2 * 128 * 64];  // 64KB total
  gemm_core<EP>(g, As, Bs);
}

template<int EPa, int EPb>
__global__ __launch_bounds__(256) void k_pair(GP a, GP b) {
  __shared__ u16 As[2 * 128 * 64], Bs[2 * 128 * 64];
  if (blockIdx.z == 0) gemm_core<EPa>(a, As, Bs);
  else gemm_core<EPb>(b, As, Bs);
}

// ---------------- fused gather: sum_h, sg (=Σ sigmoid(r2+E_r)·h), cur_o ----
// 256 threads, one node per block; every thread handles 2 cols of ALL THREE
// streams (nei-h, nei-r2, o-h) -> uniform work, no wave imbalance. rcpf
// sigmoid (1 instr vs ~10 for exact div). H_bf/R2 are L3-resident.
__global__ __launch_bounds__(256) void k_gsr(
    const u16* __restrict__ Hb, const u16* __restrict__ R2,
    const float* __restrict__ E_r, int ldg, const int* __restrict__ x_ids,
    const int* __restrict__ nei_idx, const int* __restrict__ nei_mask,
    const int* __restrict__ o_idx, const int* __restrict__ o_mask,
    u16* __restrict__ sum_h_bf, u16* __restrict__ sg_bf,
    u16* __restrict__ cur_o_bf) {
  int n = blockIdx.x;
  int t = threadIdx.x;
  __shared__ int sidx[NB], smsk[NB], soid[NB], somk[NB];
  __shared__ int sx;
  if (t < NB) {
    sidx[t] = nei_idx[(size_t)n * NB + t];
    smsk[t] = nei_mask[(size_t)n * NB + t];
  } else if (t >= 64 && t < 64 + NB) {
    int k = t - 64;
    soid[k] = o_idx[(size_t)n * NB + k];
    somk[k] = o_mask[(size_t)n * NB + k];
  } else if (t == 128) {
    sx = x_ids[n];
  }
  __syncthreads();
  int c = t * 2;
  const float2 e = *reinterpret_cast<const float2*>(E_r + (size_t)sx * ldg + c);
  float s0 = 0.f, s1 = 0.f, g0 = 0.f, g1 = 0.f, o0 = 0.f, o1 = 0.f;
#pragma unroll
  for (int k = 0; k < NB; k++) {
    if (smsk[k]) {
      u32 hv = *reinterpret_cast<const u32*>(Hb + (size_t)sidx[k] * HDIM + c);
      u32 rv = *reinterpret_cast<const u32*>(R2 + (size_t)sidx[k] * HDIM + c);
      float h0 = bu2f((u16)hv), h1 = bu2f((u16)(hv >> 16));
      float r0 = sigm(bu2f((u16)rv) + e.x);
      float r1 = sigm(bu2f((u16)(rv >> 16)) + e.y);
      s0 += h0; s1 += h1;
      g0 += r0 * h0; g1 += r1 * h1;
    }
    if (somk[k]) {
      u32 v = *reinterpret_cast<const u32*>(Hb + (size_t)soid[k] * HDIM + c);
      o0 += bu2f((u16)v); o1 += bu2f((u16)(v >> 16));
    }
  }
  size_t b = (size_t)n * HDIM + c;
  *reinterpret_cast<u32*>(&sum_h_bf[b]) = pk(s0, s1);
  *reinterpret_cast<u32*>(&sg_bf[b]) = pk(g0, g1);
  *reinterpret_cast<u32*>(&cur_o_bf[b]) = pk(o0, o1);
}

// ---------------- stop score ----------------
__global__ __launch_bounds__(256) void k_stop(
    const u16* __restrict__ shid, const float* __restrict__ Uo_w,
    const float* __restrict__ Uo_b, float* __restrict__ out) {
  int n = blockIdx.x * 4 + (threadIdx.x >> 6);
  int lane = threadIdx.x & 63;
  float s = 0.f;
  for (int j = lane; j < HDIM; j += 64)
    s += bu2f(shid[(size_t)n * HDIM + j]) * Uo_w[j];
#pragma unroll
  for (int off = 32; off; off >>= 1) s += __shfl_xor(s, off, 64);
  if (lane == 0) out[(size_t)n * 1025 + 1024] = s + Uo_b[0];
}

// ---------------- host ----------------
extern "C" void kernel_launch(void* const* d_in, const int* in_sizes, int n_in,
                              void* d_out, int out_size, void* d_ws, size_t ws_size,
                              hipStream_t stream) {
  const int* x_ids = (const int*)d_in[0];
  const int* contexts = (const int*)d_in[1];
  const int* nei_idx = (const int*)d_in[2];
  const int* nei_mask = (const int*)d_in[3];
  const int* o_idx = (const int*)d_in[4];
  const int* o_mask = (const int*)d_in[5];
  const float* H_msg = (const float*)d_in[6];
  const float* xtree = (const float*)d_in[7];
  const float* emb = (const float*)d_in[8];
  const float* Wz_w = (const float*)d_in[9];  const float* Wz_b = (const float*)d_in[10];
  const float* Wr_w = (const float*)d_in[11]; const float* Wr_b = (const float*)d_in[12];
  const float* Ur_w = (const float*)d_in[13];
  const float* Wh_w = (const float*)d_in[14]; const float* Wh_b = (const float*)d_in[15];
  const float* W_w  = (const float*)d_in[16]; const float* W_b  = (const float*)d_in[17];
  const float* Wo_w = (const float*)d_in[18]; const float* Wo_b = (const float*)d_in[19];
  const float* Ui_w = (const float*)d_in[20]; const float* Ui_b = (const float*)d_in[21];
  const float* U_w  = (const float*)d_in[22]; const float* U_b  = (const float*)d_in[23];
  const float* Uo_w = (const float*)d_in[24]; const float* Uo_b = (const float*)d_in[25];
  float* out = (float*)d_out;
  const int M = 65536;

  char* base = (char*)d_ws;
  size_t ofs = 0;
  auto alloc = [&](size_t bytes) -> char* {
    char* p = base + ofs;
    ofs = (ofs + bytes + 255) & ~(size_t)255;
    return p;
  };
  u16* wcat  = (u16*)alloc((size_t)2048 * 512 * 2);
  u16* wz_h  = (u16*)alloc(512 * 512 * 2);
  u16* wh_h  = (u16*)alloc(512 * 512 * 2);
  u16* ui_h  = (u16*)alloc(512 * 512 * 2);
  u16* ur    = (u16*)alloc(512 * 512 * 2);
  u16* w_n   = (u16*)alloc(512 * 512 * 2);
  u16* u_n   = (u16*)alloc(512 * 512 * 2);
  u16* ccat  = (u16*)alloc(1024 * 128 * 2);
  u16* wo    = (u16*)alloc(1024 * 512 * 2);
  u16* emb_bf = (u16*)alloc(1024 * 512 * 2);
  u16* xt_bf  = (u16*)alloc(256 * 128 * 2);
  float* ebias = (float*)alloc(2048 * 4);
  float* cbias = (float*)alloc(1024 * 4);
  float* E_cat = (float*)alloc((size_t)1024 * 2048 * 4);
  float* C_cat = (float*)alloc((size_t)256 * 1024 * 4);
  u16* H_bf = (u16*)alloc((size_t)M * HDIM * 2);
  u16* R2   = (u16*)alloc((size_t)M * HDIM * 2);
  float* z_f = (float*)alloc((size_t)NNODE * HDIM * 4);
  u16* sum_h_bf = (u16*)alloc((size_t)NNODE * HDIM * 2);
  u16* cur_o_bf = (u16*)alloc((size_t)NNODE * HDIM * 2);
  u16* sg_bf    = (u16*)alloc((size_t)NNODE * HDIM * 2);
  u16* newh_bf  = (u16*)alloc((size_t)NNODE * HDIM * 2);
  u16* whid_bf  = (u16*)alloc((size_t)NNODE * HDIM * 2);
  u16* stoph_bf = (u16*)alloc((size_t)NNODE * HDIM * 2);
  u16* shid_bf  = (u16*)alloc((size_t)NNODE * HDIM * 2);

  k_cvt_all<<<dim3(256, 21), dim3(256), 0, stream>>>(
      Wz_w, Wr_w, Wh_w, Ui_w, Ur_w, W_w, U_w, Wo_w, emb, xtree,
      Wz_b, Wr_b, Wh_b, Ui_b, W_b, U_b,
      wcat, wz_h, wh_h, ui_h, ur, w_n, u_n, ccat, wo, emb_bf, xt_bf,
      ebias, cbias);
  k_cvt8<<<dim3(16384), dim3(256), 0, stream>>>(H_msg, H_bf);

  // E tables: [1024 x 2048] = emb @ [Wz_x|Wr|Wh_x|Ui_x]^T + [biases]
  GP ge{emb_bf, wcat, 512, nullptr, 0, nullptr, ebias, nullptr, nullptr,
        E_cat, nullptr, 2048};
  k_gemm<0><<<dim3(8, 16), dim3(256), 0, stream>>>(ge);
  // ctx tables: [256 x 1024] = xt @ [W_c|U_c]^T + [biases]
  GP gc{xt_bf, ccat, 128, nullptr, 0, nullptr, cbias, nullptr, nullptr,
        C_cat, nullptr, 1024};
  k_gemm<0><<<dim3(2, 8), dim3(256), 0, stream>>>(gc);

  // R2_all = H_msg @ Ur^T for ALL messages (dense, 34.4 GF) -> bf16
  GP gr{H_bf, ur, 512, nullptr, 0, nullptr, nullptr, nullptr, nullptr,
        nullptr, R2, 512};
  k_gemm<4><<<dim3(512, 4), dim3(256), 0, stream>>>(gr);

  // fused gather: sum_h, sg = sum sigmoid(R2+E_r)*h, cur_o
  k_gsr<<<dim3(NNODE), dim3(256), 0, stream>>>(
      H_bf, R2, E_cat + 512, 2048, x_ids, nei_idx, nei_mask, o_idx, o_mask,
      sum_h_bf, sg_bf, cur_o_bf);

  // z (EP1) + stop_h (EP3) paired
  GP gz{sum_h_bf, wz_h, 512, E_cat, 2048, x_ids, nullptr, nullptr, nullptr,
        z_f, nullptr, 512};
  GP gs{cur_o_bf, ui_h, 512, E_cat + 1536, 2048, x_ids, nullptr, nullptr, nullptr,
        nullptr, stoph_bf, 512};
  k_pair<1, 3><<<dim3(128, 4, 2), dim3(256), 0, stream>>>(gz, gs);

  // new_h (EP2): (1-z)*sum_h + z*tanh(sg @ Wh_h^T + E_h[x_ids])
  GP gn{sg_bf, wh_h, 512, E_cat + 1024, 2048, x_ids, nullptr, z_f, sum_h_bf,
        nullptr, newh_bf, 512};
  k_gemm<2><<<dim3(128, 4), dim3(256), 0, stream>>>(gn);

  // w_hid + s_hid paired (both EP3)
  GP gw{newh_bf, w_n, 512, C_cat, 1024, contexts, nullptr, nullptr, nullptr,
        nullptr, whid_bf, 512};
  GP gu{stoph_bf, u_n, 512, C_cat + 512, 1024, contexts, nullptr, nullptr, nullptr,
        nullptr, shid_bf, 512};
  k_pair<3, 3><<<dim3(128, 4, 2), dim3(256), 0, stream>>>(gw, gu);

  // word scores -> out[:, 0:1024] (row stride 1025)
  GP gword{whid_bf, wo, 512, nullptr, 0, nullptr, Wo_b, nullptr, nullptr,
           out, nullptr, 1025};
  k_gemm<0><<<dim3(128, 8), dim3(256), 0, stream>>>(gword);

  k_stop<<<dim3(NNODE / 4), dim3(256), 0, stream>>>(shid_bf, Uo_w, Uo_b, out);
}

// Round 8
// 357.980 us; speedup vs baseline: 2.3226x; 1.2064x over previous
//
#include <hip/hip_runtime.h>
#include <hip/hip_bf16.h>

typedef unsigned short u16;
typedef unsigned int u32;
typedef __attribute__((ext_vector_type(8))) short s8v;
typedef __attribute__((ext_vector_type(4))) float f4v;

#define HDIM 512
#define NNODE 16384
#define NB 15

__device__ __forceinline__ u16 f2bu(float x) {
  union { float f; u32 i; } v; v.f = x;
  u32 r = v.i + 0x7FFFu + ((v.i >> 16) & 1u);
  return (u16)(r >> 16);
}
__device__ __forceinline__ float bu2f(u16 u) {
  union { u32 i; float f; } v; v.i = ((u32)u) << 16;
  return v.f;
}
__device__ __forceinline__ u32 pk(float a, float b) {
  return (u32)f2bu(a) | ((u32)f2bu(b) << 16);
}
__device__ __forceinline__ float sigm(float x) {
  return __builtin_amdgcn_rcpf(1.f + __expf(-x));
}
__device__ __forceinline__ void gl16(const void* g, void* l) {
  __builtin_amdgcn_global_load_lds(
      (const __attribute__((address_space(1))) u32*)g,
      (__attribute__((address_space(3))) u32*)l, 16, 0, 0);
}

// ---------------- fused weight/bias conversion (21 segments) ----------------
__global__ __launch_bounds__(256) void k_cvt_all(
    const float* Wz_w, const float* Wr_w, const float* Wh_w, const float* Ui_w,
    const float* Ur_w, const float* W_w, const float* U_w, const float* Wo_w,
    const float* emb, const float* xtree,
    const float* Wz_b, const float* Wr_b, const float* Wh_b, const float* Ui_b,
    const float* W_b, const float* U_b,
    u16* wcat, u16* wz_h, u16* wh_h, u16* ui_h, u16* ur, u16* w_n, u16* u_n,
    u16* ccat, u16* wo, u16* emb_bf, u16* xt_bf, float* ebias, float* cbias) {
  int seg = blockIdx.y;
  const float* src = nullptr; u16* dst = nullptr;
  const float* fsrc = nullptr; float* fdst = nullptr;
  int R = 0, Cs = 0, c0 = 0, C = 0, fn = 0;
  switch (seg) {
    case 0:  src = Wz_w; dst = wcat;              R = 512;  Cs = 1024; c0 = 0;   C = 512; break;
    case 1:  src = Wr_w; dst = wcat + 512 * 512;  R = 512;  Cs = 512;  c0 = 0;   C = 512; break;
    case 2:  src = Wh_w; dst = wcat + 1024 * 512; R = 512;  Cs = 1024; c0 = 0;   C = 512; break;
    case 3:  src = Ui_w; dst = wcat + 1536 * 512; R = 512;  Cs = 1024; c0 = 0;   C = 512; break;
    case 4:  src = Wz_w; dst = wz_h;              R = 512;  Cs = 1024; c0 = 512; C = 512; break;
    case 5:  src = Wh_w; dst = wh_h;              R = 512;  Cs = 1024; c0 = 512; C = 512; break;
    case 6:  src = Ui_w; dst = ui_h;              R = 512;  Cs = 1024; c0 = 512; C = 512; break;
    case 7:  src = Ur_w; dst = ur;                R = 512;  Cs = 512;  c0 = 0;   C = 512; break;
    case 8:  src = W_w;  dst = w_n;               R = 512;  Cs = 640;  c0 = 0;   C = 512; break;
    case 9:  src = U_w;  dst = u_n;               R = 512;  Cs = 640;  c0 = 0;   C = 512; break;
    case 10: src = W_w;  dst = ccat;              R = 512;  Cs = 640;  c0 = 512; C = 128; break;
    case 11: src = U_w;  dst = ccat + 512 * 128;  R = 512;  Cs = 640;  c0 = 512; C = 128; break;
    case 12: src = Wo_w; dst = wo;                R = 1024; Cs = 512;  c0 = 0;   C = 512; break;
    case 13: src = emb;  dst = emb_bf;            R = 1024; Cs = 512;  c0 = 0;   C = 512; break;
    case 14: src = xtree; dst = xt_bf;            R = 256;  Cs = 128;  c0 = 0;   C = 128; break;
    case 15: fsrc = Wz_b; fdst = ebias;        fn = 512; break;
    case 16: fsrc = Wr_b; fdst = ebias + 512;  fn = 512; break;
    case 17: fsrc = Wh_b; fdst = ebias + 1024; fn = 512; break;
    case 18: fsrc = Ui_b; fdst = ebias + 1536; fn = 512; break;
    case 19: fsrc = W_b;  fdst = cbias;        fn = 512; break;
    case 20: fsrc = U_b;  fdst = cbias + 512;  fn = 512; break;
  }
  int i = blockIdx.x * 256 + threadIdx.x;
  if (fdst) { if (i < fn) fdst[i] = fsrc[i]; return; }
  int e0 = i * 8;
  if (e0 >= R * C) return;
  int r = e0 / C, c = e0 - r * C;
  const float* s = src + (size_t)r * Cs + c0 + c;
  float4 a = *reinterpret_cast<const float4*>(s);
  float4 b = *reinterpret_cast<const float4*>(s + 4);
  uint4 o = {pk(a.x, a.y), pk(a.z, a.w), pk(b.x, b.y), pk(b.z, b.w)};
  *reinterpret_cast<uint4*>(&dst[e0]) = o;
}

// ---------------- flat f32 -> bf16, 8 elems/thread ----------------
__global__ void k_cvt8(const float* __restrict__ src, u16* __restrict__ dst) {
  size_t i = ((size_t)blockIdx.x * 256 + threadIdx.x) * 8;
  float4 a = *reinterpret_cast<const float4*>(src + i);
  float4 b = *reinterpret_cast<const float4*>(src + i + 4);
  uint4 o = {pk(a.x, a.y), pk(a.z, a.w), pk(b.x, b.y), pk(b.z, b.w)};
  *reinterpret_cast<uint4*>(dst + i) = o;
}

// ---------------- GEMM core: 128x128 tile, BK=64, dbuf, 8 waves of 64x32 ----
// N-major grid: blockIdx.x = N-tile, blockIdx.y = M-tile (adjacent blocks
// share the A-panel -> L2/L3 temporal locality). 512 thr, 16 waves/CU.
struct GP {
  const u16* A; const u16* B; int K;
  const float* gadd; int ldg; const int* gidx;
  const float* bias; const float* zf; const u16* shb;
  float* outf; u16* outh; int ldo;
};

template<int EP>
__device__ __forceinline__ void epi(int row, int col, float v, const GP& g) {
  if constexpr (EP == 0) {
    g.outf[(size_t)row * g.ldo + col] = v + (g.bias ? g.bias[col] : 0.f);
  } else if constexpr (EP == 1) {
    float pre = v + g.gadd[(size_t)g.gidx[row] * g.ldg + col];
    g.outf[(size_t)row * g.ldo + col] = sigm(pre);
  } else if constexpr (EP == 2) {
    float pre = tanhf(v + g.gadd[(size_t)g.gidx[row] * g.ldg + col]);
    float z = g.zf[(size_t)row * HDIM + col];
    float sh = bu2f(g.shb[(size_t)row * HDIM + col]);
    g.outh[(size_t)row * g.ldo + col] = f2bu((1.f - z) * sh + z * pre);
  } else if constexpr (EP == 3) {
    float pre = v + g.gadd[(size_t)g.gidx[row] * g.ldg + col];
    g.outh[(size_t)row * g.ldo + col] = f2bu(pre > 0.f ? pre : 0.f);
  } else {  // EP == 4: plain bf16 store
    g.outh[(size_t)row * g.ldo + col] = f2bu(v);
  }
}

template<int EP>
__device__ void gemm_core(const GP& g, u16* AsB, u16* BsB) {
  const int tid = threadIdx.x, lane = tid & 63, w = tid >> 6;  // 8 waves
  const int wm = (w >> 2) * 64, wn = (w & 3) * 32;
  const int n0 = blockIdx.x * 128, m0 = blockIdx.y * 128;
  const int K = g.K;

  // staging: 1024 16B-slots per tile; each thread stages 2 A + 2 B slots
  const u16* gA[2]; const u16* gB[2]; int ls[2];
#pragma unroll
  for (int i = 0; i < 2; i++) {
    int slot = tid + i * 512;
    int r = slot >> 3, c = (slot & 7) ^ (r & 7);
    gA[i] = g.A + (size_t)(m0 + r) * K + c * 8;
    gB[i] = g.B + (size_t)(n0 + r) * K + c * 8;
    ls[i] = slot * 8;
  }

  f4v acc[4][2];
  f4v z4 = {0.f, 0.f, 0.f, 0.f};
#pragma unroll
  for (int a = 0; a < 4; a++) { acc[a][0] = z4; acc[a][1] = z4; }

  const int T = K >> 6;
  // prologue: stage K-step 0 into buffer 0
#pragma unroll
  for (int i = 0; i < 2; i++) gl16(gA[i], AsB + ls[i]);
#pragma unroll
  for (int i = 0; i < 2; i++) gl16(gB[i], BsB + ls[i]);

  int cur = 0;
  for (int t = 0; t < T; t++) {
    __syncthreads();  // buf[cur] ready, buf[cur^1] free
    if (t + 1 < T) {
      int k0 = (t + 1) * 64;
      u16* as = AsB + (cur ^ 1) * 8192;
      u16* bs = BsB + (cur ^ 1) * 8192;
#pragma unroll
      for (int i = 0; i < 2; i++) gl16(gA[i] + k0, as + ls[i]);
#pragma unroll
      for (int i = 0; i < 2; i++) gl16(gB[i] + k0, bs + ls[i]);
    }
    const u16* as = AsB + cur * 8192;
    const u16* bs = BsB + cur * 8192;
#pragma unroll
    for (int ks = 0; ks < 2; ks++) {
      s8v af[4], bf[2];
      int cc = ks * 4 + (lane >> 4);
#pragma unroll
      for (int i = 0; i < 4; i++) {
        int R = wm + i * 16 + (lane & 15);
        af[i] = *reinterpret_cast<const s8v*>(&as[R * 64 + (cc ^ (R & 7)) * 8]);
      }
#pragma unroll
      for (int i = 0; i < 2; i++) {
        int C = wn + i * 16 + (lane & 15);
        bf[i] = *reinterpret_cast<const s8v*>(&bs[C * 64 + (cc ^ (C & 7)) * 8]);
      }
#pragma unroll
      for (int mi = 0; mi < 4; mi++)
#pragma unroll
        for (int ni = 0; ni < 2; ni++)
          acc[mi][ni] = __builtin_amdgcn_mfma_f32_16x16x32_bf16(
              af[mi], bf[ni], acc[mi][ni], 0, 0, 0);
    }
    cur ^= 1;
  }
#pragma unroll
  for (int mi = 0; mi < 4; mi++)
#pragma unroll
    for (int ni = 0; ni < 2; ni++)
#pragma unroll
      for (int r = 0; r < 4; r++) {
        int row = m0 + wm + mi * 16 + (lane >> 4) * 4 + r;
        int col = n0 + wn + ni * 16 + (lane & 15);
        epi<EP>(row, col, acc[mi][ni][r], g);
      }
}

template<int EP>
__global__ __launch_bounds__(512, 4) void k_gemm(GP g) {
  __shared__ u16 As[2 * 128 * 64], Bs[2 * 128 * 64];  // 64KB total
  gemm_core<EP>(g, As, Bs);
}

template<int EPa, int EPb>
__global__ __launch_bounds__(512, 4) void k_pair(GP a, GP b) {
  __shared__ u16 As[2 * 128 * 64], Bs[2 * 128 * 64];
  if (blockIdx.z == 0) gemm_core<EPa>(a, As, Bs);
  else gemm_core<EPb>(b, As, Bs);
}

// ---------------- fused gather: sum_h, sg (=Σ sigmoid(r2+E_r)·h), cur_o ----
__global__ __launch_bounds__(256) void k_gsr(
    const u16* __restrict__ Hb, const u16* __restrict__ R2,
    const float* __restrict__ E_r, int ldg, const int* __restrict__ x_ids,
    const int* __restrict__ nei_idx, const int* __restrict__ nei_mask,
    const int* __restrict__ o_idx, const int* __restrict__ o_mask,
    u16* __restrict__ sum_h_bf, u16* __restrict__ sg_bf,
    u16* __restrict__ cur_o_bf) {
  int n = blockIdx.x;
  int t = threadIdx.x;
  __shared__ int sidx[NB], smsk[NB], soid[NB], somk[NB];
  __shared__ int sx;
  if (t < NB) {
    sidx[t] = nei_idx[(size_t)n * NB + t];
    smsk[t] = nei_mask[(size_t)n * NB + t];
  } else if (t >= 64 && t < 64 + NB) {
    int k = t - 64;
    soid[k] = o_idx[(size_t)n * NB + k];
    somk[k] = o_mask[(size_t)n * NB + k];
  } else if (t == 128) {
    sx = x_ids[n];
  }
  __syncthreads();
  int c = t * 2;
  const float2 e = *reinterpret_cast<const float2*>(E_r + (size_t)sx * ldg + c);
  float s0 = 0.f, s1 = 0.f, g0 = 0.f, g1 = 0.f, o0 = 0.f, o1 = 0.f;
#pragma unroll
  for (int k = 0; k < NB; k++) {
    if (smsk[k]) {
      u32 hv = *reinterpret_cast<const u32*>(Hb + (size_t)sidx[k] * HDIM + c);
      u32 rv = *reinterpret_cast<const u32*>(R2 + (size_t)sidx[k] * HDIM + c);
      float h0 = bu2f((u16)hv), h1 = bu2f((u16)(hv >> 16));
      float r0 = sigm(bu2f((u16)rv) + e.x);
      float r1 = sigm(bu2f((u16)(rv >> 16)) + e.y);
      s0 += h0; s1 += h1;
      g0 += r0 * h0; g1 += r1 * h1;
    }
    if (somk[k]) {
      u32 v = *reinterpret_cast<const u32*>(Hb + (size_t)soid[k] * HDIM + c);
      o0 += bu2f((u16)v); o1 += bu2f((u16)(v >> 16));
    }
  }
  size_t b = (size_t)n * HDIM + c;
  *reinterpret_cast<u32*>(&sum_h_bf[b]) = pk(s0, s1);
  *reinterpret_cast<u32*>(&sg_bf[b]) = pk(g0, g1);
  *reinterpret_cast<u32*>(&cur_o_bf[b]) = pk(o0, o1);
}

// ---------------- stop score ----------------
__global__ __launch_bounds__(256) void k_stop(
    const u16* __restrict__ shid, const float* __restrict__ Uo_w,
    const float* __restrict__ Uo_b, float* __restrict__ out) {
  int n = blockIdx.x * 4 + (threadIdx.x >> 6);
  int lane = threadIdx.x & 63;
  float s = 0.f;
  for (int j = lane; j < HDIM; j += 64)
    s += bu2f(shid[(size_t)n * HDIM + j]) * Uo_w[j];
#pragma unroll
  for (int off = 32; off; off >>= 1) s += __shfl_xor(s, off, 64);
  if (lane == 0) out[(size_t)n * 1025 + 1024] = s + Uo_b[0];
}

// ---------------- host ----------------
extern "C" void kernel_launch(void* const* d_in, const int* in_sizes, int n_in,
                              void* d_out, int out_size, void* d_ws, size_t ws_size,
                              hipStream_t stream) {
  const int* x_ids = (const int*)d_in[0];
  const int* contexts = (const int*)d_in[1];
  const int* nei_idx = (const int*)d_in[2];
  const int* nei_mask = (const int*)d_in[3];
  const int* o_idx = (const int*)d_in[4];
  const int* o_mask = (const int*)d_in[5];
  const float* H_msg = (const float*)d_in[6];
  const float* xtree = (const float*)d_in[7];
  const float* emb = (const float*)d_in[8];
  const float* Wz_w = (const float*)d_in[9];  const float* Wz_b = (const float*)d_in[10];
  const float* Wr_w = (const float*)d_in[11]; const float* Wr_b = (const float*)d_in[12];
  const float* Ur_w = (const float*)d_in[13];
  const float* Wh_w = (const float*)d_in[14]; const float* Wh_b = (const float*)d_in[15];
  const float* W_w  = (const float*)d_in[16]; const float* W_b  = (const float*)d_in[17];
  const float* Wo_w = (const float*)d_in[18]; const float* Wo_b = (const float*)d_in[19];
  const float* Ui_w = (const float*)d_in[20]; const float* Ui_b = (const float*)d_in[21];
  const float* U_w  = (const float*)d_in[22]; const float* U_b  = (const float*)d_in[23];
  const float* Uo_w = (const float*)d_in[24]; const float* Uo_b = (const float*)d_in[25];
  float* out = (float*)d_out;
  const int M = 65536;

  char* base = (char*)d_ws;
  size_t ofs = 0;
  auto alloc = [&](size_t bytes) -> char* {
    char* p = base + ofs;
    ofs = (ofs + bytes + 255) & ~(size_t)255;
    return p;
  };
  u16* wcat  = (u16*)alloc((size_t)2048 * 512 * 2);
  u16* wz_h  = (u16*)alloc(512 * 512 * 2);
  u16* wh_h  = (u16*)alloc(512 * 512 * 2);
  u16* ui_h  = (u16*)alloc(512 * 512 * 2);
  u16* ur    = (u16*)alloc(512 * 512 * 2);
  u16* w_n   = (u16*)alloc(512 * 512 * 2);
  u16* u_n   = (u16*)alloc(512 * 512 * 2);
  u16* ccat  = (u16*)alloc(1024 * 128 * 2);
  u16* wo    = (u16*)alloc(1024 * 512 * 2);
  u16* emb_bf = (u16*)alloc(1024 * 512 * 2);
  u16* xt_bf  = (u16*)alloc(256 * 128 * 2);
  float* ebias = (float*)alloc(2048 * 4);
  float* cbias = (float*)alloc(1024 * 4);
  float* E_cat = (float*)alloc((size_t)1024 * 2048 * 4);
  float* C_cat = (float*)alloc((size_t)256 * 1024 * 4);
  u16* H_bf = (u16*)alloc((size_t)M * HDIM * 2);
  u16* R2   = (u16*)alloc((size_t)M * HDIM * 2);
  float* z_f = (float*)alloc((size_t)NNODE * HDIM * 4);
  u16* sum_h_bf = (u16*)alloc((size_t)NNODE * HDIM * 2);
  u16* cur_o_bf = (u16*)alloc((size_t)NNODE * HDIM * 2);
  u16* sg_bf    = (u16*)alloc((size_t)NNODE * HDIM * 2);
  u16* newh_bf  = (u16*)alloc((size_t)NNODE * HDIM * 2);
  u16* whid_bf  = (u16*)alloc((size_t)NNODE * HDIM * 2);
  u16* stoph_bf = (u16*)alloc((size_t)NNODE * HDIM * 2);
  u16* shid_bf  = (u16*)alloc((size_t)NNODE * HDIM * 2);

  k_cvt_all<<<dim3(256, 21), dim3(256), 0, stream>>>(
      Wz_w, Wr_w, Wh_w, Ui_w, Ur_w, W_w, U_w, Wo_w, emb, xtree,
      Wz_b, Wr_b, Wh_b, Ui_b, W_b, U_b,
      wcat, wz_h, wh_h, ui_h, ur, w_n, u_n, ccat, wo, emb_bf, xt_bf,
      ebias, cbias);
  k_cvt8<<<dim3(16384), dim3(256), 0, stream>>>(H_msg, H_bf);

  // E tables: [1024 x 2048] = emb @ [Wz_x|Wr|Wh_x|Ui_x]^T + [biases]
  GP ge{emb_bf, wcat, 512, nullptr, 0, nullptr, ebias, nullptr, nullptr,
        E_cat, nullptr, 2048};
  k_gemm<0><<<dim3(16, 8), dim3(512), 0, stream>>>(ge);
  // ctx tables: [256 x 1024] = xt @ [W_c|U_c]^T + [biases]
  GP gc{xt_bf, ccat, 128, nullptr, 0, nullptr, cbias, nullptr, nullptr,
        C_cat, nullptr, 1024};
  k_gemm<0><<<dim3(8, 2), dim3(512), 0, stream>>>(gc);

  // R2_all = H_msg @ Ur^T for ALL messages (dense, 34.4 GF) -> bf16
  GP gr{H_bf, ur, 512, nullptr, 0, nullptr, nullptr, nullptr, nullptr,
        nullptr, R2, 512};
  k_gemm<4><<<dim3(4, 512), dim3(512), 0, stream>>>(gr);

  // fused gather: sum_h, sg = sum sigmoid(R2+E_r)*h, cur_o
  k_gsr<<<dim3(NNODE), dim3(256), 0, stream>>>(
      H_bf, R2, E_cat + 512, 2048, x_ids, nei_idx, nei_mask, o_idx, o_mask,
      sum_h_bf, sg_bf, cur_o_bf);

  // z (EP1) + stop_h (EP3) paired
  GP gz{sum_h_bf, wz_h, 512, E_cat, 2048, x_ids, nullptr, nullptr, nullptr,
        z_f, nullptr, 512};
  GP gs{cur_o_bf, ui_h, 512, E_cat + 1536, 2048, x_ids, nullptr, nullptr, nullptr,
        nullptr, stoph_bf, 512};
  k_pair<1, 3><<<dim3(4, 128, 2), dim3(512), 0, stream>>>(gz, gs);

  // new_h (EP2): (1-z)*sum_h + z*tanh(sg @ Wh_h^T + E_h[x_ids])
  GP gn{sg_bf, wh_h, 512, E_cat + 1024, 2048, x_ids, nullptr, z_f, sum_h_bf,
        nullptr, newh_bf, 512};
  k_gemm<2><<<dim3(4, 128), dim3(512), 0, stream>>>(gn);

  // w_hid + s_hid paired (both EP3)
  GP gw{newh_bf, w_n, 512, C_cat, 1024, contexts, nullptr, nullptr, nullptr,
        nullptr, whid_bf, 512};
  GP gu{stoph_bf, u_n, 512, C_cat + 512, 1024, contexts, nullptr, nullptr, nullptr,
        nullptr, shid_bf, 512};
  k_pair<3, 3><<<dim3(4, 128, 2), dim3(512), 0, stream>>>(gw, gu);

  // word scores -> out[:, 0:1024] (row stride 1025)
  GP gword{whid_bf, wo, 512, nullptr, 0, nullptr, Wo_b, nullptr, nullptr,
           out, nullptr, 1025};
  k_gemm<0><<<dim3(8, 128), dim3(512), 0, stream>>>(gword);

  k_stop<<<dim3(NNODE / 4), dim3(256), 0, stream>>>(shid_bf, Uo_w, Uo_b, out);
}

// Round 9
// 333.034 us; speedup vs baseline: 2.4965x; 1.0749x over previous
//
#include <hip/hip_runtime.h>
#include <hip/hip_bf16.h>

typedef unsigned short u16;
typedef unsigned int u32;
typedef __attribute__((ext_vector_type(8))) short s8v;
typedef __attribute__((ext_vector_type(4))) float f4v;

#define HDIM 512
#define NNODE 16384
#define NB 15

__device__ __forceinline__ u16 f2bu(float x) {
  union { float f; u32 i; } v; v.f = x;
  u32 r = v.i + 0x7FFFu + ((v.i >> 16) & 1u);
  return (u16)(r >> 16);
}
__device__ __forceinline__ float bu2f(u16 u) {
  union { u32 i; float f; } v; v.i = ((u32)u) << 16;
  return v.f;
}
__device__ __forceinline__ u32 pk(float a, float b) {
  return (u32)f2bu(a) | ((u32)f2bu(b) << 16);
}
__device__ __forceinline__ float sigm(float x) {
  return __builtin_amdgcn_rcpf(1.f + __expf(-x));
}
__device__ __forceinline__ void gl16(const void* g, void* l) {
  __builtin_amdgcn_global_load_lds(
      (const __attribute__((address_space(1))) u32*)g,
      (__attribute__((address_space(3))) u32*)l, 16, 0, 0);
}

// ---------------- fused weight/bias conversion (21 segments) ----------------
__global__ __launch_bounds__(256) void k_cvt_all(
    const float* Wz_w, const float* Wr_w, const float* Wh_w, const float* Ui_w,
    const float* Ur_w, const float* W_w, const float* U_w, const float* Wo_w,
    const float* emb, const float* xtree,
    const float* Wz_b, const float* Wr_b, const float* Wh_b, const float* Ui_b,
    const float* W_b, const float* U_b,
    u16* wcat, u16* wz_h, u16* wh_h, u16* ui_h, u16* ur, u16* w_n, u16* u_n,
    u16* ccat, u16* wo, u16* emb_bf, u16* xt_bf, float* ebias, float* cbias) {
  int seg = blockIdx.y;
  const float* src = nullptr; u16* dst = nullptr;
  const float* fsrc = nullptr; float* fdst = nullptr;
  int R = 0, Cs = 0, c0 = 0, C = 0, fn = 0;
  switch (seg) {
    case 0:  src = Wz_w; dst = wcat;              R = 512;  Cs = 1024; c0 = 0;   C = 512; break;
    case 1:  src = Wr_w; dst = wcat + 512 * 512;  R = 512;  Cs = 512;  c0 = 0;   C = 512; break;
    case 2:  src = Wh_w; dst = wcat + 1024 * 512; R = 512;  Cs = 1024; c0 = 0;   C = 512; break;
    case 3:  src = Ui_w; dst = wcat + 1536 * 512; R = 512;  Cs = 1024; c0 = 0;   C = 512; break;
    case 4:  src = Wz_w; dst = wz_h;              R = 512;  Cs = 1024; c0 = 512; C = 512; break;
    case 5:  src = Wh_w; dst = wh_h;              R = 512;  Cs = 1024; c0 = 512; C = 512; break;
    case 6:  src = Ui_w; dst = ui_h;              R = 512;  Cs = 1024; c0 = 512; C = 512; break;
    case 7:  src = Ur_w; dst = ur;                R = 512;  Cs = 512;  c0 = 0;   C = 512; break;
    case 8:  src = W_w;  dst = w_n;               R = 512;  Cs = 640;  c0 = 0;   C = 512; break;
    case 9:  src = U_w;  dst = u_n;               R = 512;  Cs = 640;  c0 = 0;   C = 512; break;
    case 10: src = W_w;  dst = ccat;              R = 512;  Cs = 640;  c0 = 512; C = 128; break;
    case 11: src = U_w;  dst = ccat + 512 * 128;  R = 512;  Cs = 640;  c0 = 512; C = 128; break;
    case 12: src = Wo_w; dst = wo;                R = 1024; Cs = 512;  c0 = 0;   C = 512; break;
    case 13: src = emb;  dst = emb_bf;            R = 1024; Cs = 512;  c0 = 0;   C = 512; break;
    case 14: src = xtree; dst = xt_bf;            R = 256;  Cs = 128;  c0 = 0;   C = 128; break;
    case 15: fsrc = Wz_b; fdst = ebias;        fn = 512; break;
    case 16: fsrc = Wr_b; fdst = ebias + 512;  fn = 512; break;
    case 17: fsrc = Wh_b; fdst = ebias + 1024; fn = 512; break;
    case 18: fsrc = Ui_b; fdst = ebias + 1536; fn = 512; break;
    case 19: fsrc = W_b;  fdst = cbias;        fn = 512; break;
    case 20: fsrc = U_b;  fdst = cbias + 512;  fn = 512; break;
  }
  int i = blockIdx.x * 256 + threadIdx.x;
  if (fdst) { if (i < fn) fdst[i] = fsrc[i]; return; }
  int e0 = i * 8;
  if (e0 >= R * C) return;
  int r = e0 / C, c = e0 - r * C;
  const float* s = src + (size_t)r * Cs + c0 + c;
  float4 a = *reinterpret_cast<const float4*>(s);
  float4 b = *reinterpret_cast<const float4*>(s + 4);
  uint4 o = {pk(a.x, a.y), pk(a.z, a.w), pk(b.x, b.y), pk(b.z, b.w)};
  *reinterpret_cast<uint4*>(&dst[e0]) = o;
}

// ---------------- H f32 -> HR interleaved (cols 0..511 of [M][1024]) --------
__global__ void k_cvtH(const float* __restrict__ src, u16* __restrict__ HR) {
  size_t i = ((size_t)blockIdx.x * 256 + threadIdx.x) * 8;
  size_t m = i >> 9, c = i & 511;
  float4 a = *reinterpret_cast<const float4*>(src + i);
  float4 b = *reinterpret_cast<const float4*>(src + i + 4);
  uint4 o = {pk(a.x, a.y), pk(a.z, a.w), pk(b.x, b.y), pk(b.z, b.w)};
  *reinterpret_cast<uint4*>(&HR[m * 1024 + c]) = o;
}

// ---------------- GEMM core: 128x128 tile, BK=64, dbuf, 8 waves of 64x32 ----
// XCD-chunked swizzle (m157): XCD orig%8 processes contiguous tile range ->
// A-panel set stays in its private L2. N-major tile decomposition.
struct GP {
  const u16* A; const u16* B; int K; int lda;
  const float* gadd; int ldg; const int* gidx;
  const float* bias; const u16* shb;
  float* outf; u16* outh; int ldo;
};

template<int EP>
__device__ __forceinline__ void epi(int row, int col, float v, const GP& g) {
  if constexpr (EP == 0) {
    g.outf[(size_t)row * g.ldo + col] = v + (g.bias ? g.bias[col] : 0.f);
  } else if constexpr (EP == 3) {
    float pre = v + g.gadd[(size_t)g.gidx[row] * g.ldg + col];
    g.outh[(size_t)row * g.ldo + col] = f2bu(pre > 0.f ? pre : 0.f);
  } else {  // EP == 4: plain bf16 store
    g.outh[(size_t)row * g.ldo + col] = f2bu(v);
  }
}

template<int EP>
__device__ void gemm_core(const GP& g, u16* AsB, u16* BsB) {
  const int tid = threadIdx.x, lane = tid & 63, w = tid >> 6;  // 8 waves
  const int wm = (w >> 2) * 64, wn = (w & 3) * 32;
  const int nx = gridDim.x;
  int orig = blockIdx.y * nx + blockIdx.x;
  int q = (nx * gridDim.y) >> 3;
  int tile = (orig & 7) * q + (orig >> 3);
  const int n0 = (tile % nx) * 128, m0 = (tile / nx) * 128;
  const int K = g.K;

  const u16* gA[2]; const u16* gB[2]; int ls[2];
#pragma unroll
  for (int i = 0; i < 2; i++) {
    int slot = tid + i * 512;
    int r = slot >> 3, c = (slot & 7) ^ (r & 7);
    gA[i] = g.A + (size_t)(m0 + r) * g.lda + c * 8;
    gB[i] = g.B + (size_t)(n0 + r) * K + c * 8;
    ls[i] = slot * 8;
  }

  f4v acc[4][2];
  f4v z4 = {0.f, 0.f, 0.f, 0.f};
#pragma unroll
  for (int a = 0; a < 4; a++) { acc[a][0] = z4; acc[a][1] = z4; }

  const int T = K >> 6;
#pragma unroll
  for (int i = 0; i < 2; i++) gl16(gA[i], AsB + ls[i]);
#pragma unroll
  for (int i = 0; i < 2; i++) gl16(gB[i], BsB + ls[i]);

  int cur = 0;
  for (int t = 0; t < T; t++) {
    __syncthreads();  // buf[cur] ready, buf[cur^1] free
    if (t + 1 < T) {
      int k0 = (t + 1) * 64;
      u16* as = AsB + (cur ^ 1) * 8192;
      u16* bs = BsB + (cur ^ 1) * 8192;
#pragma unroll
      for (int i = 0; i < 2; i++) gl16(gA[i] + k0, as + ls[i]);
#pragma unroll
      for (int i = 0; i < 2; i++) gl16(gB[i] + k0, bs + ls[i]);
    }
    const u16* as = AsB + cur * 8192;
    const u16* bs = BsB + cur * 8192;
#pragma unroll
    for (int ks = 0; ks < 2; ks++) {
      s8v af[4], bf[2];
      int cc = ks * 4 + (lane >> 4);
#pragma unroll
      for (int i = 0; i < 4; i++) {
        int R = wm + i * 16 + (lane & 15);
        af[i] = *reinterpret_cast<const s8v*>(&as[R * 64 + (cc ^ (R & 7)) * 8]);
      }
#pragma unroll
      for (int i = 0; i < 2; i++) {
        int C = wn + i * 16 + (lane & 15);
        bf[i] = *reinterpret_cast<const s8v*>(&bs[C * 64 + (cc ^ (C & 7)) * 8]);
      }
#pragma unroll
      for (int mi = 0; mi < 4; mi++)
#pragma unroll
        for (int ni = 0; ni < 2; ni++)
          acc[mi][ni] = __builtin_amdgcn_mfma_f32_16x16x32_bf16(
              af[mi], bf[ni], acc[mi][ni], 0, 0, 0);
    }
    cur ^= 1;
  }
#pragma unroll
  for (int mi = 0; mi < 4; mi++)
#pragma unroll
    for (int ni = 0; ni < 2; ni++)
#pragma unroll
      for (int r = 0; r < 4; r++) {
        int row = m0 + wm + mi * 16 + (lane >> 4) * 4 + r;
        int col = n0 + wn + ni * 16 + (lane & 15);
        epi<EP>(row, col, acc[mi][ni][r], g);
      }
}

template<int EP>
__global__ __launch_bounds__(512, 4) void k_gemm(GP g) {
  __shared__ u16 As[2 * 128 * 64], Bs[2 * 128 * 64];  // 64KB total
  gemm_core<EP>(g, As, Bs);
}

template<int EPa, int EPb>
__global__ __launch_bounds__(512, 4) void k_pair(GP a, GP b) {
  __shared__ u16 As[2 * 128 * 64], Bs[2 * 128 * 64];
  if (blockIdx.z == 0) gemm_core<EPa>(a, As, Bs);
  else gemm_core<EPb>(b, As, Bs);
}

// ---------------- fused z+new_h: two K=512 contractions, one epilogue -------
// az = sum_h @ Wz_h^T, ah = sg @ Wh_h^T; new_h = (1-z)*sum_h + z*tanh(...).
// Kills the z_f round-trip (67 MB). 64KB single-buffered LDS, 8 waves 64x32.
__global__ __launch_bounds__(512, 4) void k_zn(
    const u16* __restrict__ sumh, const u16* __restrict__ sg,
    const u16* __restrict__ Wz, const u16* __restrict__ Wh,
    const float* __restrict__ E_z, const float* __restrict__ E_h, int ldg,
    const int* __restrict__ gidx, u16* __restrict__ newh) {
  __shared__ u16 As1[128 * 64], Bs1[128 * 64], As2[128 * 64], Bs2[128 * 64];
  const int tid = threadIdx.x, lane = tid & 63, w = tid >> 6;
  const int wm = (w >> 2) * 64, wn = (w & 3) * 32;
  const int nx = gridDim.x;
  int orig = blockIdx.y * nx + blockIdx.x;
  int q = (nx * gridDim.y) >> 3;
  int tile = (orig & 7) * q + (orig >> 3);
  const int n0 = (tile % nx) * 128, m0 = (tile / nx) * 128;

  const u16 *gA1[2], *gA2[2], *gB1[2], *gB2[2]; int ls[2];
#pragma unroll
  for (int i = 0; i < 2; i++) {
    int slot = tid + i * 512;
    int r = slot >> 3, c = (slot & 7) ^ (r & 7);
    gA1[i] = sumh + (size_t)(m0 + r) * HDIM + c * 8;
    gA2[i] = sg + (size_t)(m0 + r) * HDIM + c * 8;
    gB1[i] = Wz + (size_t)(n0 + r) * HDIM + c * 8;
    gB2[i] = Wh + (size_t)(n0 + r) * HDIM + c * 8;
    ls[i] = slot * 8;
  }

  f4v az[4][2], ah[4][2];
  f4v z4 = {0.f, 0.f, 0.f, 0.f};
#pragma unroll
  for (int a = 0; a < 4; a++) {
    az[a][0] = z4; az[a][1] = z4; ah[a][0] = z4; ah[a][1] = z4;
  }

  for (int k0 = 0; k0 < HDIM; k0 += 64) {
    __syncthreads();
#pragma unroll
    for (int i = 0; i < 2; i++) gl16(gA1[i] + k0, As1 + ls[i]);
#pragma unroll
    for (int i = 0; i < 2; i++) gl16(gB1[i] + k0, Bs1 + ls[i]);
#pragma unroll
    for (int i = 0; i < 2; i++) gl16(gA2[i] + k0, As2 + ls[i]);
#pragma unroll
    for (int i = 0; i < 2; i++) gl16(gB2[i] + k0, Bs2 + ls[i]);
    __syncthreads();
#pragma unroll
    for (int ks = 0; ks < 2; ks++) {
      int cc = ks * 4 + (lane >> 4);
      {  // z contraction (sequenced to bound live VGPRs)
        s8v af[4], bf[2];
#pragma unroll
        for (int i = 0; i < 4; i++) {
          int R = wm + i * 16 + (lane & 15);
          af[i] = *reinterpret_cast<const s8v*>(&As1[R * 64 + (cc ^ (R & 7)) * 8]);
        }
#pragma unroll
        for (int i = 0; i < 2; i++) {
          int C = wn + i * 16 + (lane & 15);
          bf[i] = *reinterpret_cast<const s8v*>(&Bs1[C * 64 + (cc ^ (C & 7)) * 8]);
        }
#pragma unroll
        for (int mi = 0; mi < 4; mi++)
#pragma unroll
          for (int ni = 0; ni < 2; ni++)
            az[mi][ni] = __builtin_amdgcn_mfma_f32_16x16x32_bf16(
                af[mi], bf[ni], az[mi][ni], 0, 0, 0);
      }
      {  // pre_h contraction
        s8v af[4], bf[2];
#pragma unroll
        for (int i = 0; i < 4; i++) {
          int R = wm + i * 16 + (lane & 15);
          af[i] = *reinterpret_cast<const s8v*>(&As2[R * 64 + (cc ^ (R & 7)) * 8]);
        }
#pragma unroll
        for (int i = 0; i < 2; i++) {
          int C = wn + i * 16 + (lane & 15);
          bf[i] = *reinterpret_cast<const s8v*>(&Bs2[C * 64 + (cc ^ (C & 7)) * 8]);
        }
#pragma unroll
        for (int mi = 0; mi < 4; mi++)
#pragma unroll
          for (int ni = 0; ni < 2; ni++)
            ah[mi][ni] = __builtin_amdgcn_mfma_f32_16x16x32_bf16(
                af[mi], bf[ni], ah[mi][ni], 0, 0, 0);
      }
    }
  }
#pragma unroll
  for (int mi = 0; mi < 4; mi++)
#pragma unroll
    for (int r = 0; r < 4; r++) {
      int row = m0 + wm + mi * 16 + (lane >> 4) * 4 + r;
      int xid = gidx[row];
      const float* ez = E_z + (size_t)xid * ldg;
      const float* eh = E_h + (size_t)xid * ldg;
#pragma unroll
      for (int ni = 0; ni < 2; ni++) {
        int col = n0 + wn + ni * 16 + (lane & 15);
        float zv = sigm(az[mi][ni][r] + ez[col]);
        float pre = tanhf(ah[mi][ni][r] + eh[col]);
        float sh = bu2f(sumh[(size_t)row * HDIM + col]);
        newh[(size_t)row * HDIM + col] = f2bu((1.f - zv) * sh + zv * pre);
      }
    }
}

// ---------------- fused gather: sum_h, sg (=Σ sigmoid(r2+E_r)·h), cur_o ----
// HR[m][0:512]=h, HR[m][512:1024]=r2 -> one 2KB row per message (page local).
__global__ __launch_bounds__(256) void k_gsr(
    const u16* __restrict__ HR,
    const float* __restrict__ E_r, int ldg, const int* __restrict__ x_ids,
    const int* __restrict__ nei_idx, const int* __restrict__ nei_mask,
    const int* __restrict__ o_idx, const int* __restrict__ o_mask,
    u16* __restrict__ sum_h_bf, u16* __restrict__ sg_bf,
    u16* __restrict__ cur_o_bf) {
  int n = blockIdx.x;
  int t = threadIdx.x;
  __shared__ int sidx[NB], smsk[NB], soid[NB], somk[NB];
  __shared__ int sx;
  if (t < NB) {
    sidx[t] = nei_idx[(size_t)n * NB + t];
    smsk[t] = nei_mask[(size_t)n * NB + t];
  } else if (t >= 64 && t < 64 + NB) {
    int k = t - 64;
    soid[k] = o_idx[(size_t)n * NB + k];
    somk[k] = o_mask[(size_t)n * NB + k];
  } else if (t == 128) {
    sx = x_ids[n];
  }
  __syncthreads();
  int c = t * 2;
  const float2 e = *reinterpret_cast<const float2*>(E_r + (size_t)sx * ldg + c);
  float s0 = 0.f, s1 = 0.f, g0 = 0.f, g1 = 0.f, o0 = 0.f, o1 = 0.f;
#pragma unroll
  for (int k = 0; k < NB; k++) {
    if (smsk[k]) {
      const u16* row = HR + (size_t)sidx[k] * 1024;
      u32 hv = *reinterpret_cast<const u32*>(row + c);
      u32 rv = *reinterpret_cast<const u32*>(row + 512 + c);
      float h0 = bu2f((u16)hv), h1 = bu2f((u16)(hv >> 16));
      float r0 = sigm(bu2f((u16)rv) + e.x);
      float r1 = sigm(bu2f((u16)(rv >> 16)) + e.y);
      s0 += h0; s1 += h1;
      g0 += r0 * h0; g1 += r1 * h1;
    }
    if (somk[k]) {
      u32 v = *reinterpret_cast<const u32*>(HR + (size_t)soid[k] * 1024 + c);
      o0 += bu2f((u16)v); o1 += bu2f((u16)(v >> 16));
    }
  }
  size_t b = (size_t)n * HDIM + c;
  *reinterpret_cast<u32*>(&sum_h_bf[b]) = pk(s0, s1);
  *reinterpret_cast<u32*>(&sg_bf[b]) = pk(g0, g1);
  *reinterpret_cast<u32*>(&cur_o_bf[b]) = pk(o0, o1);
}

// ---------------- stop score ----------------
__global__ __launch_bounds__(256) void k_stop(
    const u16* __restrict__ shid, const float* __restrict__ Uo_w,
    const float* __restrict__ Uo_b, float* __restrict__ out) {
  int n = blockIdx.x * 4 + (threadIdx.x >> 6);
  int lane = threadIdx.x & 63;
  float s = 0.f;
  for (int j = lane; j < HDIM; j += 64)
    s += bu2f(shid[(size_t)n * HDIM + j]) * Uo_w[j];
#pragma unroll
  for (int off = 32; off; off >>= 1) s += __shfl_xor(s, off, 64);
  if (lane == 0) out[(size_t)n * 1025 + 1024] = s + Uo_b[0];
}

// ---------------- host ----------------
extern "C" void kernel_launch(void* const* d_in, const int* in_sizes, int n_in,
                              void* d_out, int out_size, void* d_ws, size_t ws_size,
                              hipStream_t stream) {
  const int* x_ids = (const int*)d_in[0];
  const int* contexts = (const int*)d_in[1];
  const int* nei_idx = (const int*)d_in[2];
  const int* nei_mask = (const int*)d_in[3];
  const int* o_idx = (const int*)d_in[4];
  const int* o_mask = (const int*)d_in[5];
  const float* H_msg = (const float*)d_in[6];
  const float* xtree = (const float*)d_in[7];
  const float* emb = (const float*)d_in[8];
  const float* Wz_w = (const float*)d_in[9];  const float* Wz_b = (const float*)d_in[10];
  const float* Wr_w = (const float*)d_in[11]; const float* Wr_b = (const float*)d_in[12];
  const float* Ur_w = (const float*)d_in[13];
  const float* Wh_w = (const float*)d_in[14]; const float* Wh_b = (const float*)d_in[15];
  const float* W_w  = (const float*)d_in[16]; const float* W_b  = (const float*)d_in[17];
  const float* Wo_w = (const float*)d_in[18]; const float* Wo_b = (const float*)d_in[19];
  const float* Ui_w = (const float*)d_in[20]; const float* Ui_b = (const float*)d_in[21];
  const float* U_w  = (const float*)d_in[22]; const float* U_b  = (const float*)d_in[23];
  const float* Uo_w = (const float*)d_in[24]; const float* Uo_b = (const float*)d_in[25];
  float* out = (float*)d_out;
  const int M = 65536;

  char* base = (char*)d_ws;
  size_t ofs = 0;
  auto alloc = [&](size_t bytes) -> char* {
    char* p = base + ofs;
    ofs = (ofs + bytes + 255) & ~(size_t)255;
    return p;
  };
  u16* wcat  = (u16*)alloc((size_t)2048 * 512 * 2);
  u16* wz_h  = (u16*)alloc(512 * 512 * 2);
  u16* wh_h  = (u16*)alloc(512 * 512 * 2);
  u16* ui_h  = (u16*)alloc(512 * 512 * 2);
  u16* ur    = (u16*)alloc(512 * 512 * 2);
  u16* w_n   = (u16*)alloc(512 * 512 * 2);
  u16* u_n   = (u16*)alloc(512 * 512 * 2);
  u16* ccat  = (u16*)alloc(1024 * 128 * 2);
  u16* wo    = (u16*)alloc(1024 * 512 * 2);
  u16* emb_bf = (u16*)alloc(1024 * 512 * 2);
  u16* xt_bf  = (u16*)alloc(256 * 128 * 2);
  float* ebias = (float*)alloc(2048 * 4);
  float* cbias = (float*)alloc(1024 * 4);
  float* E_cat = (float*)alloc((size_t)1024 * 2048 * 4);
  float* C_cat = (float*)alloc((size_t)256 * 1024 * 4);
  u16* HR = (u16*)alloc((size_t)M * 1024 * 2);  // [m][0:512]=h, [512:1024]=r2
  u16* sum_h_bf = (u16*)alloc((size_t)NNODE * HDIM * 2);
  u16* cur_o_bf = (u16*)alloc((size_t)NNODE * HDIM * 2);
  u16* sg_bf    = (u16*)alloc((size_t)NNODE * HDIM * 2);
  u16* newh_bf  = (u16*)alloc((size_t)NNODE * HDIM * 2);
  u16* whid_bf  = (u16*)alloc((size_t)NNODE * HDIM * 2);
  u16* stoph_bf = (u16*)alloc((size_t)NNODE * HDIM * 2);
  u16* shid_bf  = (u16*)alloc((size_t)NNODE * HDIM * 2);

  k_cvt_all<<<dim3(256, 21), dim3(256), 0, stream>>>(
      Wz_w, Wr_w, Wh_w, Ui_w, Ur_w, W_w, U_w, Wo_w, emb, xtree,
      Wz_b, Wr_b, Wh_b, Ui_b, W_b, U_b,
      wcat, wz_h, wh_h, ui_h, ur, w_n, u_n, ccat, wo, emb_bf, xt_bf,
      ebias, cbias);
  k_cvtH<<<dim3(16384), dim3(256), 0, stream>>>(H_msg, HR);

  // E tables: [1024 x 2048] = emb @ [Wz_x|Wr|Wh_x|Ui_x]^T + [biases]
  GP ge{emb_bf, wcat, 512, 512, nullptr, 0, nullptr, ebias, nullptr,
        E_cat, nullptr, 2048};
  k_gemm<0><<<dim3(16, 8), dim3(512), 0, stream>>>(ge);
  // ctx tables: [256 x 1024] = xt @ [W_c|U_c]^T + [biases]
  GP gc{xt_bf, ccat, 128, 128, nullptr, 0, nullptr, cbias, nullptr,
        C_cat, nullptr, 1024};
  k_gemm<0><<<dim3(8, 2), dim3(512), 0, stream>>>(gc);

  // R2 = H @ Ur^T for ALL messages -> interleaved into HR[:,512:1024]
  GP gr{HR, ur, 512, 1024, nullptr, 0, nullptr, nullptr, nullptr,
        nullptr, HR + 512, 1024};
  k_gemm<4><<<dim3(4, 512), dim3(512), 0, stream>>>(gr);

  // fused gather: sum_h, sg = sum sigmoid(r2+E_r)*h, cur_o
  k_gsr<<<dim3(NNODE), dim3(256), 0, stream>>>(
      HR, E_cat + 512, 2048, x_ids, nei_idx, nei_mask, o_idx, o_mask,
      sum_h_bf, sg_bf, cur_o_bf);

  // stop_h = relu(cur_o @ Ui_h^T + E_i[x_ids])
  GP gs{cur_o_bf, ui_h, 512, 512, E_cat + 1536, 2048, x_ids, nullptr, nullptr,
        nullptr, stoph_bf, 512};
  k_gemm<3><<<dim3(4, 128), dim3(512), 0, stream>>>(gs);

  // fused z + new_h
  k_zn<<<dim3(4, 128), dim3(512), 0, stream>>>(
      sum_h_bf, sg_bf, wz_h, wh_h, E_cat, E_cat + 1024, 2048, x_ids, newh_bf);

  // w_hid + s_hid paired (both EP3)
  GP gw{newh_bf, w_n, 512, 512, C_cat, 1024, contexts, nullptr, nullptr,
        nullptr, whid_bf, 512};
  GP gu{stoph_bf, u_n, 512, 512, C_cat + 512, 1024, contexts, nullptr, nullptr,
        nullptr, shid_bf, 512};
  k_pair<3, 3><<<dim3(4, 128, 2), dim3(512), 0, stream>>>(gw, gu);

  // word scores -> out[:, 0:1024] (row stride 1025)
  GP gword{whid_bf, wo, 512, 512, nullptr, 0, nullptr, Wo_b, nullptr,
           out, nullptr, 1025};
  k_gemm<0><<<dim3(8, 128), dim3(512), 0, stream>>>(gword);

  k_stop<<<dim3(NNODE / 4), dim3(256), 0, stream>>>(shid_bf, Uo_w, Uo_b, out);
}

// Round 10
// 331.772 us; speedup vs baseline: 2.5060x; 1.0038x over previous
//
#include <hip/hip_runtime.h>
#include <hip/hip_bf16.h>

typedef unsigned short u16;
typedef unsigned int u32;
typedef __attribute__((ext_vector_type(8))) short s8v;
typedef __attribute__((ext_vector_type(4))) float f4v;

#define HDIM 512
#define NNODE 16384
#define NB 15

__device__ __forceinline__ u16 f2bu(float x) {
  union { float f; u32 i; } v; v.f = x;
  u32 r = v.i + 0x7FFFu + ((v.i >> 16) & 1u);
  return (u16)(r >> 16);
}
__device__ __forceinline__ float bu2f(u16 u) {
  union { u32 i; float f; } v; v.i = ((u32)u) << 16;
  return v.f;
}
__device__ __forceinline__ u32 pk(float a, float b) {
  return (u32)f2bu(a) | ((u32)f2bu(b) << 16);
}
__device__ __forceinline__ float sigm(float x) {
  return __builtin_amdgcn_rcpf(1.f + __expf(-x));
}
__device__ __forceinline__ void gl16(const void* g, void* l) {
  __builtin_amdgcn_global_load_lds(
      (const __attribute__((address_space(1))) u32*)g,
      (__attribute__((address_space(3))) u32*)l, 16, 0, 0);
}
template<int N> __device__ __forceinline__ void wait_vm() {
  if constexpr (N == 0) asm volatile("s_waitcnt vmcnt(0)" ::: "memory");
  else if constexpr (N == 2) asm volatile("s_waitcnt vmcnt(2)" ::: "memory");
  else asm volatile("s_waitcnt vmcnt(4)" ::: "memory");
}

// ---------------- fused weight/bias conversion (21 segments) ----------------
__global__ __launch_bounds__(256) void k_cvt_all(
    const float* Wz_w, const float* Wr_w, const float* Wh_w, const float* Ui_w,
    const float* Ur_w, const float* W_w, const float* U_w, const float* Wo_w,
    const float* emb, const float* xtree,
    const float* Wz_b, const float* Wr_b, const float* Wh_b, const float* Ui_b,
    const float* W_b, const float* U_b,
    u16* wcat, u16* wz_h, u16* wh_h, u16* ui_h, u16* ur, u16* w_n, u16* u_n,
    u16* ccat, u16* wo, u16* emb_bf, u16* xt_bf, float* ebias, float* cbias) {
  int seg = blockIdx.y;
  const float* src = nullptr; u16* dst = nullptr;
  const float* fsrc = nullptr; float* fdst = nullptr;
  int R = 0, Cs = 0, c0 = 0, C = 0, fn = 0;
  switch (seg) {
    case 0:  src = Wz_w; dst = wcat;              R = 512;  Cs = 1024; c0 = 0;   C = 512; break;
    case 1:  src = Wr_w; dst = wcat + 512 * 512;  R = 512;  Cs = 512;  c0 = 0;   C = 512; break;
    case 2:  src = Wh_w; dst = wcat + 1024 * 512; R = 512;  Cs = 1024; c0 = 0;   C = 512; break;
    case 3:  src = Ui_w; dst = wcat + 1536 * 512; R = 512;  Cs = 1024; c0 = 0;   C = 512; break;
    case 4:  src = Wz_w; dst = wz_h;              R = 512;  Cs = 1024; c0 = 512; C = 512; break;
    case 5:  src = Wh_w; dst = wh_h;              R = 512;  Cs = 1024; c0 = 512; C = 512; break;
    case 6:  src = Ui_w; dst = ui_h;              R = 512;  Cs = 1024; c0 = 512; C = 512; break;
    case 7:  src = Ur_w; dst = ur;                R = 512;  Cs = 512;  c0 = 0;   C = 512; break;
    case 8:  src = W_w;  dst = w_n;               R = 512;  Cs = 640;  c0 = 0;   C = 512; break;
    case 9:  src = U_w;  dst = u_n;               R = 512;  Cs = 640;  c0 = 0;   C = 512; break;
    case 10: src = W_w;  dst = ccat;              R = 512;  Cs = 640;  c0 = 512; C = 128; break;
    case 11: src = U_w;  dst = ccat + 512 * 128;  R = 512;  Cs = 640;  c0 = 512; C = 128; break;
    case 12: src = Wo_w; dst = wo;                R = 1024; Cs = 512;  c0 = 0;   C = 512; break;
    case 13: src = emb;  dst = emb_bf;            R = 1024; Cs = 512;  c0 = 0;   C = 512; break;
    case 14: src = xtree; dst = xt_bf;            R = 256;  Cs = 128;  c0 = 0;   C = 128; break;
    case 15: fsrc = Wz_b; fdst = ebias;        fn = 512; break;
    case 16: fsrc = Wr_b; fdst = ebias + 512;  fn = 512; break;
    case 17: fsrc = Wh_b; fdst = ebias + 1024; fn = 512; break;
    case 18: fsrc = Ui_b; fdst = ebias + 1536; fn = 512; break;
    case 19: fsrc = W_b;  fdst = cbias;        fn = 512; break;
    case 20: fsrc = U_b;  fdst = cbias + 512;  fn = 512; break;
  }
  int i = blockIdx.x * 256 + threadIdx.x;
  if (fdst) { if (i < fn) fdst[i] = fsrc[i]; return; }
  int e0 = i * 8;
  if (e0 >= R * C) return;
  int r = e0 / C, c = e0 - r * C;
  const float* s = src + (size_t)r * Cs + c0 + c;
  float4 a = *reinterpret_cast<const float4*>(s);
  float4 b = *reinterpret_cast<const float4*>(s + 4);
  uint4 o = {pk(a.x, a.y), pk(a.z, a.w), pk(b.x, b.y), pk(b.z, b.w)};
  *reinterpret_cast<uint4*>(&dst[e0]) = o;
}

// ---------------- H f32 -> HR interleaved (cols 0..511 of [M][1024]) --------
__global__ void k_cvtH(const float* __restrict__ src, u16* __restrict__ HR) {
  size_t i = ((size_t)blockIdx.x * 256 + threadIdx.x) * 8;
  size_t m = i >> 9, c = i & 511;
  float4 a = *reinterpret_cast<const float4*>(src + i);
  float4 b = *reinterpret_cast<const float4*>(src + i + 4);
  uint4 o = {pk(a.x, a.y), pk(a.z, a.w), pk(b.x, b.y), pk(b.z, b.w)};
  *reinterpret_cast<uint4*>(&HR[m * 1024 + c]) = o;
}

// ---------------- GEMM core: 128x128 tile, BK=32, 4-buf 3-deep pipeline ----
// Counted vmcnt (never 0 mid-loop) + raw s_barrier keeps 3 K-steps of
// global_load_lds in flight across barriers (T4). XCD-chunked swizzle,
// N-major. 8 waves of 64x32; 64KB LDS -> 2 blocks/CU (16 waves).
struct GP {
  const u16* A; const u16* B; int K; int lda;
  const float* gadd; int ldg; const int* gidx;
  const float* bias; const u16* shb;
  float* outf; u16* outh; int ldo;
};

template<int EP>
__device__ __forceinline__ void epi(int row, int col, float v, const GP& g) {
  if constexpr (EP == 0) {
    g.outf[(size_t)row * g.ldo + col] = v + (g.bias ? g.bias[col] : 0.f);
  } else if constexpr (EP == 3) {
    float pre = v + g.gadd[(size_t)g.gidx[row] * g.ldg + col];
    g.outh[(size_t)row * g.ldo + col] = f2bu(pre > 0.f ? pre : 0.f);
  } else {  // EP == 4: plain bf16 store
    g.outh[(size_t)row * g.ldo + col] = f2bu(v);
  }
}

template<int EP, int KV>
__device__ void gemm_core(const GP& g, u16* AsB, u16* BsB) {
  const int tid = threadIdx.x, lane = tid & 63, w = tid >> 6;  // 8 waves
  const int wm = (w >> 2) * 64, wn = (w & 3) * 32;
  const int nx = gridDim.x;
  int orig = blockIdx.y * nx + blockIdx.x;
  int q = (nx * gridDim.y) >> 3;
  int tile = (orig & 7) * q + (orig >> 3);
  const int n0 = (tile % nx) * 128, m0 = (tile / nx) * 128;

  // one 16B staging slot per thread per tensor per K-step (512 slots)
  const int sr = tid >> 2, sc = (tid & 3) ^ (sr & 3);
  const u16* gA = g.A + (size_t)(m0 + sr) * g.lda + sc * 8;
  const u16* gB = g.B + (size_t)(n0 + sr) * KV + sc * 8;
  const int ls = tid * 8;

  f4v acc[4][2];
  f4v z4 = {0.f, 0.f, 0.f, 0.f};
#pragma unroll
  for (int a = 0; a < 4; a++) { acc[a][0] = z4; acc[a][1] = z4; }

  constexpr int T = KV / 32;
  auto STAGE = [&](int t) {
    int buf = (t & 3) * 4096;
    gl16(gA + t * 32, AsB + buf + ls);
    gl16(gB + t * 32, BsB + buf + ls);
  };
  STAGE(0); STAGE(1); STAGE(2);  // 3 tiles in flight (T >= 4 always)

#pragma unroll
  for (int t = 0; t < T; t++) {
    if (t < T - 2) wait_vm<4>();        // tile t's 2 loads retired
    else if (t == T - 2) wait_vm<2>();
    else wait_vm<0>();
    __builtin_amdgcn_s_barrier();
    asm volatile("" ::: "memory");
    if (t + 3 < T) STAGE(t + 3);
    const u16* as = AsB + (t & 3) * 4096;
    const u16* bs = BsB + (t & 3) * 4096;
    s8v af[4], bf[2];
    int cc = lane >> 4;
#pragma unroll
    for (int i = 0; i < 4; i++) {
      int R = wm + i * 16 + (lane & 15);
      af[i] = *reinterpret_cast<const s8v*>(&as[R * 32 + (cc ^ (R & 3)) * 8]);
    }
#pragma unroll
    for (int i = 0; i < 2; i++) {
      int C = wn + i * 16 + (lane & 15);
      bf[i] = *reinterpret_cast<const s8v*>(&bs[C * 32 + (cc ^ (C & 3)) * 8]);
    }
#pragma unroll
    for (int mi = 0; mi < 4; mi++)
#pragma unroll
      for (int ni = 0; ni < 2; ni++)
        acc[mi][ni] = __builtin_amdgcn_mfma_f32_16x16x32_bf16(
            af[mi], bf[ni], acc[mi][ni], 0, 0, 0);
  }
#pragma unroll
  for (int mi = 0; mi < 4; mi++)
#pragma unroll
    for (int ni = 0; ni < 2; ni++)
#pragma unroll
      for (int r = 0; r < 4; r++) {
        int row = m0 + wm + mi * 16 + (lane >> 4) * 4 + r;
        int col = n0 + wn + ni * 16 + (lane & 15);
        epi<EP>(row, col, acc[mi][ni][r], g);
      }
}

template<int EP, int KV>
__global__ __launch_bounds__(512, 4) void k_gemm(GP g) {
  __shared__ u16 As[4 * 4096], Bs[4 * 4096];  // 64KB total
  gemm_core<EP, KV>(g, As, Bs);
}

template<int EPa, int EPb, int KV>
__global__ __launch_bounds__(512, 4) void k_pair(GP a, GP b) {
  __shared__ u16 As[4 * 4096], Bs[4 * 4096];
  if (blockIdx.z == 0) gemm_core<EPa, KV>(a, As, Bs);
  else gemm_core<EPb, KV>(b, As, Bs);
}

// ---------------- fused z+new_h: two K=512 contractions, one epilogue -------
__global__ __launch_bounds__(512, 4) void k_zn(
    const u16* __restrict__ sumh, const u16* __restrict__ sg,
    const u16* __restrict__ Wz, const u16* __restrict__ Wh,
    const float* __restrict__ E_z, const float* __restrict__ E_h, int ldg,
    const int* __restrict__ gidx, u16* __restrict__ newh) {
  __shared__ u16 As1[128 * 64], Bs1[128 * 64], As2[128 * 64], Bs2[128 * 64];
  const int tid = threadIdx.x, lane = tid & 63, w = tid >> 6;
  const int wm = (w >> 2) * 64, wn = (w & 3) * 32;
  const int nx = gridDim.x;
  int orig = blockIdx.y * nx + blockIdx.x;
  int q = (nx * gridDim.y) >> 3;
  int tile = (orig & 7) * q + (orig >> 3);
  const int n0 = (tile % nx) * 128, m0 = (tile / nx) * 128;

  const u16 *gA1[2], *gA2[2], *gB1[2], *gB2[2]; int ls[2];
#pragma unroll
  for (int i = 0; i < 2; i++) {
    int slot = tid + i * 512;
    int r = slot >> 3, c = (slot & 7) ^ (r & 7);
    gA1[i] = sumh + (size_t)(m0 + r) * HDIM + c * 8;
    gA2[i] = sg + (size_t)(m0 + r) * HDIM + c * 8;
    gB1[i] = Wz + (size_t)(n0 + r) * HDIM + c * 8;
    gB2[i] = Wh + (size_t)(n0 + r) * HDIM + c * 8;
    ls[i] = slot * 8;
  }

  f4v az[4][2], ah[4][2];
  f4v z4 = {0.f, 0.f, 0.f, 0.f};
#pragma unroll
  for (int a = 0; a < 4; a++) {
    az[a][0] = z4; az[a][1] = z4; ah[a][0] = z4; ah[a][1] = z4;
  }

  for (int k0 = 0; k0 < HDIM; k0 += 64) {
    __syncthreads();
#pragma unroll
    for (int i = 0; i < 2; i++) gl16(gA1[i] + k0, As1 + ls[i]);
#pragma unroll
    for (int i = 0; i < 2; i++) gl16(gB1[i] + k0, Bs1 + ls[i]);
#pragma unroll
    for (int i = 0; i < 2; i++) gl16(gA2[i] + k0, As2 + ls[i]);
#pragma unroll
    for (int i = 0; i < 2; i++) gl16(gB2[i] + k0, Bs2 + ls[i]);
    __syncthreads();
#pragma unroll
    for (int ks = 0; ks < 2; ks++) {
      int cc = ks * 4 + (lane >> 4);
      {
        s8v af[4], bf[2];
#pragma unroll
        for (int i = 0; i < 4; i++) {
          int R = wm + i * 16 + (lane & 15);
          af[i] = *reinterpret_cast<const s8v*>(&As1[R * 64 + (cc ^ (R & 7)) * 8]);
        }
#pragma unroll
        for (int i = 0; i < 2; i++) {
          int C = wn + i * 16 + (lane & 15);
          bf[i] = *reinterpret_cast<const s8v*>(&Bs1[C * 64 + (cc ^ (C & 7)) * 8]);
        }
#pragma unroll
        for (int mi = 0; mi < 4; mi++)
#pragma unroll
          for (int ni = 0; ni < 2; ni++)
            az[mi][ni] = __builtin_amdgcn_mfma_f32_16x16x32_bf16(
                af[mi], bf[ni], az[mi][ni], 0, 0, 0);
      }
      {
        s8v af[4], bf[2];
#pragma unroll
        for (int i = 0; i < 4; i++) {
          int R = wm + i * 16 + (lane & 15);
          af[i] = *reinterpret_cast<const s8v*>(&As2[R * 64 + (cc ^ (R & 7)) * 8]);
        }
#pragma unroll
        for (int i = 0; i < 2; i++) {
          int C = wn + i * 16 + (lane & 15);
          bf[i] = *reinterpret_cast<const s8v*>(&Bs2[C * 64 + (cc ^ (C & 7)) * 8]);
        }
#pragma unroll
        for (int mi = 0; mi < 4; mi++)
#pragma unroll
          for (int ni = 0; ni < 2; ni++)
            ah[mi][ni] = __builtin_amdgcn_mfma_f32_16x16x32_bf16(
                af[mi], bf[ni], ah[mi][ni], 0, 0, 0);
      }
    }
  }
#pragma unroll
  for (int mi = 0; mi < 4; mi++)
#pragma unroll
    for (int r = 0; r < 4; r++) {
      int row = m0 + wm + mi * 16 + (lane >> 4) * 4 + r;
      int xid = gidx[row];
      const float* ez = E_z + (size_t)xid * ldg;
      const float* eh = E_h + (size_t)xid * ldg;
#pragma unroll
      for (int ni = 0; ni < 2; ni++) {
        int col = n0 + wn + ni * 16 + (lane & 15);
        float zv = sigm(az[mi][ni][r] + ez[col]);
        float pre = tanhf(ah[mi][ni][r] + eh[col]);
        float sh = bu2f(sumh[(size_t)row * HDIM + col]);
        newh[(size_t)row * HDIM + col] = f2bu((1.f - zv) * sh + zv * pre);
      }
    }
}

// ---------------- fused gather: 2 nodes/block, 4 cols/thread, uint2 loads ---
__global__ __launch_bounds__(256) void k_gsr(
    const u16* __restrict__ HR,
    const float* __restrict__ E_r, int ldg, const int* __restrict__ x_ids,
    const int* __restrict__ nei_idx, const int* __restrict__ nei_mask,
    const int* __restrict__ o_idx, const int* __restrict__ o_mask,
    u16* __restrict__ sum_h_bf, u16* __restrict__ sg_bf,
    u16* __restrict__ cur_o_bf) {
  int t = threadIdx.x;
  int nd = t >> 7, lt = t & 127;
  int n = blockIdx.x * 2 + nd;
  __shared__ int sidx[2][NB], smsk[2][NB], soid[2][NB], somk[2][NB];
  __shared__ int sx[2];
  if (lt < NB) {
    sidx[nd][lt] = nei_idx[(size_t)n * NB + lt];
    smsk[nd][lt] = nei_mask[(size_t)n * NB + lt];
  } else if (lt >= 32 && lt < 32 + NB) {
    int k = lt - 32;
    soid[nd][k] = o_idx[(size_t)n * NB + k];
    somk[nd][k] = o_mask[(size_t)n * NB + k];
  } else if (lt == 64) {
    sx[nd] = x_ids[n];
  }
  __syncthreads();
  int c = lt * 4;
  float4 e = *reinterpret_cast<const float4*>(E_r + (size_t)sx[nd] * ldg + c);
  float s0 = 0.f, s1 = 0.f, s2 = 0.f, s3 = 0.f;
  float g0 = 0.f, g1 = 0.f, g2 = 0.f, g3 = 0.f;
  float o0 = 0.f, o1 = 0.f, o2 = 0.f, o3 = 0.f;
#pragma unroll
  for (int k = 0; k < NB; k++) {
    if (smsk[nd][k]) {
      const u16* row = HR + (size_t)sidx[nd][k] * 1024;
      uint2 hv = *reinterpret_cast<const uint2*>(row + c);
      uint2 rv = *reinterpret_cast<const uint2*>(row + 512 + c);
      float h0 = bu2f((u16)hv.x), h1 = bu2f((u16)(hv.x >> 16));
      float h2 = bu2f((u16)hv.y), h3 = bu2f((u16)(hv.y >> 16));
      s0 += h0; s1 += h1; s2 += h2; s3 += h3;
      g0 += sigm(bu2f((u16)rv.x) + e.x) * h0;
      g1 += sigm(bu2f((u16)(rv.x >> 16)) + e.y) * h1;
      g2 += sigm(bu2f((u16)rv.y) + e.z) * h2;
      g3 += sigm(bu2f((u16)(rv.y >> 16)) + e.w) * h3;
    }
    if (somk[nd][k]) {
      uint2 ov = *reinterpret_cast<const uint2*>(HR + (size_t)soid[nd][k] * 1024 + c);
      o0 += bu2f((u16)ov.x); o1 += bu2f((u16)(ov.x >> 16));
      o2 += bu2f((u16)ov.y); o3 += bu2f((u16)(ov.y >> 16));
    }
  }
  size_t b = (size_t)n * HDIM + c;
  uint2 ps = {pk(s0, s1), pk(s2, s3)};
  uint2 pg = {pk(g0, g1), pk(g2, g3)};
  uint2 po = {pk(o0, o1), pk(o2, o3)};
  *reinterpret_cast<uint2*>(&sum_h_bf[b]) = ps;
  *reinterpret_cast<uint2*>(&sg_bf[b]) = pg;
  *reinterpret_cast<uint2*>(&cur_o_bf[b]) = po;
}

// ---------------- stop score ----------------
__global__ __launch_bounds__(256) void k_stop(
    const u16* __restrict__ shid, const float* __restrict__ Uo_w,
    const float* __restrict__ Uo_b, float* __restrict__ out) {
  int n = blockIdx.x * 4 + (threadIdx.x >> 6);
  int lane = threadIdx.x & 63;
  float s = 0.f;
  for (int j = lane; j < HDIM; j += 64)
    s += bu2f(shid[(size_t)n * HDIM + j]) * Uo_w[j];
#pragma unroll
  for (int off = 32; off; off >>= 1) s += __shfl_xor(s, off, 64);
  if (lane == 0) out[(size_t)n * 1025 + 1024] = s + Uo_b[0];
}

// ---------------- host ----------------
extern "C" void kernel_launch(void* const* d_in, const int* in_sizes, int n_in,
                              void* d_out, int out_size, void* d_ws, size_t ws_size,
                              hipStream_t stream) {
  const int* x_ids = (const int*)d_in[0];
  const int* contexts = (const int*)d_in[1];
  const int* nei_idx = (const int*)d_in[2];
  const int* nei_mask = (const int*)d_in[3];
  const int* o_idx = (const int*)d_in[4];
  const int* o_mask = (const int*)d_in[5];
  const float* H_msg = (const float*)d_in[6];
  const float* xtree = (const float*)d_in[7];
  const float* emb = (const float*)d_in[8];
  const float* Wz_w = (const float*)d_in[9];  const float* Wz_b = (const float*)d_in[10];
  const float* Wr_w = (const float*)d_in[11]; const float* Wr_b = (const float*)d_in[12];
  const float* Ur_w = (const float*)d_in[13];
  const float* Wh_w = (const float*)d_in[14]; const float* Wh_b = (const float*)d_in[15];
  const float* W_w  = (const float*)d_in[16]; const float* W_b  = (const float*)d_in[17];
  const float* Wo_w = (const float*)d_in[18]; const float* Wo_b = (const float*)d_in[19];
  const float* Ui_w = (const float*)d_in[20]; const float* Ui_b = (const float*)d_in[21];
  const float* U_w  = (const float*)d_in[22]; const float* U_b  = (const float*)d_in[23];
  const float* Uo_w = (const float*)d_in[24]; const float* Uo_b = (const float*)d_in[25];
  float* out = (float*)d_out;
  const int M = 65536;

  char* base = (char*)d_ws;
  size_t ofs = 0;
  auto alloc = [&](size_t bytes) -> char* {
    char* p = base + ofs;
    ofs = (ofs + bytes + 255) & ~(size_t)255;
    return p;
  };
  u16* wcat  = (u16*)alloc((size_t)2048 * 512 * 2);
  u16* wz_h  = (u16*)alloc(512 * 512 * 2);
  u16* wh_h  = (u16*)alloc(512 * 512 * 2);
  u16* ui_h  = (u16*)alloc(512 * 512 * 2);
  u16* ur    = (u16*)alloc(512 * 512 * 2);
  u16* w_n   = (u16*)alloc(512 * 512 * 2);
  u16* u_n   = (u16*)alloc(512 * 512 * 2);
  u16* ccat  = (u16*)alloc(1024 * 128 * 2);
  u16* wo    = (u16*)alloc(1024 * 512 * 2);
  u16* emb_bf = (u16*)alloc(1024 * 512 * 2);
  u16* xt_bf  = (u16*)alloc(256 * 128 * 2);
  float* ebias = (float*)alloc(2048 * 4);
  float* cbias = (float*)alloc(1024 * 4);
  float* E_cat = (float*)alloc((size_t)1024 * 2048 * 4);
  float* C_cat = (float*)alloc((size_t)256 * 1024 * 4);
  u16* HR = (u16*)alloc((size_t)M * 1024 * 2);  // [m][0:512]=h, [512:1024]=r2
  u16* sum_h_bf = (u16*)alloc((size_t)NNODE * HDIM * 2);
  u16* cur_o_bf = (u16*)alloc((size_t)NNODE * HDIM * 2);
  u16* sg_bf    = (u16*)alloc((size_t)NNODE * HDIM * 2);
  u16* newh_bf  = (u16*)alloc((size_t)NNODE * HDIM * 2);
  u16* whid_bf  = (u16*)alloc((size_t)NNODE * HDIM * 2);
  u16* stoph_bf = (u16*)alloc((size_t)NNODE * HDIM * 2);
  u16* shid_bf  = (u16*)alloc((size_t)NNODE * HDIM * 2);

  k_cvt_all<<<dim3(256, 21), dim3(256), 0, stream>>>(
      Wz_w, Wr_w, Wh_w, Ui_w, Ur_w, W_w, U_w, Wo_w, emb, xtree,
      Wz_b, Wr_b, Wh_b, Ui_b, W_b, U_b,
      wcat, wz_h, wh_h, ui_h, ur, w_n, u_n, ccat, wo, emb_bf, xt_bf,
      ebias, cbias);
  k_cvtH<<<dim3(16384), dim3(256), 0, stream>>>(H_msg, HR);

  // E tables: [1024 x 2048] = emb @ [Wz_x|Wr|Wh_x|Ui_x]^T + [biases]
  GP ge{emb_bf, wcat, 512, 512, nullptr, 0, nullptr, ebias, nullptr,
        E_cat, nullptr, 2048};
  k_gemm<0, 512><<<dim3(16, 8), dim3(512), 0, stream>>>(ge);
  // ctx tables: [256 x 1024] = xt @ [W_c|U_c]^T + [biases]
  GP gc{xt_bf, ccat, 128, 128, nullptr, 0, nullptr, cbias, nullptr,
        C_cat, nullptr, 1024};
  k_gemm<0, 128><<<dim3(8, 2), dim3(512), 0, stream>>>(gc);

  // R2 = H @ Ur^T for ALL messages -> interleaved into HR[:,512:1024]
  GP gr{HR, ur, 512, 1024, nullptr, 0, nullptr, nullptr, nullptr,
        nullptr, HR + 512, 1024};
  k_gemm<4, 512><<<dim3(4, 512), dim3(512), 0, stream>>>(gr);

  // fused gather: sum_h, sg = sum sigmoid(r2+E_r)*h, cur_o
  k_gsr<<<dim3(NNODE / 2), dim3(256), 0, stream>>>(
      HR, E_cat + 512, 2048, x_ids, nei_idx, nei_mask, o_idx, o_mask,
      sum_h_bf, sg_bf, cur_o_bf);

  // stop_h = relu(cur_o @ Ui_h^T + E_i[x_ids])
  GP gs{cur_o_bf, ui_h, 512, 512, E_cat + 1536, 2048, x_ids, nullptr, nullptr,
        nullptr, stoph_bf, 512};
  k_gemm<3, 512><<<dim3(4, 128), dim3(512), 0, stream>>>(gs);

  // fused z + new_h
  k_zn<<<dim3(4, 128), dim3(512), 0, stream>>>(
      sum_h_bf, sg_bf, wz_h, wh_h, E_cat, E_cat + 1024, 2048, x_ids, newh_bf);

  // w_hid + s_hid paired (both EP3)
  GP gw{newh_bf, w_n, 512, 512, C_cat, 1024, contexts, nullptr, nullptr,
        nullptr, whid_bf, 512};
  GP gu{stoph_bf, u_n, 512, 512, C_cat + 512, 1024, contexts, nullptr, nullptr,
        nullptr, shid_bf, 512};
  k_pair<3, 3, 512><<<dim3(4, 128, 2), dim3(512), 0, stream>>>(gw, gu);

  // word scores -> out[:, 0:1024] (row stride 1025)
  GP gword{whid_bf, wo, 512, 512, nullptr, 0, nullptr, Wo_b, nullptr,
           out, nullptr, 1025};
  k_gemm<0, 512><<<dim3(8, 128), dim3(512), 0, stream>>>(gword);

  k_stop<<<dim3(NNODE / 4), dim3(256), 0, stream>>>(shid_bf, Uo_w, Uo_b, out);
}

// Round 11
// 320.135 us; speedup vs baseline: 2.5971x; 1.0364x over previous
//
#include <hip/hip_runtime.h>
#include <hip/hip_bf16.h>

typedef unsigned short u16;
typedef unsigned int u32;
typedef __attribute__((ext_vector_type(8))) short s8v;
typedef __attribute__((ext_vector_type(4))) float f4v;

#define HDIM 512
#define NNODE 16384
#define NB 15

__device__ __forceinline__ u16 f2bu(float x) {
  union { float f; u32 i; } v; v.f = x;
  u32 r = v.i + 0x7FFFu + ((v.i >> 16) & 1u);
  return (u16)(r >> 16);
}
__device__ __forceinline__ float bu2f(u16 u) {
  union { u32 i; float f; } v; v.i = ((u32)u) << 16;
  return v.f;
}
__device__ __forceinline__ u32 pk(float a, float b) {
  return (u32)f2bu(a) | ((u32)f2bu(b) << 16);
}
__device__ __forceinline__ float sigm(float x) {
  return __builtin_amdgcn_rcpf(1.f + __expf(-x));
}
__device__ __forceinline__ void gl16(const void* g, void* l) {
  __builtin_amdgcn_global_load_lds(
      (const __attribute__((address_space(1))) u32*)g,
      (__attribute__((address_space(3))) u32*)l, 16, 0, 0);
}
template<int N> __device__ __forceinline__ void wait_vm() {
  if constexpr (N == 0) asm volatile("s_waitcnt vmcnt(0)" ::: "memory");
  else if constexpr (N == 2) asm volatile("s_waitcnt vmcnt(2)" ::: "memory");
  else asm volatile("s_waitcnt vmcnt(4)" ::: "memory");
}

// ---------------- fused weight/bias conversion (21 segments) ----------------
__global__ __launch_bounds__(256) void k_cvt_all(
    const float* Wz_w, const float* Wr_w, const float* Wh_w, const float* Ui_w,
    const float* Ur_w, const float* W_w, const float* U_w, const float* Wo_w,
    const float* emb, const float* xtree,
    const float* Wz_b, const float* Wr_b, const float* Wh_b, const float* Ui_b,
    const float* W_b, const float* U_b,
    u16* wcat, u16* wz_h, u16* wh_h, u16* ui_h, u16* ur, u16* w_n, u16* u_n,
    u16* ccat, u16* wo, u16* emb_bf, u16* xt_bf, float* ebias, float* cbias) {
  int seg = blockIdx.y;
  const float* src = nullptr; u16* dst = nullptr;
  const float* fsrc = nullptr; float* fdst = nullptr;
  int R = 0, Cs = 0, c0 = 0, C = 0, fn = 0;
  switch (seg) {
    case 0:  src = Wz_w; dst = wcat;              R = 512;  Cs = 1024; c0 = 0;   C = 512; break;
    case 1:  src = Wr_w; dst = wcat + 512 * 512;  R = 512;  Cs = 512;  c0 = 0;   C = 512; break;
    case 2:  src = Wh_w; dst = wcat + 1024 * 512; R = 512;  Cs = 1024; c0 = 0;   C = 512; break;
    case 3:  src = Ui_w; dst = wcat + 1536 * 512; R = 512;  Cs = 1024; c0 = 0;   C = 512; break;
    case 4:  src = Wz_w; dst = wz_h;              R = 512;  Cs = 1024; c0 = 512; C = 512; break;
    case 5:  src = Wh_w; dst = wh_h;              R = 512;  Cs = 1024; c0 = 512; C = 512; break;
    case 6:  src = Ui_w; dst = ui_h;              R = 512;  Cs = 1024; c0 = 512; C = 512; break;
    case 7:  src = Ur_w; dst = ur;                R = 512;  Cs = 512;  c0 = 0;   C = 512; break;
    case 8:  src = W_w;  dst = w_n;               R = 512;  Cs = 640;  c0 = 0;   C = 512; break;
    case 9:  src = U_w;  dst = u_n;               R = 512;  Cs = 640;  c0 = 0;   C = 512; break;
    case 10: src = W_w;  dst = ccat;              R = 512;  Cs = 640;  c0 = 512; C = 128; break;
    case 11: src = U_w;  dst = ccat + 512 * 128;  R = 512;  Cs = 640;  c0 = 512; C = 128; break;
    case 12: src = Wo_w; dst = wo;                R = 1024; Cs = 512;  c0 = 0;   C = 512; break;
    case 13: src = emb;  dst = emb_bf;            R = 1024; Cs = 512;  c0 = 0;   C = 512; break;
    case 14: src = xtree; dst = xt_bf;            R = 256;  Cs = 128;  c0 = 0;   C = 128; break;
    case 15: fsrc = Wz_b; fdst = ebias;        fn = 512; break;
    case 16: fsrc = Wr_b; fdst = ebias + 512;  fn = 512; break;
    case 17: fsrc = Wh_b; fdst = ebias + 1024; fn = 512; break;
    case 18: fsrc = Ui_b; fdst = ebias + 1536; fn = 512; break;
    case 19: fsrc = W_b;  fdst = cbias;        fn = 512; break;
    case 20: fsrc = U_b;  fdst = cbias + 512;  fn = 512; break;
  }
  int i = blockIdx.x * 256 + threadIdx.x;
  if (fdst) { if (i < fn) fdst[i] = fsrc[i]; return; }
  int e0 = i * 8;
  if (e0 >= R * C) return;
  int r = e0 / C, c = e0 - r * C;
  const float* s = src + (size_t)r * Cs + c0 + c;
  float4 a = *reinterpret_cast<const float4*>(s);
  float4 b = *reinterpret_cast<const float4*>(s + 4);
  uint4 o = {pk(a.x, a.y), pk(a.z, a.w), pk(b.x, b.y), pk(b.z, b.w)};
  *reinterpret_cast<uint4*>(&dst[e0]) = o;
}

// ---------------- H f32 -> HR interleaved (cols 0..511 of [M][1024]) --------
__global__ void k_cvtH(const float* __restrict__ src, u16* __restrict__ HR) {
  size_t i = ((size_t)blockIdx.x * 256 + threadIdx.x) * 8;
  size_t m = i >> 9, c = i & 511;
  float4 a = *reinterpret_cast<const float4*>(src + i);
  float4 b = *reinterpret_cast<const float4*>(src + i + 4);
  uint4 o = {pk(a.x, a.y), pk(a.z, a.w), pk(b.x, b.y), pk(b.z, b.w)};
  *reinterpret_cast<uint4*>(&HR[m * 1024 + c]) = o;
}

// ---------------- GEMM core: 128x128 tile, BK=32, 4-buf 3-deep pipeline ----
struct GP {
  const u16* A; const u16* B; int K; int lda;
  const float* gadd; int ldg; const int* gidx;
  const float* bias; const u16* shb;
  float* outf; u16* outh; int ldo;
};

template<int EP>
__device__ __forceinline__ void epi(int row, int col, float v, const GP& g) {
  if constexpr (EP == 0) {
    g.outf[(size_t)row * g.ldo + col] = v + (g.bias ? g.bias[col] : 0.f);
  } else if constexpr (EP == 3) {
    float pre = v + g.gadd[(size_t)g.gidx[row] * g.ldg + col];
    g.outh[(size_t)row * g.ldo + col] = f2bu(pre > 0.f ? pre : 0.f);
  } else {  // EP == 4: plain bf16 store
    g.outh[(size_t)row * g.ldo + col] = f2bu(v);
  }
}

template<int EP, int KV>
__device__ void gemm_core(const GP& g, u16* AsB, u16* BsB) {
  const int tid = threadIdx.x, lane = tid & 63, w = tid >> 6;  // 8 waves
  const int wm = (w >> 2) * 64, wn = (w & 3) * 32;
  const int nx = gridDim.x;
  int orig = blockIdx.y * nx + blockIdx.x;
  int q = (nx * gridDim.y) >> 3;
  int tile = (orig & 7) * q + (orig >> 3);
  const int n0 = (tile % nx) * 128, m0 = (tile / nx) * 128;

  const int sr = tid >> 2, sc = (tid & 3) ^ (sr & 3);
  const u16* gA = g.A + (size_t)(m0 + sr) * g.lda + sc * 8;
  const u16* gB = g.B + (size_t)(n0 + sr) * KV + sc * 8;
  const int ls = tid * 8;

  f4v acc[4][2];
  f4v z4 = {0.f, 0.f, 0.f, 0.f};
#pragma unroll
  for (int a = 0; a < 4; a++) { acc[a][0] = z4; acc[a][1] = z4; }

  constexpr int T = KV / 32;
  auto STAGE = [&](int t) {
    int buf = (t & 3) * 4096;
    gl16(gA + t * 32, AsB + buf + ls);
    gl16(gB + t * 32, BsB + buf + ls);
  };
  STAGE(0); STAGE(1); STAGE(2);

#pragma unroll
  for (int t = 0; t < T; t++) {
    if (t < T - 2) wait_vm<4>();
    else if (t == T - 2) wait_vm<2>();
    else wait_vm<0>();
    __builtin_amdgcn_s_barrier();
    asm volatile("" ::: "memory");
    if (t + 3 < T) STAGE(t + 3);
    const u16* as = AsB + (t & 3) * 4096;
    const u16* bs = BsB + (t & 3) * 4096;
    s8v af[4], bf[2];
    int cc = lane >> 4;
#pragma unroll
    for (int i = 0; i < 4; i++) {
      int R = wm + i * 16 + (lane & 15);
      af[i] = *reinterpret_cast<const s8v*>(&as[R * 32 + (cc ^ (R & 3)) * 8]);
    }
#pragma unroll
    for (int i = 0; i < 2; i++) {
      int C = wn + i * 16 + (lane & 15);
      bf[i] = *reinterpret_cast<const s8v*>(&bs[C * 32 + (cc ^ (C & 3)) * 8]);
    }
    __builtin_amdgcn_s_setprio(1);
#pragma unroll
    for (int mi = 0; mi < 4; mi++)
#pragma unroll
      for (int ni = 0; ni < 2; ni++)
        acc[mi][ni] = __builtin_amdgcn_mfma_f32_16x16x32_bf16(
            af[mi], bf[ni], acc[mi][ni], 0, 0, 0);
    __builtin_amdgcn_s_setprio(0);
  }
#pragma unroll
  for (int mi = 0; mi < 4; mi++)
#pragma unroll
    for (int ni = 0; ni < 2; ni++)
#pragma unroll
      for (int r = 0; r < 4; r++) {
        int row = m0 + wm + mi * 16 + (lane >> 4) * 4 + r;
        int col = n0 + wn + ni * 16 + (lane & 15);
        epi<EP>(row, col, acc[mi][ni][r], g);
      }
}

template<int EP, int KV>
__global__ __launch_bounds__(512, 4) void k_gemm(GP g) {
  __shared__ u16 As[4 * 4096], Bs[4 * 4096];
  gemm_core<EP, KV>(g, As, Bs);
}

template<int EPa, int EPb, int KV>
__global__ __launch_bounds__(512, 4) void k_pair(GP a, GP b) {
  __shared__ u16 As[4 * 4096], Bs[4 * 4096];
  if (blockIdx.z == 0) gemm_core<EPa, KV>(a, As, Bs);
  else gemm_core<EPb, KV>(b, As, Bs);
}

// ---------------- fused z+new_h (z==0) + stop_h GEMM (z==1) -----------------
__global__ __launch_bounds__(512, 4) void k_znp(
    const u16* __restrict__ sumh, const u16* __restrict__ sg,
    const u16* __restrict__ Wz, const u16* __restrict__ Wh,
    const float* __restrict__ E_z, const float* __restrict__ E_h, int ldg,
    const int* __restrict__ gidx, u16* __restrict__ newh, GP gs) {
  __shared__ u16 S[32768];  // 64 KB shared between the two block roles
  if (blockIdx.z == 1) { gemm_core<3, 512>(gs, S, S + 16384); return; }
  u16* As1 = S; u16* Bs1 = S + 8192;
  u16* As2 = S + 16384; u16* Bs2 = S + 24576;
  const int tid = threadIdx.x, lane = tid & 63, w = tid >> 6;
  const int wm = (w >> 2) * 64, wn = (w & 3) * 32;
  const int nx = gridDim.x;
  int orig = blockIdx.y * nx + blockIdx.x;
  int q = (nx * gridDim.y) >> 3;
  int tile = (orig & 7) * q + (orig >> 3);
  const int n0 = (tile % nx) * 128, m0 = (tile / nx) * 128;

  const u16 *gA1[2], *gA2[2], *gB1[2], *gB2[2]; int ls[2];
#pragma unroll
  for (int i = 0; i < 2; i++) {
    int slot = tid + i * 512;
    int r = slot >> 3, c = (slot & 7) ^ (r & 7);
    gA1[i] = sumh + (size_t)(m0 + r) * HDIM + c * 8;
    gA2[i] = sg + (size_t)(m0 + r) * HDIM + c * 8;
    gB1[i] = Wz + (size_t)(n0 + r) * HDIM + c * 8;
    gB2[i] = Wh + (size_t)(n0 + r) * HDIM + c * 8;
    ls[i] = slot * 8;
  }

  f4v az[4][2], ah[4][2];
  f4v z4 = {0.f, 0.f, 0.f, 0.f};
#pragma unroll
  for (int a = 0; a < 4; a++) {
    az[a][0] = z4; az[a][1] = z4; ah[a][0] = z4; ah[a][1] = z4;
  }

  for (int k0 = 0; k0 < HDIM; k0 += 64) {
    __syncthreads();
#pragma unroll
    for (int i = 0; i < 2; i++) gl16(gA1[i] + k0, As1 + ls[i]);
#pragma unroll
    for (int i = 0; i < 2; i++) gl16(gB1[i] + k0, Bs1 + ls[i]);
#pragma unroll
    for (int i = 0; i < 2; i++) gl16(gA2[i] + k0, As2 + ls[i]);
#pragma unroll
    for (int i = 0; i < 2; i++) gl16(gB2[i] + k0, Bs2 + ls[i]);
    __syncthreads();
#pragma unroll
    for (int ks = 0; ks < 2; ks++) {
      int cc = ks * 4 + (lane >> 4);
      {
        s8v af[4], bf[2];
#pragma unroll
        for (int i = 0; i < 4; i++) {
          int R = wm + i * 16 + (lane & 15);
          af[i] = *reinterpret_cast<const s8v*>(&As1[R * 64 + (cc ^ (R & 7)) * 8]);
        }
#pragma unroll
        for (int i = 0; i < 2; i++) {
          int C = wn + i * 16 + (lane & 15);
          bf[i] = *reinterpret_cast<const s8v*>(&Bs1[C * 64 + (cc ^ (C & 7)) * 8]);
        }
        __builtin_amdgcn_s_setprio(1);
#pragma unroll
        for (int mi = 0; mi < 4; mi++)
#pragma unroll
          for (int ni = 0; ni < 2; ni++)
            az[mi][ni] = __builtin_amdgcn_mfma_f32_16x16x32_bf16(
                af[mi], bf[ni], az[mi][ni], 0, 0, 0);
        __builtin_amdgcn_s_setprio(0);
      }
      {
        s8v af[4], bf[2];
#pragma unroll
        for (int i = 0; i < 4; i++) {
          int R = wm + i * 16 + (lane & 15);
          af[i] = *reinterpret_cast<const s8v*>(&As2[R * 64 + (cc ^ (R & 7)) * 8]);
        }
#pragma unroll
        for (int i = 0; i < 2; i++) {
          int C = wn + i * 16 + (lane & 15);
          bf[i] = *reinterpret_cast<const s8v*>(&Bs2[C * 64 + (cc ^ (C & 7)) * 8]);
        }
        __builtin_amdgcn_s_setprio(1);
#pragma unroll
        for (int mi = 0; mi < 4; mi++)
#pragma unroll
          for (int ni = 0; ni < 2; ni++)
            ah[mi][ni] = __builtin_amdgcn_mfma_f32_16x16x32_bf16(
                af[mi], bf[ni], ah[mi][ni], 0, 0, 0);
        __builtin_amdgcn_s_setprio(0);
      }
    }
  }
#pragma unroll
  for (int mi = 0; mi < 4; mi++)
#pragma unroll
    for (int r = 0; r < 4; r++) {
      int row = m0 + wm + mi * 16 + (lane >> 4) * 4 + r;
      int xid = gidx[row];
      const float* ez = E_z + (size_t)xid * ldg;
      const float* eh = E_h + (size_t)xid * ldg;
#pragma unroll
      for (int ni = 0; ni < 2; ni++) {
        int col = n0 + wn + ni * 16 + (lane & 15);
        float zv = sigm(az[mi][ni][r] + ez[col]);
        float pre = tanhf(ah[mi][ni][r] + eh[col]);
        float sh = bu2f(sumh[(size_t)row * HDIM + col]);
        newh[(size_t)row * HDIM + col] = f2bu((1.f - zv) * sh + zv * pre);
      }
    }
}

// ---------------- fused gather: 4 nodes/block, 64 thr/node, uint4 loads -----
// One wave per node: each masked row is one fully-coalesced 1KB wave burst.
__global__ __launch_bounds__(256) void k_gsr(
    const u16* __restrict__ HR,
    const float* __restrict__ E_r, int ldg, const int* __restrict__ x_ids,
    const int* __restrict__ nei_idx, const int* __restrict__ nei_mask,
    const int* __restrict__ o_idx, const int* __restrict__ o_mask,
    u16* __restrict__ sum_h_bf, u16* __restrict__ sg_bf,
    u16* __restrict__ cur_o_bf) {
  int t = threadIdx.x;
  int nd = t >> 6, lane = t & 63;
  int n = blockIdx.x * 4 + nd;
  __shared__ int sidx[4][NB], smsk[4][NB], soid[4][NB], somk[4][NB];
  __shared__ int sx[4];
  if (t < 60) {
    int nn = t / 15, k = t - nn * 15;
    size_t gofs = (size_t)(blockIdx.x * 4 + nn) * NB + k;
    sidx[nn][k] = nei_idx[gofs];
    smsk[nn][k] = nei_mask[gofs];
  } else if (t >= 64 && t < 124) {
    int tt = t - 64;
    int nn = tt / 15, k = tt - nn * 15;
    size_t gofs = (size_t)(blockIdx.x * 4 + nn) * NB + k;
    soid[nn][k] = o_idx[gofs];
    somk[nn][k] = o_mask[gofs];
  } else if (t >= 128 && t < 132) {
    sx[t - 128] = x_ids[blockIdx.x * 4 + (t - 128)];
  }
  __syncthreads();
  int c = lane * 8;
  const float* er = E_r + (size_t)sx[nd] * ldg + c;
  float4 e0 = *reinterpret_cast<const float4*>(er);
  float4 e1 = *reinterpret_cast<const float4*>(er + 4);
  float ev[8] = {e0.x, e0.y, e0.z, e0.w, e1.x, e1.y, e1.z, e1.w};
  float s[8], gg[8], oo[8];
#pragma unroll
  for (int i = 0; i < 8; i++) { s[i] = 0.f; gg[i] = 0.f; oo[i] = 0.f; }
#pragma unroll
  for (int k = 0; k < NB; k++) {
    if (smsk[nd][k]) {
      const u16* row = HR + (size_t)sidx[nd][k] * 1024 + c;
      uint4 hv = *reinterpret_cast<const uint4*>(row);
      uint4 rv = *reinterpret_cast<const uint4*>(row + 512);
      u32 ha[4] = {hv.x, hv.y, hv.z, hv.w};
      u32 ra[4] = {rv.x, rv.y, rv.z, rv.w};
#pragma unroll
      for (int p = 0; p < 4; p++) {
        float h0 = bu2f((u16)ha[p]), h1 = bu2f((u16)(ha[p] >> 16));
        s[p * 2] += h0; s[p * 2 + 1] += h1;
        gg[p * 2] += sigm(bu2f((u16)ra[p]) + ev[p * 2]) * h0;
        gg[p * 2 + 1] += sigm(bu2f((u16)(ra[p] >> 16)) + ev[p * 2 + 1]) * h1;
      }
    }
    if (somk[nd][k]) {
      uint4 ov = *reinterpret_cast<const uint4*>(
          HR + (size_t)soid[nd][k] * 1024 + c);
      u32 oa[4] = {ov.x, ov.y, ov.z, ov.w};
#pragma unroll
      for (int p = 0; p < 4; p++) {
        oo[p * 2] += bu2f((u16)oa[p]);
        oo[p * 2 + 1] += bu2f((u16)(oa[p] >> 16));
      }
    }
  }
  size_t b = (size_t)n * HDIM + c;
  uint4 ps = {pk(s[0], s[1]), pk(s[2], s[3]), pk(s[4], s[5]), pk(s[6], s[7])};
  uint4 pg = {pk(gg[0], gg[1]), pk(gg[2], gg[3]), pk(gg[4], gg[5]), pk(gg[6], gg[7])};
  uint4 po = {pk(oo[0], oo[1]), pk(oo[2], oo[3]), pk(oo[4], oo[5]), pk(oo[6], oo[7])};
  *reinterpret_cast<uint4*>(&sum_h_bf[b]) = ps;
  *reinterpret_cast<uint4*>(&sg_bf[b]) = pg;
  *reinterpret_cast<uint4*>(&cur_o_bf[b]) = po;
}

// ---------------- word GEMM (z==0) + stop scores (z==1) ---------------------
__global__ __launch_bounds__(512, 4) void k_wordstop(
    GP wgp, const u16* __restrict__ shid, const float* __restrict__ Uo_w,
    const float* __restrict__ Uo_b, float* __restrict__ out) {
  __shared__ u16 As[4 * 4096], Bs[4 * 4096];
  if (blockIdx.z == 0) { gemm_core<0, 512>(wgp, As, Bs); return; }
  // stop: 1024 blocks x 16 nodes; 8 waves x 2 nodes each
  int b = blockIdx.y * gridDim.x + blockIdx.x;  // 0..1023
  int wv = threadIdx.x >> 6, lane = threadIdx.x & 63;
#pragma unroll
  for (int i = 0; i < 2; i++) {
    int n = b * 16 + wv * 2 + i;
    const u16* row = shid + (size_t)n * HDIM + lane * 8;
    const float* uw = Uo_w + lane * 8;
    uint4 v = *reinterpret_cast<const uint4*>(row);
    float4 u0 = *reinterpret_cast<const float4*>(uw);
    float4 u1 = *reinterpret_cast<const float4*>(uw + 4);
    float s = bu2f((u16)v.x) * u0.x + bu2f((u16)(v.x >> 16)) * u0.y +
              bu2f((u16)v.y) * u0.z + bu2f((u16)(v.y >> 16)) * u0.w +
              bu2f((u16)v.z) * u1.x + bu2f((u16)(v.z >> 16)) * u1.y +
              bu2f((u16)v.w) * u1.z + bu2f((u16)(v.w >> 16)) * u1.w;
#pragma unroll
    for (int off = 32; off; off >>= 1) s += __shfl_xor(s, off, 64);
    if (lane == 0) out[(size_t)n * 1025 + 1024] = s + Uo_b[0];
  }
}

// ---------------- host ----------------
extern "C" void kernel_launch(void* const* d_in, const int* in_sizes, int n_in,
                              void* d_out, int out_size, void* d_ws, size_t ws_size,
                              hipStream_t stream) {
  const int* x_ids = (const int*)d_in[0];
  const int* contexts = (const int*)d_in[1];
  const int* nei_idx = (const int*)d_in[2];
  const int* nei_mask = (const int*)d_in[3];
  const int* o_idx = (const int*)d_in[4];
  const int* o_mask = (const int*)d_in[5];
  const float* H_msg = (const float*)d_in[6];
  const float* xtree = (const float*)d_in[7];
  const float* emb = (const float*)d_in[8];
  const float* Wz_w = (const float*)d_in[9];  const float* Wz_b = (const float*)d_in[10];
  const float* Wr_w = (const float*)d_in[11]; const float* Wr_b = (const float*)d_in[12];
  const float* Ur_w = (const float*)d_in[13];
  const float* Wh_w = (const float*)d_in[14]; const float* Wh_b = (const float*)d_in[15];
  const float* W_w  = (const float*)d_in[16]; const float* W_b  = (const float*)d_in[17];
  const float* Wo_w = (const float*)d_in[18]; const float* Wo_b = (const float*)d_in[19];
  const float* Ui_w = (const float*)d_in[20]; const float* Ui_b = (const float*)d_in[21];
  const float* U_w  = (const float*)d_in[22]; const float* U_b  = (const float*)d_in[23];
  const float* Uo_w = (const float*)d_in[24]; const float* Uo_b = (const float*)d_in[25];
  float* out = (float*)d_out;
  const int M = 65536;

  char* base = (char*)d_ws;
  size_t ofs = 0;
  auto alloc = [&](size_t bytes) -> char* {
    char* p = base + ofs;
    ofs = (ofs + bytes + 255) & ~(size_t)255;
    return p;
  };
  u16* wcat  = (u16*)alloc((size_t)2048 * 512 * 2);
  u16* wz_h  = (u16*)alloc(512 * 512 * 2);
  u16* wh_h  = (u16*)alloc(512 * 512 * 2);
  u16* ui_h  = (u16*)alloc(512 * 512 * 2);
  u16* ur    = (u16*)alloc(512 * 512 * 2);
  u16* w_n   = (u16*)alloc(512 * 512 * 2);
  u16* u_n   = (u16*)alloc(512 * 512 * 2);
  u16* ccat  = (u16*)alloc(1024 * 128 * 2);
  u16* wo    = (u16*)alloc(1024 * 512 * 2);
  u16* emb_bf = (u16*)alloc(1024 * 512 * 2);
  u16* xt_bf  = (u16*)alloc(256 * 128 * 2);
  float* ebias = (float*)alloc(2048 * 4);
  float* cbias = (float*)alloc(1024 * 4);
  float* E_cat = (float*)alloc((size_t)1024 * 2048 * 4);
  float* C_cat = (float*)alloc((size_t)256 * 1024 * 4);
  u16* HR = (u16*)alloc((size_t)M * 1024 * 2);  // [m][0:512]=h, [512:1024]=r2
  u16* sum_h_bf = (u16*)alloc((size_t)NNODE * HDIM * 2);
  u16* cur_o_bf = (u16*)alloc((size_t)NNODE * HDIM * 2);
  u16* sg_bf    = (u16*)alloc((size_t)NNODE * HDIM * 2);
  u16* newh_bf  = (u16*)alloc((size_t)NNODE * HDIM * 2);
  u16* whid_bf  = (u16*)alloc((size_t)NNODE * HDIM * 2);
  u16* stoph_bf = (u16*)alloc((size_t)NNODE * HDIM * 2);
  u16* shid_bf  = (u16*)alloc((size_t)NNODE * HDIM * 2);

  k_cvt_all<<<dim3(256, 21), dim3(256), 0, stream>>>(
      Wz_w, Wr_w, Wh_w, Ui_w, Ur_w, W_w, U_w, Wo_w, emb, xtree,
      Wz_b, Wr_b, Wh_b, Ui_b, W_b, U_b,
      wcat, wz_h, wh_h, ui_h, ur, w_n, u_n, ccat, wo, emb_bf, xt_bf,
      ebias, cbias);
  k_cvtH<<<dim3(16384), dim3(256), 0, stream>>>(H_msg, HR);

  // E tables: [1024 x 2048] = emb @ [Wz_x|Wr|Wh_x|Ui_x]^T + [biases]
  GP ge{emb_bf, wcat, 512, 512, nullptr, 0, nullptr, ebias, nullptr,
        E_cat, nullptr, 2048};
  k_gemm<0, 512><<<dim3(16, 8), dim3(512), 0, stream>>>(ge);
  // ctx tables: [256 x 1024] = xt @ [W_c|U_c]^T + [biases]
  GP gc{xt_bf, ccat, 128, 128, nullptr, 0, nullptr, cbias, nullptr,
        C_cat, nullptr, 1024};
  k_gemm<0, 128><<<dim3(8, 2), dim3(512), 0, stream>>>(gc);

  // R2 = H @ Ur^T for ALL messages -> interleaved into HR[:,512:1024]
  GP gr{HR, ur, 512, 1024, nullptr, 0, nullptr, nullptr, nullptr,
        nullptr, HR + 512, 1024};
  k_gemm<4, 512><<<dim3(4, 512), dim3(512), 0, stream>>>(gr);

  // fused gather: sum_h, sg = sum sigmoid(r2+E_r)*h, cur_o
  k_gsr<<<dim3(NNODE / 4), dim3(256), 0, stream>>>(
      HR, E_cat + 512, 2048, x_ids, nei_idx, nei_mask, o_idx, o_mask,
      sum_h_bf, sg_bf, cur_o_bf);

  // z+new_h (z==0) and stop_h (z==1) in one dispatch
  GP gs{cur_o_bf, ui_h, 512, 512, E_cat + 1536, 2048, x_ids, nullptr, nullptr,
        nullptr, stoph_bf, 512};
  k_znp<<<dim3(4, 128, 2), dim3(512), 0, stream>>>(
      sum_h_bf, sg_bf, wz_h, wh_h, E_cat, E_cat + 1024, 2048, x_ids,
      newh_bf, gs);

  // w_hid + s_hid paired (both EP3)
  GP gw{newh_bf, w_n, 512, 512, C_cat, 1024, contexts, nullptr, nullptr,
        nullptr, whid_bf, 512};
  GP gu{stoph_bf, u_n, 512, 512, C_cat + 512, 1024, contexts, nullptr, nullptr,
        nullptr, shid_bf, 512};
  k_pair<3, 3, 512><<<dim3(4, 128, 2), dim3(512), 0, stream>>>(gw, gu);

  // word scores (z==0) + stop scores (z==1)
  GP gword{whid_bf, wo, 512, 512, nullptr, 0, nullptr, Wo_b, nullptr,
           out, nullptr, 1025};
  k_wordstop<<<dim3(8, 128, 2), dim3(512), 0, stream>>>(
      gword, shid_bf, Uo_w, Uo_b, out);
}